// Round 6
// baseline (1003.022 us; speedup 1.0000x reference)
//
#include <hip/hip_runtime.h>
#include <math.h>

#define DEV __device__ __forceinline__

#define LOG2E 1.4426950408889634f

DEV float fexp(float x)  { return __builtin_amdgcn_exp2f(LOG2E * x); }
DEV float fsigm(float x) { return __builtin_amdgcn_rcpf(1.0f + __builtin_amdgcn_exp2f(-LOG2E * x)); }
DEV float ftanh(float x) { return 1.0f - 2.0f * __builtin_amdgcn_rcpf(__builtin_amdgcn_exp2f(2.0f * LOG2E * x) + 1.0f); }
DEV float lrelu02(float x) { return x > 0.0f ? x : 0.2f * x; }
DEV float readl(float v, int l) {
    return __int_as_float(__builtin_amdgcn_readlane(__float_as_int(v), l));
}

// ---------------------------------------------------------------------------
// Degree histogram, standalone at full width (attribution probe + width).
// ---------------------------------------------------------------------------
__global__ __launch_bounds__(256) void k_deg(
    const int* __restrict__ ei, int* __restrict__ deg, int E)
{
    int stride = gridDim.x * blockDim.x;
    for (int e = blockIdx.x * blockDim.x + threadIdx.x; e < E; e += stride)
        atomicAdd(&deg[ei[E + e]], 1);
}

// ---------------------------------------------------------------------------
// Front kernel, 512 threads/block:
//   block 0          : 2-layer LSTM, quad-gate layout, ONE barrier/step.
//   blocks [1, 1+GB) : GAT-1 partial GEMM Wxp = nf @ W1[:16] (no tsb bias).
// Front duration ~= LSTM duration now (GEMM role is ~25 us at GB=255).
// ---------------------------------------------------------------------------
__global__ __launch_bounds__(512) void k_front(
    const float* __restrict__ ts,
    const float* __restrict__ Wih0, const float* __restrict__ Whh0, const float* __restrict__ b0,
    const float* __restrict__ Wih1, const float* __restrict__ Whh1, const float* __restrict__ b1,
    const float* __restrict__ W1, float* __restrict__ tsb,
    const float* __restrict__ nf, float* __restrict__ Wxp,
    int N, int T, int GB)
{
    __shared__ __align__(16) float h0b[2][64], h1b[2][64];
    __shared__ float tss[512];
    const int tid = threadIdx.x;

    if (blockIdx.x == 0) {
        const int seg = tid >> 8;
        const int idx = tid & 255;
        const int u = idx >> 2;        // hidden unit
        const int q = idx & 3;         // gate (i,f,g,o)
        const int row = q * 64 + u;    // torch gate-row index
        const int lane = tid & 63;
        const int qbase = lane & ~3;

        float wa[64], wb[64], wih[3], bias;
        if (seg == 0) {
            bias = b0[row];
            wih[0] = Wih0[row*3+0]; wih[1] = Wih0[row*3+1]; wih[2] = Wih0[row*3+2];
#pragma unroll
            for (int k = 0; k < 64; k++) wa[k] = Whh0[row * 64 + k];
#pragma unroll
            for (int k = 0; k < 64; k++) wb[k] = 0.0f;
        } else {
            bias = b1[row];
            wih[0] = wih[1] = wih[2] = 0.f;
#pragma unroll
            for (int k = 0; k < 64; k++) wa[k] = Whh1[row * 64 + k];
#pragma unroll
            for (int k = 0; k < 64; k++) wb[k] = Wih1[row * 64 + k];
        }
        for (int i = tid; i < 3 * T && i < 512; i += 512) tss[i] = ts[i];
        if (tid < 64) {
            h0b[0][tid] = 0.f; h0b[1][tid] = 0.f;
            h1b[0][tid] = 0.f; h1b[1][tid] = 0.f;
        }
        float creg = 0.0f;             // c(u) held redundantly by the quad
        __syncthreads();

        for (int k = 0; k <= T; ++k) {
            if (seg == 0) {
                if (k < T) {
                    const float* hprev = h0b[(k + 1) & 1];   // h0(k-1)
                    float a0 = bias, a1 = 0.f, a2 = 0.f, a3 = 0.f;
                    a0 = fmaf(tss[3*k+0], wih[0], a0);
                    a1 = fmaf(tss[3*k+1], wih[1], a1);
                    a2 = fmaf(tss[3*k+2], wih[2], a2);
#pragma unroll
                    for (int p = 0; p < 64; p += 16) {
                        float4 u0 = *(const float4*)&hprev[p];
                        float4 u1 = *(const float4*)&hprev[p+4];
                        float4 u2 = *(const float4*)&hprev[p+8];
                        float4 u3 = *(const float4*)&hprev[p+12];
                        a0 = fmaf(u0.x, wa[p+0],  a0); a0 = fmaf(u0.y, wa[p+1],  a0);
                        a0 = fmaf(u0.z, wa[p+2],  a0); a0 = fmaf(u0.w, wa[p+3],  a0);
                        a1 = fmaf(u1.x, wa[p+4],  a1); a1 = fmaf(u1.y, wa[p+5],  a1);
                        a1 = fmaf(u1.z, wa[p+6],  a1); a1 = fmaf(u1.w, wa[p+7],  a1);
                        a2 = fmaf(u2.x, wa[p+8],  a2); a2 = fmaf(u2.y, wa[p+9],  a2);
                        a2 = fmaf(u2.z, wa[p+10], a2); a2 = fmaf(u2.w, wa[p+11], a2);
                        a3 = fmaf(u3.x, wa[p+12], a3); a3 = fmaf(u3.y, wa[p+13], a3);
                        a3 = fmaf(u3.z, wa[p+14], a3); a3 = fmaf(u3.w, wa[p+15], a3);
                    }
                    float mine = (a0 + a1) + (a2 + a3);
                    float gi = __shfl(mine, qbase + 0, 64);
                    float gf = __shfl(mine, qbase + 1, 64);
                    float gg = __shfl(mine, qbase + 2, 64);
                    float go = __shfl(mine, qbase + 3, 64);
                    creg = fsigm(gf) * creg + fsigm(gi) * ftanh(gg);
                    float h = fsigm(go) * ftanh(creg);
                    if (q == 0) h0b[k & 1][u] = h;
                }
            } else {
                if (k >= 1) {
                    const float* h1prev = h1b[k & 1];        // h1(k-2)
                    const float* h0in   = h0b[(k + 1) & 1];  // h0(k-1)
                    float a0 = bias, a1 = 0.f, a2 = 0.f, a3 = 0.f;
#pragma unroll
                    for (int p = 0; p < 64; p += 8) {
                        float4 u0 = *(const float4*)&h1prev[p];
                        float4 u1 = *(const float4*)&h1prev[p+4];
                        a0 = fmaf(u0.x, wa[p+0], a0); a0 = fmaf(u0.y, wa[p+1], a0);
                        a0 = fmaf(u0.z, wa[p+2], a0); a0 = fmaf(u0.w, wa[p+3], a0);
                        a1 = fmaf(u1.x, wa[p+4], a1); a1 = fmaf(u1.y, wa[p+5], a1);
                        a1 = fmaf(u1.z, wa[p+6], a1); a1 = fmaf(u1.w, wa[p+7], a1);
                        float4 v0 = *(const float4*)&h0in[p];
                        float4 v1 = *(const float4*)&h0in[p+4];
                        a2 = fmaf(v0.x, wb[p+0], a2); a2 = fmaf(v0.y, wb[p+1], a2);
                        a2 = fmaf(v0.z, wb[p+2], a2); a2 = fmaf(v0.w, wb[p+3], a2);
                        a3 = fmaf(v1.x, wb[p+4], a3); a3 = fmaf(v1.y, wb[p+5], a3);
                        a3 = fmaf(v1.z, wb[p+6], a3); a3 = fmaf(v1.w, wb[p+7], a3);
                    }
                    float mine = (a0 + a1) + (a2 + a3);
                    float gi = __shfl(mine, qbase + 0, 64);
                    float gf = __shfl(mine, qbase + 1, 64);
                    float gg = __shfl(mine, qbase + 2, 64);
                    float go = __shfl(mine, qbase + 3, 64);
                    creg = fsigm(gf) * creg + fsigm(gi) * ftanh(gg);
                    float h = fsigm(go) * ftanh(creg);
                    if (q == 0) h1b[(k + 1) & 1][u] = h;     // h1(k-1)
                }
            }
            __syncthreads();
        }
        // epilogue: tsb[c] = sum_k h1[k] * W1[16+k][c];  final h1 = h1(T-1)
        if (tid < 128) {
            const float* hf = h1b[(T - 1) & 1];
            float acc = 0.f;
#pragma unroll
            for (int kk = 0; kk < 64; kk++)
                acc = fmaf(hf[kk], W1[(16 + kk) * 128 + tid], acc);
            tsb[tid] = acc;
        }
    } else {
        // ----- GAT-1 partial GEMM: Wxp[n][c] = sum_{k<16} nf[n][k]*W1[k][c] -----
        int lane = tid & 63;
        int bw = (blockIdx.x - 1) * 8 + (tid >> 6);
        int half = bw & 1;
        int col = lane + 64 * half;
        float wreg[16];
#pragma unroll
        for (int k = 0; k < 16; k++) wreg[k] = W1[k * 128 + col];
        int nstride = (GB * 8) >> 1;
        for (int n = (bw >> 1); n < N; n += nstride) {
            int nu = __builtin_amdgcn_readfirstlane(n);
            const float* xrow = nf + (size_t)nu * 16;
            float acc = 0.f;
#pragma unroll
            for (int k = 0; k < 16; k++) acc = fmaf(xrow[k], wreg[k], acc);
            Wxp[(size_t)nu * 128 + col] = acc;
        }
    }
}

// ---------------------------------------------------------------------------
// GEMM: Y[n][c] = sum_k X[n][k]*W[k][c], C=128 fixed (layer-2 only).
// ---------------------------------------------------------------------------
template <int K>
__global__ __launch_bounds__(256) void k_gemm(
    const float* __restrict__ X, const float* __restrict__ W,
    float* __restrict__ Y, int N)
{
    int tid = threadIdx.x;
    int lane = tid & 63;
    int gw = (blockIdx.x * blockDim.x + tid) >> 6;
    int half = gw & 1;
    int col = lane + 64 * half;
    float wreg[K];
#pragma unroll
    for (int k = 0; k < K; k++) wreg[k] = W[k * 128 + col];
    int total_waves = (gridDim.x * blockDim.x) >> 6;
    int nstride = total_waves >> 1;
    for (int n = (gw >> 1); n < N; n += nstride) {
        int nu = __builtin_amdgcn_readfirstlane(n);
        const float* xrow = X + (size_t)nu * K;
        float acc = 0.f;
#pragma unroll
        for (int k = 0; k < K; k++) acc = fmaf(xrow[k], wreg[k], acc);
        Y[(size_t)nu * 128 + col] = acc;
    }
}

// ---------------------------------------------------------------------------
// Attention projections; lane owns column pair (2l, 2l+1).
// FIX=1: inputs are Wxp (missing +tsb); add per-head constants from tsb.
// ---------------------------------------------------------------------------
template <int FIX>
__global__ __launch_bounds__(256) void k_att(
    const float* __restrict__ Wx, const float* __restrict__ A,
    const float* __restrict__ tsb,
    float* __restrict__ asrc, float* __restrict__ adst, int N)
{
    int tid = threadIdx.x;
    int lane = tid & 63;
    int gw = (blockIdx.x * blockDim.x + tid) >> 6;
    int waves = (gridDim.x * blockDim.x) >> 6;
    float4 s0 = ((const float4*)A)[2*lane];
    float4 s1 = ((const float4*)A)[2*lane + 1];
    float4 d0 = ((const float4*)A)[128 + 2*lane];
    float4 d1 = ((const float4*)A)[128 + 2*lane + 1];
    float cs[4] = {0.f,0.f,0.f,0.f}, cd[4] = {0.f,0.f,0.f,0.f};
    if (FIX) {
        float2 t = ((const float2*)tsb)[lane];
        cs[0] = t.x*s0.x + t.y*s1.x; cs[1] = t.x*s0.y + t.y*s1.y;
        cs[2] = t.x*s0.z + t.y*s1.z; cs[3] = t.x*s0.w + t.y*s1.w;
        cd[0] = t.x*d0.x + t.y*d1.x; cd[1] = t.x*d0.y + t.y*d1.y;
        cd[2] = t.x*d0.z + t.y*d1.z; cd[3] = t.x*d0.w + t.y*d1.w;
#pragma unroll
        for (int off = 32; off; off >>= 1) {
#pragma unroll
            for (int h = 0; h < 4; h++) {
                cs[h] += __shfl_xor(cs[h], off, 64);
                cd[h] += __shfl_xor(cd[h], off, 64);
            }
        }
    }
    for (int n = gw; n < N; n += waves) {
        float2 w = ((const float2*)(Wx + (size_t)n * 128))[lane];
        float as[4], ad[4];
        as[0] = w.x*s0.x + w.y*s1.x; as[1] = w.x*s0.y + w.y*s1.y;
        as[2] = w.x*s0.z + w.y*s1.z; as[3] = w.x*s0.w + w.y*s1.w;
        ad[0] = w.x*d0.x + w.y*d1.x; ad[1] = w.x*d0.y + w.y*d1.y;
        ad[2] = w.x*d0.z + w.y*d1.z; ad[3] = w.x*d0.w + w.y*d1.w;
#pragma unroll
        for (int off = 32; off; off >>= 1) {
#pragma unroll
            for (int h = 0; h < 4; h++) {
                as[h] += __shfl_xor(as[h], off, 64);
                ad[h] += __shfl_xor(ad[h], off, 64);
            }
        }
        if (lane == 0) {
            float4 o1; o1.x = as[0]+cs[0]; o1.y = as[1]+cs[1];
            o1.z = as[2]+cs[2]; o1.w = as[3]+cs[3];
            float4 o2; o2.x = ad[0]+cd[0]; o2.y = ad[1]+cd[1];
            o2.z = ad[2]+cd[2]; o2.w = ad[3]+cd[3];
            ((float4*)asrc)[n] = o1;
            ((float4*)adst)[n] = o2;
        }
    }
}

// ---------------------------------------------------------------------------
// CSR build: scan of degrees + scatter of src ids.
// ---------------------------------------------------------------------------
__global__ __launch_bounds__(256) void k_scan1(
    const int* __restrict__ deg, int* __restrict__ excl, int* __restrict__ bsum, int N)
{
    int tid = threadIdx.x;
    int base = blockIdx.x * 1024 + tid * 4;
    int d0 = base + 0 < N ? deg[base + 0] : 0;
    int d1 = base + 1 < N ? deg[base + 1] : 0;
    int d2 = base + 2 < N ? deg[base + 2] : 0;
    int d3 = base + 3 < N ? deg[base + 3] : 0;
    int tsum = d0 + d1 + d2 + d3;
    int lane = tid & 63, wid = tid >> 6;
    int incl = tsum;
#pragma unroll
    for (int off = 1; off < 64; off <<= 1) {
        int t = __shfl_up(incl, off, 64);
        if (lane >= off) incl += t;
    }
    __shared__ int wsum[4];
    if (lane == 63) wsum[wid] = incl;
    __syncthreads();
    int woff = 0;
#pragma unroll
    for (int w = 0; w < 4; w++) if (w < wid) woff += wsum[w];
    int tex = woff + incl - tsum;
    if (base + 0 < N) excl[base + 0] = tex;
    if (base + 1 < N) excl[base + 1] = tex + d0;
    if (base + 2 < N) excl[base + 2] = tex + d0 + d1;
    if (base + 3 < N) excl[base + 3] = tex + d0 + d1 + d2;
    if (tid == 255) bsum[blockIdx.x] = woff + incl;
}

__global__ __launch_bounds__(256) void k_scan2(int* __restrict__ bsum, int nb)
{
    __shared__ int tmp[256];
    int tid = threadIdx.x;
    int v = tid < nb ? bsum[tid] : 0;
    tmp[tid] = v;
    __syncthreads();
    for (int off = 1; off < 256; off <<= 1) {
        int t = (tid >= off) ? tmp[tid - off] : 0;
        __syncthreads();
        tmp[tid] += t;
        __syncthreads();
    }
    if (tid < nb) bsum[tid] = tmp[tid] - v;
}

__global__ __launch_bounds__(256) void k_scan3(
    int* __restrict__ excl, const int* __restrict__ bsum,
    int* __restrict__ rowptr, int* __restrict__ fill, int N, int E)
{
    int tid = threadIdx.x;
    int base = blockIdx.x * 1024 + tid * 4;
    int off = bsum[blockIdx.x];
#pragma unroll
    for (int i = 0; i < 4; i++) {
        int idx = base + i;
        if (idx < N) {
            int v = excl[idx] + off;
            rowptr[idx] = v;
            fill[idx] = v;
        }
    }
    if (blockIdx.x == 0 && tid == 0) rowptr[N] = E;
}

__global__ __launch_bounds__(256) void k_scatter(
    const int* __restrict__ ei, int* __restrict__ fill, int* __restrict__ esrc, int E)
{
    int stride = gridDim.x * blockDim.x;
    for (int e = blockIdx.x * blockDim.x + threadIdx.x; e < E; e += stride) {
        int s = ei[e], d = ei[E + e];
        int pos = atomicAdd(&fill[d], 1);
        esrc[pos] = s;
    }
}

// ---------------------------------------------------------------------------
// Fused GAT aggregate, CSR gather, QUARTER-WAVE form: 16-lane group per dst
// node, 4 nodes per wave. Chunk = 16 edges (matches mean degree 16): full
// lane utilization in the asrc gather. Lane owns 8 output cols (2 float4).
// Chunk-0 exps stay in registers. Group-uniform cj>0 test skips dead slots.
// LAYER1=1: Wx is Wxp (missing +tsb) -> add csum*tsb, apply /4 + ELU.
// ---------------------------------------------------------------------------
template <int LAYER1>
__global__ __launch_bounds__(256) void k_msg_csr(
    const int* __restrict__ rowptr, const int* __restrict__ esrc,
    const float* __restrict__ asrc, const float* __restrict__ adst,
    const float* __restrict__ Wx, const float* __restrict__ tsb,
    float* __restrict__ out, int N)
{
    int tid = threadIdx.x;
    int lane = tid & 63;
    int grp = lane >> 4;          // 0..3: which node of the wave
    int gl = lane & 15;           // lane within group
    int wbase = lane & 48;        // group's base lane for shfl
    int gw = (blockIdx.x * blockDim.x + tid) >> 6;
    int waves = (gridDim.x * blockDim.x) >> 6;
    float4 tb0 = {0,0,0,0}, tb1 = {0,0,0,0};
    if (LAYER1) {
        tb0 = ((const float4*)tsb)[gl*2];
        tb1 = ((const float4*)tsb)[gl*2+1];
    }
    for (int m = gw; m * 4 < N; m += waves) {
        int n = m * 4 + grp;
        bool nv = n < N;
        int beg = nv ? rowptr[n] : 0;
        int end = nv ? rowptr[n + 1] : 0;
        float4 ad = {0,0,0,0};
        if (nv) ad = ((const float4*)adst)[n];

        // chunk 0 (edges beg..beg+16): exps into registers
        int e0 = beg + gl;
        bool v0 = e0 < end;
        int s0 = v0 ? esrc[e0] : 0;
        float4 a0 = ((const float4*)asrc)[s0];
        float x0 = v0 ? fexp(lrelu02(a0.x + ad.x)) : 0.f;
        float x1 = v0 ? fexp(lrelu02(a0.y + ad.y)) : 0.f;
        float x2 = v0 ? fexp(lrelu02(a0.z + ad.z)) : 0.f;
        float x3 = v0 ? fexp(lrelu02(a0.w + ad.w)) : 0.f;
        float d0 = x0, d1 = x1, d2 = x2, d3 = x3;
        for (int c = beg + 16; c < end; c += 16) {     // extra chunks (deg>16)
            int e = c + gl;
            bool v = e < end;
            int s = v ? esrc[e] : 0;
            float4 a = ((const float4*)asrc)[s];
            if (v) {
                d0 += fexp(lrelu02(a.x + ad.x));
                d1 += fexp(lrelu02(a.y + ad.y));
                d2 += fexp(lrelu02(a.z + ad.z));
                d3 += fexp(lrelu02(a.w + ad.w));
            }
        }
        // group (16-lane) reduce
#pragma unroll
        for (int off = 8; off; off >>= 1) {
            d0 += __shfl_xor(d0, off, 64);
            d1 += __shfl_xor(d1, off, 64);
            d2 += __shfl_xor(d2, off, 64);
            d3 += __shfl_xor(d3, off, 64);
        }
        float r0 = __builtin_amdgcn_rcpf(d0 + 2e-9f);
        float r1 = __builtin_amdgcn_rcpf(d1 + 2e-9f);
        float r2 = __builtin_amdgcn_rcpf(d2 + 2e-9f);
        float r3 = __builtin_amdgcn_rcpf(d3 + 2e-9f);

        float4 acc0, acc1;
        if (LAYER1) {
            float csum = d0*r0 + d1*r1 + d2*r2 + d3*r3;
            acc0.x = csum*tb0.x; acc0.y = csum*tb0.y; acc0.z = csum*tb0.z; acc0.w = csum*tb0.w;
            acc1.x = csum*tb1.x; acc1.y = csum*tb1.y; acc1.z = csum*tb1.z; acc1.w = csum*tb1.w;
        } else {
            acc0 = {0,0,0,0}; acc1 = {0,0,0,0};
        }

        // accumulate chunk 0 from registers
        float coef = x0*r0 + x1*r1 + x2*r2 + x3*r3;
#pragma unroll 4
        for (int jj = 0; jj < 16; ++jj) {
            float cj = __shfl(coef, wbase + jj, 64);
            if (cj > 0.f) {
                int sj = __shfl(s0, wbase + jj, 64);
                const float4* wr = (const float4*)(Wx + (size_t)sj * 128);
                float4 w0 = wr[gl*2], w1 = wr[gl*2+1];
                acc0.x = fmaf(cj, w0.x, acc0.x); acc0.y = fmaf(cj, w0.y, acc0.y);
                acc0.z = fmaf(cj, w0.z, acc0.z); acc0.w = fmaf(cj, w0.w, acc0.w);
                acc1.x = fmaf(cj, w1.x, acc1.x); acc1.y = fmaf(cj, w1.y, acc1.y);
                acc1.z = fmaf(cj, w1.z, acc1.z); acc1.w = fmaf(cj, w1.w, acc1.w);
            }
        }
        for (int c = beg + 16; c < end; c += 16) {     // extra chunks
            int e = c + gl;
            bool v = e < end;
            int s = v ? esrc[e] : 0;
            float4 a = ((const float4*)asrc)[s];
            float cf = 0.f;
            if (v) {
                cf = fexp(lrelu02(a.x + ad.x)) * r0
                   + fexp(lrelu02(a.y + ad.y)) * r1
                   + fexp(lrelu02(a.z + ad.z)) * r2
                   + fexp(lrelu02(a.w + ad.w)) * r3;
            }
#pragma unroll 4
            for (int jj = 0; jj < 16; ++jj) {
                float cj = __shfl(cf, wbase + jj, 64);
                if (cj > 0.f) {
                    int sj = __shfl(s, wbase + jj, 64);
                    const float4* wr = (const float4*)(Wx + (size_t)sj * 128);
                    float4 w0 = wr[gl*2], w1 = wr[gl*2+1];
                    acc0.x = fmaf(cj, w0.x, acc0.x); acc0.y = fmaf(cj, w0.y, acc0.y);
                    acc0.z = fmaf(cj, w0.z, acc0.z); acc0.w = fmaf(cj, w0.w, acc0.w);
                    acc1.x = fmaf(cj, w1.x, acc1.x); acc1.y = fmaf(cj, w1.y, acc1.y);
                    acc1.z = fmaf(cj, w1.z, acc1.z); acc1.w = fmaf(cj, w1.w, acc1.w);
                }
            }
        }
        if (LAYER1) {
            acc0.x *= 0.25f; acc0.y *= 0.25f; acc0.z *= 0.25f; acc0.w *= 0.25f;
            acc1.x *= 0.25f; acc1.y *= 0.25f; acc1.z *= 0.25f; acc1.w *= 0.25f;
            acc0.x = acc0.x > 0.f ? acc0.x : expm1f(acc0.x);
            acc0.y = acc0.y > 0.f ? acc0.y : expm1f(acc0.y);
            acc0.z = acc0.z > 0.f ? acc0.z : expm1f(acc0.z);
            acc0.w = acc0.w > 0.f ? acc0.w : expm1f(acc0.w);
            acc1.x = acc1.x > 0.f ? acc1.x : expm1f(acc1.x);
            acc1.y = acc1.y > 0.f ? acc1.y : expm1f(acc1.y);
            acc1.z = acc1.z > 0.f ? acc1.z : expm1f(acc1.z);
            acc1.w = acc1.w > 0.f ? acc1.w : expm1f(acc1.w);
        }
        if (nv) {
            float4* orow = (float4*)(out + (size_t)n * 128);
            orow[gl*2] = acc0;
            orow[gl*2+1] = acc1;
        }
    }
}

// ---------------------------------------------------------------------------
// Fused ELU + FC head. Wave per node; lane owns column pair (2l, 2l+1).
// ---------------------------------------------------------------------------
__global__ __launch_bounds__(256) void k_fc(
    const float* __restrict__ acc2, const float* __restrict__ fc1w,
    const float* __restrict__ fc1b, const float* __restrict__ fc2w,
    const float* __restrict__ fc2b, float* __restrict__ out, int N)
{
    int tid = threadIdx.x;
    int lane = tid & 63;
    int gw = (blockIdx.x * blockDim.x + tid) >> 6;
    int waves = (gridDim.x * blockDim.x) >> 6;
    float w1reg[128];
#pragma unroll
    for (int c = 0; c < 128; c++) w1reg[c] = fc1w[c * 64 + lane];
    float b1v = fc1b[lane];
    float w2 = fc2w[lane];
    float b2 = fc2b[0];
    for (int n = gw; n < N; n += waves) {
        float2 xv = ((const float2*)(acc2 + (size_t)n * 128))[lane];
        float x0 = xv.x * 0.25f, x1 = xv.y * 0.25f;
        x0 = x0 > 0.f ? x0 : expm1f(x0);
        x1 = x1 > 0.f ? x1 : expm1f(x1);
        float h = b1v;
#pragma unroll
        for (int j = 0; j < 64; j++) {
            h = fmaf(readl(x0, j), w1reg[2*j],     h);
            h = fmaf(readl(x1, j), w1reg[2*j + 1], h);
        }
        float r = fmaxf(h, 0.0f) * w2;
#pragma unroll
        for (int off = 32; off; off >>= 1) r += __shfl_xor(r, off, 64);
        if (lane == 0) out[n] = r + b2;
    }
}

extern "C" void kernel_launch(void* const* d_in, const int* in_sizes, int n_in,
                              void* d_out, int out_size, void* d_ws, size_t ws_size,
                              hipStream_t stream)
{
    const float* nf   = (const float*)d_in[0];
    const int*   ei   = (const int*)  d_in[1];
    const float* ts   = (const float*)d_in[2];
    const float* Wih0 = (const float*)d_in[3];
    const float* Whh0 = (const float*)d_in[4];
    const float* b0   = (const float*)d_in[5];
    const float* Wih1 = (const float*)d_in[6];
    const float* Whh1 = (const float*)d_in[7];
    const float* b1   = (const float*)d_in[8];
    const float* W1   = (const float*)d_in[9];
    const float* A1   = (const float*)d_in[10];
    const float* W2   = (const float*)d_in[11];
    const float* A2   = (const float*)d_in[12];
    const float* fc1w = (const float*)d_in[13];
    const float* fc1b = (const float*)d_in[14];
    const float* fc2w = (const float*)d_in[15];
    const float* fc2b = (const float*)d_in[16];

    int N = in_sizes[0] / 16;
    int E = in_sizes[1] / 2;
    int T = in_sizes[2] / 3;

    char* ws = (char*)d_ws;
    size_t off = 0;
    auto alloc = [&](size_t bytes) {
        char* p = ws + off;
        off = (off + bytes + 255) & ~(size_t)255;
        return p;
    };
    float* tsb    = (float*)alloc(512);
    float* asrc   = (float*)alloc((size_t)N * 4 * sizeof(float));
    float* adst   = (float*)alloc((size_t)N * 4 * sizeof(float));
    int*   rowptr = (int*)  alloc((size_t)(N + 1) * sizeof(int));
    int*   esrc   = (int*)  alloc((size_t)E * sizeof(int));
    int*   degfil = (int*)  alloc((size_t)N * sizeof(int));
    int*   bsum   = (int*)  alloc(256 * sizeof(int));
    float* bufA   = (float*)alloc((size_t)N * 128 * sizeof(float));
    float* bufB   = (float*)alloc((size_t)N * 128 * sizeof(float));

    int nb_scan = (N + 1023) / 1024;
    const int GB = 255;   // 1 + 255 = 256 blocks in front

    // ---- histogram standalone (attribution probe, full width) ----
    hipMemsetAsync(degfil, 0, (size_t)N * sizeof(int), stream);
    k_deg<<<2048, 256, 0, stream>>>(ei, degfil, E);

    // ---- front: LSTM (block 0) || GAT-1 partial GEMM ----
    k_front<<<1 + GB, 512, 0, stream>>>(
        ts, Wih0, Whh0, b0, Wih1, Whh1, b1, W1, tsb, nf, bufA, N, T, GB);

    // ---- CSR (scan + scatter) ----
    k_scan1<<<nb_scan, 256, 0, stream>>>(degfil, rowptr, bsum, N);
    k_scan2<<<1, 256, 0, stream>>>(bsum, nb_scan);
    k_scan3<<<nb_scan, 256, 0, stream>>>(rowptr, bsum, rowptr, degfil, N, E);
    k_scatter<<<2048, 256, 0, stream>>>(ei, degfil, esrc, E);

    // ---- GAT layer 1 (tsb folded in via fixups) ----
    k_att<1><<<1024, 256, 0, stream>>>(bufA, A1, tsb, asrc, adst, N);
    k_msg_csr<1><<<2048, 256, 0, stream>>>(rowptr, esrc, asrc, adst, bufA, tsb, bufB, N);

    // ---- GAT layer 2 ----
    k_gemm<128><<<1024, 256, 0, stream>>>(bufB, W2, bufA, N);
    k_att<0><<<1024, 256, 0, stream>>>(bufA, A2, tsb, asrc, adst, N);
    k_msg_csr<0><<<2048, 256, 0, stream>>>(rowptr, esrc, asrc, adst, bufA, tsb, bufB, N);

    // ---- FC head (fused ELU) ----
    k_fc<<<1024, 256, 0, stream>>>(bufB, fc1w, fc1b, fc2w, fc2b, (float*)d_out, N);
}

// Round 7
// 904.130 us; speedup vs baseline: 1.1094x; 1.1094x over previous
//
#include <hip/hip_runtime.h>
#include <math.h>

#define DEV __device__ __forceinline__

#define LOG2E 1.4426950408889634f

DEV float fexp(float x)  { return __builtin_amdgcn_exp2f(LOG2E * x); }
DEV float fsigm(float x) { return __builtin_amdgcn_rcpf(1.0f + __builtin_amdgcn_exp2f(-LOG2E * x)); }
DEV float ftanh(float x) { return 1.0f - 2.0f * __builtin_amdgcn_rcpf(__builtin_amdgcn_exp2f(2.0f * LOG2E * x) + 1.0f); }
DEV float lrelu02(float x) { return x > 0.0f ? x : 0.2f * x; }
DEV float readl(float v, int l) {
    return __int_as_float(__builtin_amdgcn_readlane(__float_as_int(v), l));
}

// ---------------------------------------------------------------------------
// Front kernel, 512 thr x 256 blocks (VGPR>128 => 1 block/CU, LSTM never
// shares its CU):
//   block 0               : 2-layer LSTM (quad-gate, 1 barrier/step)
//                           + epilogue: tsb and attfix[8] = tsb@A1 halves.
//   blocks [1, 1+HB)      : degree histogram (hidden under LSTM).
//   blocks [1+HB, +AB)    : att1 projections asrcP/adstP = nf @ (W1p@A1)
//                           (M1 trick; tsb part folded in via attfix later).
//   rest (GB)             : GAT-1 partial GEMM Wxp = nf @ W1[:16].
// ---------------------------------------------------------------------------
__global__ __launch_bounds__(512) void k_front(
    const float* __restrict__ ts,
    const float* __restrict__ Wih0, const float* __restrict__ Whh0, const float* __restrict__ b0,
    const float* __restrict__ Wih1, const float* __restrict__ Whh1, const float* __restrict__ b1,
    const float* __restrict__ W1, const float* __restrict__ A1,
    float* __restrict__ tsb, float* __restrict__ attfix,
    const int* __restrict__ ei, int* __restrict__ deg,
    const float* __restrict__ nf, float* __restrict__ Wxp,
    float* __restrict__ asrcP, float* __restrict__ adstP,
    int N, int E, int T, int HB, int AB, int GB)
{
    __shared__ __align__(16) float h0b[2][64], h1b[2][64];
    __shared__ float tss[512], tsbl[128], m1s[128];
    const int tid = threadIdx.x;
    const int bid = blockIdx.x;

    if (bid == 0) {
        // ----- LSTM -----
        const int seg = tid >> 8;
        const int idx = tid & 255;
        const int u = idx >> 2;
        const int q = idx & 3;
        const int row = q * 64 + u;
        const int lane = tid & 63;
        const int qbase = lane & ~3;

        float wa[64], wb[64], wih[3], bias;
        if (seg == 0) {
            bias = b0[row];
            wih[0] = Wih0[row*3+0]; wih[1] = Wih0[row*3+1]; wih[2] = Wih0[row*3+2];
#pragma unroll
            for (int k = 0; k < 64; k++) wa[k] = Whh0[row * 64 + k];
#pragma unroll
            for (int k = 0; k < 64; k++) wb[k] = 0.0f;
        } else {
            bias = b1[row];
            wih[0] = wih[1] = wih[2] = 0.f;
#pragma unroll
            for (int k = 0; k < 64; k++) wa[k] = Whh1[row * 64 + k];
#pragma unroll
            for (int k = 0; k < 64; k++) wb[k] = Wih1[row * 64 + k];
        }
        for (int i = tid; i < 3 * T && i < 512; i += 512) tss[i] = ts[i];
        if (tid < 64) {
            h0b[0][tid] = 0.f; h0b[1][tid] = 0.f;
            h1b[0][tid] = 0.f; h1b[1][tid] = 0.f;
        }
        float creg = 0.0f;
        __syncthreads();

        for (int k = 0; k <= T; ++k) {
            if (seg == 0) {
                if (k < T) {
                    const float* hprev = h0b[(k + 1) & 1];
                    float a0 = bias, a1 = 0.f, a2 = 0.f, a3 = 0.f;
                    a0 = fmaf(tss[3*k+0], wih[0], a0);
                    a1 = fmaf(tss[3*k+1], wih[1], a1);
                    a2 = fmaf(tss[3*k+2], wih[2], a2);
#pragma unroll
                    for (int p = 0; p < 64; p += 16) {
                        float4 u0 = *(const float4*)&hprev[p];
                        float4 u1 = *(const float4*)&hprev[p+4];
                        float4 u2 = *(const float4*)&hprev[p+8];
                        float4 u3 = *(const float4*)&hprev[p+12];
                        a0 = fmaf(u0.x, wa[p+0],  a0); a0 = fmaf(u0.y, wa[p+1],  a0);
                        a0 = fmaf(u0.z, wa[p+2],  a0); a0 = fmaf(u0.w, wa[p+3],  a0);
                        a1 = fmaf(u1.x, wa[p+4],  a1); a1 = fmaf(u1.y, wa[p+5],  a1);
                        a1 = fmaf(u1.z, wa[p+6],  a1); a1 = fmaf(u1.w, wa[p+7],  a1);
                        a2 = fmaf(u2.x, wa[p+8],  a2); a2 = fmaf(u2.y, wa[p+9],  a2);
                        a2 = fmaf(u2.z, wa[p+10], a2); a2 = fmaf(u2.w, wa[p+11], a2);
                        a3 = fmaf(u3.x, wa[p+12], a3); a3 = fmaf(u3.y, wa[p+13], a3);
                        a3 = fmaf(u3.z, wa[p+14], a3); a3 = fmaf(u3.w, wa[p+15], a3);
                    }
                    float mine = (a0 + a1) + (a2 + a3);
                    float gi = __shfl(mine, qbase + 0, 64);
                    float gf = __shfl(mine, qbase + 1, 64);
                    float gg = __shfl(mine, qbase + 2, 64);
                    float go = __shfl(mine, qbase + 3, 64);
                    creg = fsigm(gf) * creg + fsigm(gi) * ftanh(gg);
                    float h = fsigm(go) * ftanh(creg);
                    if (q == 0) h0b[k & 1][u] = h;
                }
            } else {
                if (k >= 1) {
                    const float* h1prev = h1b[k & 1];
                    const float* h0in   = h0b[(k + 1) & 1];
                    float a0 = bias, a1 = 0.f, a2 = 0.f, a3 = 0.f;
#pragma unroll
                    for (int p = 0; p < 64; p += 8) {
                        float4 u0 = *(const float4*)&h1prev[p];
                        float4 u1 = *(const float4*)&h1prev[p+4];
                        a0 = fmaf(u0.x, wa[p+0], a0); a0 = fmaf(u0.y, wa[p+1], a0);
                        a0 = fmaf(u0.z, wa[p+2], a0); a0 = fmaf(u0.w, wa[p+3], a0);
                        a1 = fmaf(u1.x, wa[p+4], a1); a1 = fmaf(u1.y, wa[p+5], a1);
                        a1 = fmaf(u1.z, wa[p+6], a1); a1 = fmaf(u1.w, wa[p+7], a1);
                        float4 v0 = *(const float4*)&h0in[p];
                        float4 v1 = *(const float4*)&h0in[p+4];
                        a2 = fmaf(v0.x, wb[p+0], a2); a2 = fmaf(v0.y, wb[p+1], a2);
                        a2 = fmaf(v0.z, wb[p+2], a2); a2 = fmaf(v0.w, wb[p+3], a2);
                        a3 = fmaf(v1.x, wb[p+4], a3); a3 = fmaf(v1.y, wb[p+5], a3);
                        a3 = fmaf(v1.z, wb[p+6], a3); a3 = fmaf(v1.w, wb[p+7], a3);
                    }
                    float mine = (a0 + a1) + (a2 + a3);
                    float gi = __shfl(mine, qbase + 0, 64);
                    float gf = __shfl(mine, qbase + 1, 64);
                    float gg = __shfl(mine, qbase + 2, 64);
                    float go = __shfl(mine, qbase + 3, 64);
                    creg = fsigm(gf) * creg + fsigm(gi) * ftanh(gg);
                    float h = fsigm(go) * ftanh(creg);
                    if (q == 0) h1b[(k + 1) & 1][u] = h;
                }
            }
            __syncthreads();
        }
        // epilogue: tsb[c] = h1 @ W1[16:], attfix[h8] = tsb @ A1 halves
        if (tid < 128) {
            const float* hf = h1b[(T - 1) & 1];
            float acc = 0.f;
#pragma unroll
            for (int kk = 0; kk < 64; kk++)
                acc = fmaf(hf[kk], W1[(16 + kk) * 128 + tid], acc);
            tsb[tid] = acc;
            tsbl[tid] = acc;
        }
        __syncthreads();
        if (tid < 8) {
            int half = tid >> 2, h = tid & 3;
            const float* a1p = A1 + (size_t)half * 512 + h;
            float acc = 0.f;
            for (int c = 0; c < 128; c++) acc = fmaf(tsbl[c], a1p[c * 4], acc);
            attfix[tid] = acc;
        }
    } else if (bid <= HB) {
        // ----- degree histogram -----
        int idx = (bid - 1) * 512 + tid;
        int stride = HB * 512;
        for (int e = idx; e < E; e += stride)
            atomicAdd(&deg[ei[E + e]], 1);
    } else if (bid <= HB + AB) {
        // ----- att1 projections: asrcP/adstP[n][h] = nf[n] @ M1, M1 = W1p@A1 -----
        if (tid < 128) {
            int k = tid >> 3, h8 = tid & 7, half = h8 >> 2, h = h8 & 3;
            const float* a1p = A1 + (size_t)half * 512 + h;
            const float* w1p = W1 + (size_t)k * 128;
            float acc = 0.f;
            for (int c = 0; c < 128; c++) acc = fmaf(w1p[c], a1p[c * 4], acc);
            m1s[tid] = acc;   // m1s[k*8 + (half*4+h)]
        }
        __syncthreads();
        float m1r[128];
#pragma unroll
        for (int i = 0; i < 128; i++) m1r[i] = m1s[i];
        int gt = (bid - 1 - HB) * 512 + tid;
        int tstride = AB * 512;
        for (int n = gt; n < N; n += tstride) {
            const float4* nfr = (const float4*)(nf + (size_t)n * 16);
            float4 f0 = nfr[0], f1 = nfr[1], f2 = nfr[2], f3 = nfr[3];
            float xk[16] = {f0.x,f0.y,f0.z,f0.w, f1.x,f1.y,f1.z,f1.w,
                            f2.x,f2.y,f2.z,f2.w, f3.x,f3.y,f3.z,f3.w};
            float as0=0,as1=0,as2=0,as3=0, ad0=0,ad1=0,ad2=0,ad3=0;
#pragma unroll
            for (int k = 0; k < 16; k++) {
                float xv = xk[k];
                as0 = fmaf(xv, m1r[k*8+0], as0); as1 = fmaf(xv, m1r[k*8+1], as1);
                as2 = fmaf(xv, m1r[k*8+2], as2); as3 = fmaf(xv, m1r[k*8+3], as3);
                ad0 = fmaf(xv, m1r[k*8+4], ad0); ad1 = fmaf(xv, m1r[k*8+5], ad1);
                ad2 = fmaf(xv, m1r[k*8+6], ad2); ad3 = fmaf(xv, m1r[k*8+7], ad3);
            }
            float4 o1; o1.x=as0; o1.y=as1; o1.z=as2; o1.w=as3;
            float4 o2; o2.x=ad0; o2.y=ad1; o2.z=ad2; o2.w=ad3;
            ((float4*)asrcP)[n] = o1;
            ((float4*)adstP)[n] = o2;
        }
    } else {
        // ----- GAT-1 partial GEMM: Wxp = nf @ W1[:16] -----
        int lane = tid & 63;
        int bw = (bid - 1 - HB - AB) * 8 + (tid >> 6);
        int half = bw & 1;
        int col = lane + 64 * half;
        float wreg[16];
#pragma unroll
        for (int k = 0; k < 16; k++) wreg[k] = W1[k * 128 + col];
        int nstride = GB * 4;
        for (int n = (bw >> 1); n < N; n += nstride) {
            int nu = __builtin_amdgcn_readfirstlane(n);
            const float4* xr = (const float4*)(nf + (size_t)nu * 16);
            float4 x0 = xr[0], x1 = xr[1], x2 = xr[2], x3 = xr[3];
            float acc = 0.f;
            acc = fmaf(x0.x, wreg[0],  acc); acc = fmaf(x0.y, wreg[1],  acc);
            acc = fmaf(x0.z, wreg[2],  acc); acc = fmaf(x0.w, wreg[3],  acc);
            acc = fmaf(x1.x, wreg[4],  acc); acc = fmaf(x1.y, wreg[5],  acc);
            acc = fmaf(x1.z, wreg[6],  acc); acc = fmaf(x1.w, wreg[7],  acc);
            acc = fmaf(x2.x, wreg[8],  acc); acc = fmaf(x2.y, wreg[9],  acc);
            acc = fmaf(x2.z, wreg[10], acc); acc = fmaf(x2.w, wreg[11], acc);
            acc = fmaf(x3.x, wreg[12], acc); acc = fmaf(x3.y, wreg[13], acc);
            acc = fmaf(x3.z, wreg[14], acc); acc = fmaf(x3.w, wreg[15], acc);
            Wxp[(size_t)nu * 128 + col] = acc;
        }
    }
}

// ---------------------------------------------------------------------------
// Layer-2 prep, fused: blocks [0,GB2) = GEMM Wx2 = x1 @ W2;
// blocks [GB2, GB2+AB2) = att2 projections asrc/adst = x1 @ (W2@A2).
// Both only read x1 -> no intra-kernel dependency.
// ---------------------------------------------------------------------------
__global__ __launch_bounds__(256) void k_l2pre(
    const float* __restrict__ X, const float* __restrict__ W2,
    const float* __restrict__ A2, float* __restrict__ Y,
    float* __restrict__ asrc, float* __restrict__ adst,
    int N, int GB2, int AB2)
{
    __shared__ float m2[1024];
    int tid = threadIdx.x;
    if ((int)blockIdx.x < GB2) {
        int lane = tid & 63;
        int gw = blockIdx.x * 4 + (tid >> 6);
        int half = gw & 1;
        int col = lane + 64 * half;
        float wreg[128];
#pragma unroll
        for (int k = 0; k < 128; k++) wreg[k] = W2[k * 128 + col];
        int nstride = GB2 * 2;
        for (int n = (gw >> 1); n < N; n += nstride) {
            int nu = __builtin_amdgcn_readfirstlane(n);
            const float* xrow = X + (size_t)nu * 128;
            float acc = 0.f;
#pragma unroll
            for (int k = 0; k < 128; k++) acc = fmaf(xrow[k], wreg[k], acc);
            Y[(size_t)nu * 128 + col] = acc;
        }
    } else {
        // M2[k][h8] = sum_c W2[k][c] * A2[(half*128+c)*4+h]
        {
            int k = tid >> 1;
            int hpair = (tid & 1) * 4;
            const float* w2p = W2 + (size_t)k * 128;
            const float* a2p = A2 + (size_t)(tid & 1) * 512;
            float c0 = 0, c1 = 0, c2 = 0, c3 = 0;
            for (int c = 0; c < 128; c++) {
                float w = w2p[c];
                c0 = fmaf(w, a2p[c*4+0], c0);
                c1 = fmaf(w, a2p[c*4+1], c1);
                c2 = fmaf(w, a2p[c*4+2], c2);
                c3 = fmaf(w, a2p[c*4+3], c3);
            }
            m2[k*8+hpair+0] = c0; m2[k*8+hpair+1] = c1;
            m2[k*8+hpair+2] = c2; m2[k*8+hpair+3] = c3;
        }
        __syncthreads();
        int gt = (blockIdx.x - GB2) * 256 + tid;
        int tstride = AB2 * 256;
        for (int n = gt; n < N; n += tstride) {
            const float4* xr = (const float4*)(X + (size_t)n * 128);
            float s0=0,s1=0,s2=0,s3=0, d0=0,d1=0,d2=0,d3=0;
#pragma unroll 8
            for (int c4 = 0; c4 < 32; c4++) {
                float4 xv = xr[c4];
                const float4* mrow = (const float4*)&m2[(c4*4)*8];
#pragma unroll
                for (int j = 0; j < 4; j++) {
                    float x = j==0?xv.x : j==1?xv.y : j==2?xv.z : xv.w;
                    float4 ms = mrow[j*2], md = mrow[j*2+1];
                    s0 = fmaf(x, ms.x, s0); s1 = fmaf(x, ms.y, s1);
                    s2 = fmaf(x, ms.z, s2); s3 = fmaf(x, ms.w, s3);
                    d0 = fmaf(x, md.x, d0); d1 = fmaf(x, md.y, d1);
                    d2 = fmaf(x, md.z, d2); d3 = fmaf(x, md.w, d3);
                }
            }
            float4 o1; o1.x=s0; o1.y=s1; o1.z=s2; o1.w=s3;
            float4 o2; o2.x=d0; o2.y=d1; o2.z=d2; o2.w=d3;
            ((float4*)asrc)[n] = o1;
            ((float4*)adst)[n] = o2;
        }
    }
}

// ---------------------------------------------------------------------------
// CSR build: scan of degrees + scatter of src ids.
// ---------------------------------------------------------------------------
__global__ __launch_bounds__(256) void k_scan1(
    const int* __restrict__ deg, int* __restrict__ excl, int* __restrict__ bsum, int N)
{
    int tid = threadIdx.x;
    int base = blockIdx.x * 1024 + tid * 4;
    int d0 = base + 0 < N ? deg[base + 0] : 0;
    int d1 = base + 1 < N ? deg[base + 1] : 0;
    int d2 = base + 2 < N ? deg[base + 2] : 0;
    int d3 = base + 3 < N ? deg[base + 3] : 0;
    int tsum = d0 + d1 + d2 + d3;
    int lane = tid & 63, wid = tid >> 6;
    int incl = tsum;
#pragma unroll
    for (int off = 1; off < 64; off <<= 1) {
        int t = __shfl_up(incl, off, 64);
        if (lane >= off) incl += t;
    }
    __shared__ int wsum[4];
    if (lane == 63) wsum[wid] = incl;
    __syncthreads();
    int woff = 0;
#pragma unroll
    for (int w = 0; w < 4; w++) if (w < wid) woff += wsum[w];
    int tex = woff + incl - tsum;
    if (base + 0 < N) excl[base + 0] = tex;
    if (base + 1 < N) excl[base + 1] = tex + d0;
    if (base + 2 < N) excl[base + 2] = tex + d0 + d1;
    if (base + 3 < N) excl[base + 3] = tex + d0 + d1 + d2;
    if (tid == 255) bsum[blockIdx.x] = woff + incl;
}

__global__ __launch_bounds__(256) void k_scan2(int* __restrict__ bsum, int nb)
{
    __shared__ int tmp[256];
    int tid = threadIdx.x;
    int v = tid < nb ? bsum[tid] : 0;
    tmp[tid] = v;
    __syncthreads();
    for (int off = 1; off < 256; off <<= 1) {
        int t = (tid >= off) ? tmp[tid - off] : 0;
        __syncthreads();
        tmp[tid] += t;
        __syncthreads();
    }
    if (tid < nb) bsum[tid] = tmp[tid] - v;
}

__global__ __launch_bounds__(256) void k_scan3(
    int* __restrict__ excl, const int* __restrict__ bsum,
    int* __restrict__ rowptr, int* __restrict__ fill, int N, int E)
{
    int tid = threadIdx.x;
    int base = blockIdx.x * 1024 + tid * 4;
    int off = bsum[blockIdx.x];
#pragma unroll
    for (int i = 0; i < 4; i++) {
        int idx = base + i;
        if (idx < N) {
            int v = excl[idx] + off;
            rowptr[idx] = v;
            fill[idx] = v;
        }
    }
    if (blockIdx.x == 0 && tid == 0) rowptr[N] = E;
}

__global__ __launch_bounds__(256) void k_scatter(
    const int* __restrict__ ei, int* __restrict__ fill, int* __restrict__ esrc, int E)
{
    int stride = gridDim.x * blockDim.x;
    for (int e = blockIdx.x * blockDim.x + threadIdx.x; e < E; e += stride) {
        int s = ei[e], d = ei[E + e];
        int pos = atomicAdd(&fill[d], 1);
        esrc[pos] = s;
    }
}

// ---------------------------------------------------------------------------
// Fused GAT aggregate, CSR gather, quarter-wave (16-lane group per node).
// LAYER1=1: asrc/adst are P-versions; per-head constant attfix folded into
// the exp argument; output gets +csum*tsb, /4, ELU.
// ---------------------------------------------------------------------------
template <int LAYER1>
__global__ __launch_bounds__(256) void k_msg_csr(
    const int* __restrict__ rowptr, const int* __restrict__ esrc,
    const float* __restrict__ asrc, const float* __restrict__ adst,
    const float* __restrict__ Wx, const float* __restrict__ tsb,
    const float* __restrict__ attfix,
    float* __restrict__ out, int N)
{
    int tid = threadIdx.x;
    int lane = tid & 63;
    int grp = lane >> 4;
    int gl = lane & 15;
    int wbase = lane & 48;
    int gw = (blockIdx.x * blockDim.x + tid) >> 6;
    int waves = (gridDim.x * blockDim.x) >> 6;
    float4 tb0 = {0,0,0,0}, tb1 = {0,0,0,0};
    float cc0 = 0, cc1 = 0, cc2 = 0, cc3 = 0;
    if (LAYER1) {
        tb0 = ((const float4*)tsb)[gl*2];
        tb1 = ((const float4*)tsb)[gl*2+1];
        cc0 = attfix[0] + attfix[4];
        cc1 = attfix[1] + attfix[5];
        cc2 = attfix[2] + attfix[6];
        cc3 = attfix[3] + attfix[7];
    }
    for (int m = gw; m * 4 < N; m += waves) {
        int n = m * 4 + grp;
        bool nv = n < N;
        int beg = nv ? rowptr[n] : 0;
        int end = nv ? rowptr[n + 1] : 0;
        float4 ad = {0,0,0,0};
        if (nv) ad = ((const float4*)adst)[n];
        if (LAYER1) { ad.x += cc0; ad.y += cc1; ad.z += cc2; ad.w += cc3; }

        int e0 = beg + gl;
        bool v0 = e0 < end;
        int s0 = v0 ? esrc[e0] : 0;
        float4 a0 = ((const float4*)asrc)[s0];
        float x0 = v0 ? fexp(lrelu02(a0.x + ad.x)) : 0.f;
        float x1 = v0 ? fexp(lrelu02(a0.y + ad.y)) : 0.f;
        float x2 = v0 ? fexp(lrelu02(a0.z + ad.z)) : 0.f;
        float x3 = v0 ? fexp(lrelu02(a0.w + ad.w)) : 0.f;
        float d0 = x0, d1 = x1, d2 = x2, d3 = x3;
        for (int c = beg + 16; c < end; c += 16) {
            int e = c + gl;
            bool v = e < end;
            int s = v ? esrc[e] : 0;
            float4 a = ((const float4*)asrc)[s];
            if (v) {
                d0 += fexp(lrelu02(a.x + ad.x));
                d1 += fexp(lrelu02(a.y + ad.y));
                d2 += fexp(lrelu02(a.z + ad.z));
                d3 += fexp(lrelu02(a.w + ad.w));
            }
        }
#pragma unroll
        for (int off = 8; off; off >>= 1) {
            d0 += __shfl_xor(d0, off, 64);
            d1 += __shfl_xor(d1, off, 64);
            d2 += __shfl_xor(d2, off, 64);
            d3 += __shfl_xor(d3, off, 64);
        }
        float r0 = __builtin_amdgcn_rcpf(d0 + 2e-9f);
        float r1 = __builtin_amdgcn_rcpf(d1 + 2e-9f);
        float r2 = __builtin_amdgcn_rcpf(d2 + 2e-9f);
        float r3 = __builtin_amdgcn_rcpf(d3 + 2e-9f);

        float4 acc0, acc1;
        if (LAYER1) {
            float csum = d0*r0 + d1*r1 + d2*r2 + d3*r3;
            acc0.x = csum*tb0.x; acc0.y = csum*tb0.y; acc0.z = csum*tb0.z; acc0.w = csum*tb0.w;
            acc1.x = csum*tb1.x; acc1.y = csum*tb1.y; acc1.z = csum*tb1.z; acc1.w = csum*tb1.w;
        } else {
            acc0 = {0,0,0,0}; acc1 = {0,0,0,0};
        }

        float coef = x0*r0 + x1*r1 + x2*r2 + x3*r3;
#pragma unroll 4
        for (int jj = 0; jj < 16; ++jj) {
            float cj = __shfl(coef, wbase + jj, 64);
            if (cj > 0.f) {
                int sj = __shfl(s0, wbase + jj, 64);
                const float4* wr = (const float4*)(Wx + (size_t)sj * 128);
                float4 w0 = wr[gl*2], w1 = wr[gl*2+1];
                acc0.x = fmaf(cj, w0.x, acc0.x); acc0.y = fmaf(cj, w0.y, acc0.y);
                acc0.z = fmaf(cj, w0.z, acc0.z); acc0.w = fmaf(cj, w0.w, acc0.w);
                acc1.x = fmaf(cj, w1.x, acc1.x); acc1.y = fmaf(cj, w1.y, acc1.y);
                acc1.z = fmaf(cj, w1.z, acc1.z); acc1.w = fmaf(cj, w1.w, acc1.w);
            }
        }
        for (int c = beg + 16; c < end; c += 16) {
            int e = c + gl;
            bool v = e < end;
            int s = v ? esrc[e] : 0;
            float4 a = ((const float4*)asrc)[s];
            float cf = 0.f;
            if (v) {
                cf = fexp(lrelu02(a.x + ad.x)) * r0
                   + fexp(lrelu02(a.y + ad.y)) * r1
                   + fexp(lrelu02(a.z + ad.z)) * r2
                   + fexp(lrelu02(a.w + ad.w)) * r3;
            }
#pragma unroll 4
            for (int jj = 0; jj < 16; ++jj) {
                float cj = __shfl(cf, wbase + jj, 64);
                if (cj > 0.f) {
                    int sj = __shfl(s, wbase + jj, 64);
                    const float4* wr = (const float4*)(Wx + (size_t)sj * 128);
                    float4 w0 = wr[gl*2], w1 = wr[gl*2+1];
                    acc0.x = fmaf(cj, w0.x, acc0.x); acc0.y = fmaf(cj, w0.y, acc0.y);
                    acc0.z = fmaf(cj, w0.z, acc0.z); acc0.w = fmaf(cj, w0.w, acc0.w);
                    acc1.x = fmaf(cj, w1.x, acc1.x); acc1.y = fmaf(cj, w1.y, acc1.y);
                    acc1.z = fmaf(cj, w1.z, acc1.z); acc1.w = fmaf(cj, w1.w, acc1.w);
                }
            }
        }
        if (LAYER1) {
            acc0.x *= 0.25f; acc0.y *= 0.25f; acc0.z *= 0.25f; acc0.w *= 0.25f;
            acc1.x *= 0.25f; acc1.y *= 0.25f; acc1.z *= 0.25f; acc1.w *= 0.25f;
            acc0.x = acc0.x > 0.f ? acc0.x : expm1f(acc0.x);
            acc0.y = acc0.y > 0.f ? acc0.y : expm1f(acc0.y);
            acc0.z = acc0.z > 0.f ? acc0.z : expm1f(acc0.z);
            acc0.w = acc0.w > 0.f ? acc0.w : expm1f(acc0.w);
            acc1.x = acc1.x > 0.f ? acc1.x : expm1f(acc1.x);
            acc1.y = acc1.y > 0.f ? acc1.y : expm1f(acc1.y);
            acc1.z = acc1.z > 0.f ? acc1.z : expm1f(acc1.z);
            acc1.w = acc1.w > 0.f ? acc1.w : expm1f(acc1.w);
        }
        if (nv) {
            float4* orow = (float4*)(out + (size_t)n * 128);
            orow[gl*2] = acc0;
            orow[gl*2+1] = acc1;
        }
    }
}

// ---------------------------------------------------------------------------
// Fused ELU + FC head. Wave per node; lane owns column pair (2l, 2l+1).
// ---------------------------------------------------------------------------
__global__ __launch_bounds__(256) void k_fc(
    const float* __restrict__ acc2, const float* __restrict__ fc1w,
    const float* __restrict__ fc1b, const float* __restrict__ fc2w,
    const float* __restrict__ fc2b, float* __restrict__ out, int N)
{
    int tid = threadIdx.x;
    int lane = tid & 63;
    int gw = (blockIdx.x * blockDim.x + tid) >> 6;
    int waves = (gridDim.x * blockDim.x) >> 6;
    float w1reg[128];
#pragma unroll
    for (int c = 0; c < 128; c++) w1reg[c] = fc1w[c * 64 + lane];
    float b1v = fc1b[lane];
    float w2 = fc2w[lane];
    float b2 = fc2b[0];
    for (int n = gw; n < N; n += waves) {
        float2 xv = ((const float2*)(acc2 + (size_t)n * 128))[lane];
        float x0 = xv.x * 0.25f, x1 = xv.y * 0.25f;
        x0 = x0 > 0.f ? x0 : expm1f(x0);
        x1 = x1 > 0.f ? x1 : expm1f(x1);
        float h = b1v;
#pragma unroll
        for (int j = 0; j < 64; j++) {
            h = fmaf(readl(x0, j), w1reg[2*j],     h);
            h = fmaf(readl(x1, j), w1reg[2*j + 1], h);
        }
        float r = fmaxf(h, 0.0f) * w2;
#pragma unroll
        for (int off = 32; off; off >>= 1) r += __shfl_xor(r, off, 64);
        if (lane == 0) out[n] = r + b2;
    }
}

extern "C" void kernel_launch(void* const* d_in, const int* in_sizes, int n_in,
                              void* d_out, int out_size, void* d_ws, size_t ws_size,
                              hipStream_t stream)
{
    const float* nf   = (const float*)d_in[0];
    const int*   ei   = (const int*)  d_in[1];
    const float* ts   = (const float*)d_in[2];
    const float* Wih0 = (const float*)d_in[3];
    const float* Whh0 = (const float*)d_in[4];
    const float* b0   = (const float*)d_in[5];
    const float* Wih1 = (const float*)d_in[6];
    const float* Whh1 = (const float*)d_in[7];
    const float* b1   = (const float*)d_in[8];
    const float* W1   = (const float*)d_in[9];
    const float* A1   = (const float*)d_in[10];
    const float* W2   = (const float*)d_in[11];
    const float* A2   = (const float*)d_in[12];
    const float* fc1w = (const float*)d_in[13];
    const float* fc1b = (const float*)d_in[14];
    const float* fc2w = (const float*)d_in[15];
    const float* fc2b = (const float*)d_in[16];

    int N = in_sizes[0] / 16;
    int E = in_sizes[1] / 2;
    int T = in_sizes[2] / 3;

    char* ws = (char*)d_ws;
    size_t off = 0;
    auto alloc = [&](size_t bytes) {
        char* p = ws + off;
        off = (off + bytes + 255) & ~(size_t)255;
        return p;
    };
    float* tsb    = (float*)alloc(512);
    float* attfix = (float*)alloc(64);
    float* asrc   = (float*)alloc((size_t)N * 4 * sizeof(float));
    float* adst   = (float*)alloc((size_t)N * 4 * sizeof(float));
    int*   rowptr = (int*)  alloc((size_t)(N + 1) * sizeof(int));
    int*   esrc   = (int*)  alloc((size_t)E * sizeof(int));
    int*   degfil = (int*)  alloc((size_t)N * sizeof(int));
    int*   bsum   = (int*)  alloc(256 * sizeof(int));
    float* bufA   = (float*)alloc((size_t)N * 128 * sizeof(float));
    float* bufB   = (float*)alloc((size_t)N * 128 * sizeof(float));

    int nb_scan = (N + 1023) / 1024;
    const int HB = 64, AB = 32, GB = 159;   // 1 + 64 + 32 + 159 = 256 blocks

    // ---- front: LSTM || histogram || att1P || GAT-1 partial GEMM ----
    hipMemsetAsync(degfil, 0, (size_t)N * sizeof(int), stream);
    k_front<<<1 + HB + AB + GB, 512, 0, stream>>>(
        ts, Wih0, Whh0, b0, Wih1, Whh1, b1, W1, A1, tsb, attfix,
        ei, degfil, nf, bufA, asrc, adst, N, E, T, HB, AB, GB);

    // ---- CSR (scan + scatter) ----
    k_scan1<<<nb_scan, 256, 0, stream>>>(degfil, rowptr, bsum, N);
    k_scan2<<<1, 256, 0, stream>>>(bsum, nb_scan);
    k_scan3<<<nb_scan, 256, 0, stream>>>(rowptr, bsum, rowptr, degfil, N, E);
    k_scatter<<<2048, 256, 0, stream>>>(ei, degfil, esrc, E);

    // ---- GAT layer 1 aggregate ----
    k_msg_csr<1><<<2048, 256, 0, stream>>>(rowptr, esrc, asrc, adst, bufA, tsb, attfix, bufB, N);

    // ---- layer-2 prep: GEMM || att2 projections (fused) ----
    k_l2pre<<<1024 + 96, 256, 0, stream>>>(bufB, W2, A2, bufA, asrc, adst, N, 1024, 96);

    // ---- GAT layer 2 aggregate ----
    k_msg_csr<0><<<2048, 256, 0, stream>>>(rowptr, esrc, asrc, adst, bufA, tsb, attfix, bufB, N);

    // ---- FC head (fused ELU) ----
    k_fc<<<1024, 256, 0, stream>>>(bufB, fc1w, fc1b, fc2w, fc2b, (float*)d_out, N);
}

// Round 8
// 770.961 us; speedup vs baseline: 1.3010x; 1.1727x over previous
//
#include <hip/hip_runtime.h>
#include <math.h>

#define DEV __device__ __forceinline__

#define LOG2E 1.4426950408889634f

DEV float fexp(float x)  { return __builtin_amdgcn_exp2f(LOG2E * x); }
DEV float fsigm(float x) { return __builtin_amdgcn_rcpf(1.0f + __builtin_amdgcn_exp2f(-LOG2E * x)); }
DEV float ftanh(float x) { return 1.0f - 2.0f * __builtin_amdgcn_rcpf(__builtin_amdgcn_exp2f(2.0f * LOG2E * x) + 1.0f); }
DEV float lrelu02(float x) { return x > 0.0f ? x : 0.2f * x; }
DEV float readl(float v, int l) {
    return __int_as_float(__builtin_amdgcn_readlane(__float_as_int(v), l));
}
DEV int aload(const int* p) {
    return __hip_atomic_load(p, __ATOMIC_RELAXED, __HIP_MEMORY_SCOPE_AGENT);
}
DEV void astore(int* p, int v) {
    __hip_atomic_store(p, v, __ATOMIC_RELAXED, __HIP_MEMORY_SCOPE_AGENT);
}

// ---------------------------------------------------------------------------
// Mega-front kernel: 256 blocks x 512 threads, 86KB static LDS => exactly
// 1 block/CU, grid == CU count => all blocks co-resident => device-scope
// flag spins are deadlock-free (no dispatch-order assumption beyond
// capacity >= grid).
//   block 0          : 2-layer LSTM (quad-gate, 1 barrier/step) + tsb/attfix.
//   blocks 1..255    : histogram -> (scan1/scan2/scan3 via flags) -> scatter,
//                      with att1P and Wxp on the non-scan blocks in between.
// CSR build is fully hidden under the LSTM's ~200us.
// Cross-block data INSIDE the kernel moves via agent-scope atomics only
// (deg reads, bsum, fill); everything else is consumed after a kernel
// boundary (full flush).
// ---------------------------------------------------------------------------
__global__ __launch_bounds__(512) void k_front(
    const float* __restrict__ ts,
    const float* __restrict__ Wih0, const float* __restrict__ Whh0, const float* __restrict__ b0,
    const float* __restrict__ Wih1, const float* __restrict__ Whh1, const float* __restrict__ b1,
    const float* __restrict__ W1, const float* __restrict__ A1,
    float* __restrict__ tsb, float* __restrict__ attfix,
    const int* __restrict__ ei, int* __restrict__ deg,
    const float* __restrict__ nf, float* __restrict__ Wxp,
    float* __restrict__ asrcP, float* __restrict__ adstP,
    int* __restrict__ rowptr, int* __restrict__ bsum,
    int* __restrict__ fill, int* __restrict__ esrc, int* __restrict__ flags,
    int N, int E, int T, int NCH)
{
    __shared__ __align__(16) float h0b[2][64], h1b[2][64];
    __shared__ __align__(16) float tsbig[21504];   // 84KB pad -> 1 block/CU; [0,512) = ts stage
    __shared__ float m1s[128];
    __shared__ int iwsum[8];
    __shared__ int stmp[512];
    const int tid = threadIdx.x;
    const int bid = blockIdx.x;

    auto signalflag = [&](int* f) {
        __syncthreads();
        if (tid == 0) {
            __threadfence();
            __hip_atomic_fetch_add(f, 1, __ATOMIC_RELEASE, __HIP_MEMORY_SCOPE_AGENT);
        }
    };
    auto waitflag = [&](int* f, int tgt) {
        if (tid == 0) {
            while (__hip_atomic_load(f, __ATOMIC_ACQUIRE, __HIP_MEMORY_SCOPE_AGENT) < tgt)
                __builtin_amdgcn_s_sleep(8);
        }
        __syncthreads();
    };

    if (bid == 0) {
        // ================= LSTM =================
        const int seg = tid >> 8;
        const int idx = tid & 255;
        const int u = idx >> 2;
        const int q = idx & 3;
        const int row = q * 64 + u;
        const int lane = tid & 63;
        const int qbase = lane & ~3;
        float* tss = tsbig;

        float wa[64], wb[64], wih[3], bias;
        if (seg == 0) {
            bias = b0[row];
            wih[0] = Wih0[row*3+0]; wih[1] = Wih0[row*3+1]; wih[2] = Wih0[row*3+2];
#pragma unroll
            for (int k = 0; k < 64; k++) wa[k] = Whh0[row * 64 + k];
#pragma unroll
            for (int k = 0; k < 64; k++) wb[k] = 0.0f;
        } else {
            bias = b1[row];
            wih[0] = wih[1] = wih[2] = 0.f;
#pragma unroll
            for (int k = 0; k < 64; k++) wa[k] = Whh1[row * 64 + k];
#pragma unroll
            for (int k = 0; k < 64; k++) wb[k] = Wih1[row * 64 + k];
        }
        for (int i = tid; i < 3 * T && i < 512; i += 512) tss[i] = ts[i];
        if (tid < 64) {
            h0b[0][tid] = 0.f; h0b[1][tid] = 0.f;
            h1b[0][tid] = 0.f; h1b[1][tid] = 0.f;
        }
        float creg = 0.0f;
        __syncthreads();

        for (int k = 0; k <= T; ++k) {
            if (seg == 0) {
                if (k < T) {
                    const float* hprev = h0b[(k + 1) & 1];
                    float a0 = bias, a1 = 0.f, a2 = 0.f, a3 = 0.f;
                    a0 = fmaf(tss[3*k+0], wih[0], a0);
                    a1 = fmaf(tss[3*k+1], wih[1], a1);
                    a2 = fmaf(tss[3*k+2], wih[2], a2);
#pragma unroll
                    for (int p = 0; p < 64; p += 16) {
                        float4 u0 = *(const float4*)&hprev[p];
                        float4 u1 = *(const float4*)&hprev[p+4];
                        float4 u2 = *(const float4*)&hprev[p+8];
                        float4 u3 = *(const float4*)&hprev[p+12];
                        a0 = fmaf(u0.x, wa[p+0],  a0); a0 = fmaf(u0.y, wa[p+1],  a0);
                        a0 = fmaf(u0.z, wa[p+2],  a0); a0 = fmaf(u0.w, wa[p+3],  a0);
                        a1 = fmaf(u1.x, wa[p+4],  a1); a1 = fmaf(u1.y, wa[p+5],  a1);
                        a1 = fmaf(u1.z, wa[p+6],  a1); a1 = fmaf(u1.w, wa[p+7],  a1);
                        a2 = fmaf(u2.x, wa[p+8],  a2); a2 = fmaf(u2.y, wa[p+9],  a2);
                        a2 = fmaf(u2.z, wa[p+10], a2); a2 = fmaf(u2.w, wa[p+11], a2);
                        a3 = fmaf(u3.x, wa[p+12], a3); a3 = fmaf(u3.y, wa[p+13], a3);
                        a3 = fmaf(u3.z, wa[p+14], a3); a3 = fmaf(u3.w, wa[p+15], a3);
                    }
                    float mine = (a0 + a1) + (a2 + a3);
                    float gi = __shfl(mine, qbase + 0, 64);
                    float gf = __shfl(mine, qbase + 1, 64);
                    float gg = __shfl(mine, qbase + 2, 64);
                    float go = __shfl(mine, qbase + 3, 64);
                    creg = fsigm(gf) * creg + fsigm(gi) * ftanh(gg);
                    float h = fsigm(go) * ftanh(creg);
                    if (q == 0) h0b[k & 1][u] = h;
                }
            } else {
                if (k >= 1) {
                    const float* h1prev = h1b[k & 1];
                    const float* h0in   = h0b[(k + 1) & 1];
                    float a0 = bias, a1 = 0.f, a2 = 0.f, a3 = 0.f;
#pragma unroll
                    for (int p = 0; p < 64; p += 8) {
                        float4 u0 = *(const float4*)&h1prev[p];
                        float4 u1 = *(const float4*)&h1prev[p+4];
                        a0 = fmaf(u0.x, wa[p+0], a0); a0 = fmaf(u0.y, wa[p+1], a0);
                        a0 = fmaf(u0.z, wa[p+2], a0); a0 = fmaf(u0.w, wa[p+3], a0);
                        a1 = fmaf(u1.x, wa[p+4], a1); a1 = fmaf(u1.y, wa[p+5], a1);
                        a1 = fmaf(u1.z, wa[p+6], a1); a1 = fmaf(u1.w, wa[p+7], a1);
                        float4 v0 = *(const float4*)&h0in[p];
                        float4 v1 = *(const float4*)&h0in[p+4];
                        a2 = fmaf(v0.x, wb[p+0], a2); a2 = fmaf(v0.y, wb[p+1], a2);
                        a2 = fmaf(v0.z, wb[p+2], a2); a2 = fmaf(v0.w, wb[p+3], a2);
                        a3 = fmaf(v1.x, wb[p+4], a3); a3 = fmaf(v1.y, wb[p+5], a3);
                        a3 = fmaf(v1.z, wb[p+6], a3); a3 = fmaf(v1.w, wb[p+7], a3);
                    }
                    float mine = (a0 + a1) + (a2 + a3);
                    float gi = __shfl(mine, qbase + 0, 64);
                    float gf = __shfl(mine, qbase + 1, 64);
                    float gg = __shfl(mine, qbase + 2, 64);
                    float go = __shfl(mine, qbase + 3, 64);
                    creg = fsigm(gf) * creg + fsigm(gi) * ftanh(gg);
                    float h = fsigm(go) * ftanh(creg);
                    if (q == 0) h1b[(k + 1) & 1][u] = h;
                }
            }
            __syncthreads();
        }
        if (tid < 128) {
            const float* hf = h1b[(T - 1) & 1];
            float acc = 0.f;
#pragma unroll
            for (int kk = 0; kk < 64; kk++)
                acc = fmaf(hf[kk], W1[(16 + kk) * 128 + tid], acc);
            tsb[tid] = acc;
            m1s[tid] = acc;
        }
        __syncthreads();
        if (tid < 8) {
            int half = tid >> 2, h = tid & 3;
            const float* a1p = A1 + (size_t)half * 512 + h;
            float acc = 0.f;
            for (int c = 0; c < 128; c++) acc = fmaf(m1s[c], a1p[c * 4], acc);
            attfix[tid] = acc;
        }
        return;
    }

    // ================= workers =================
    const int W = gridDim.x - 1;     // 255
    const int wid = bid - 1;         // 0..254

    // ---- phase H: histogram (full worker width) ----
    {
        int g = wid * 512 + tid, stride = W * 512;
        for (int e = g; e < E; e += stride)
            atomicAdd(&deg[ei[E + e]], 1);
    }
    signalflag(&flags[0]);

    if (wid < NCH) {
        // ---- CSR scan path ----
        waitflag(&flags[0], W);
        // scan1: chunk wid (2048 elems)
        int base = wid * 2048 + tid * 4;
        int d0 = base + 0 < N ? aload(&deg[base + 0]) : 0;
        int d1 = base + 1 < N ? aload(&deg[base + 1]) : 0;
        int d2 = base + 2 < N ? aload(&deg[base + 2]) : 0;
        int d3 = base + 3 < N ? aload(&deg[base + 3]) : 0;
        int tsum = d0 + d1 + d2 + d3;
        int lane = tid & 63, wv = tid >> 6;
        int incl = tsum;
#pragma unroll
        for (int off = 1; off < 64; off <<= 1) {
            int t = __shfl_up(incl, off, 64);
            if (lane >= off) incl += t;
        }
        if (lane == 63) iwsum[wv] = incl;
        __syncthreads();
        int woff = 0;
#pragma unroll
        for (int w = 0; w < 8; w++) if (w < wv) woff += iwsum[w];
        int tex = woff + incl - tsum;
        if (base + 0 < N) rowptr[base + 0] = tex;
        if (base + 1 < N) rowptr[base + 1] = tex + d0;
        if (base + 2 < N) rowptr[base + 2] = tex + d0 + d1;
        if (base + 3 < N) rowptr[base + 3] = tex + d0 + d1 + d2;
        if (tid == 511) astore(&bsum[wid], woff + incl);
        signalflag(&flags[1]);
        // scan3 (after scan2 publishes offsets)
        waitflag(&flags[2], 1);
        int off2 = aload(&bsum[wid]);
#pragma unroll
        for (int i = 0; i < 4; i++) {
            int idx = base + i;
            if (idx < N) {
                int v = rowptr[idx] + off2;
                rowptr[idx] = v;
                astore(&fill[idx], v);
            }
        }
        if (wid == 0 && tid == 0) rowptr[N] = E;
        signalflag(&flags[3]);
    } else if (wid == NCH) {
        // ---- scan2: exclusive scan of NCH block sums ----
        waitflag(&flags[1], NCH);
        int v = tid < NCH ? aload(&bsum[tid]) : 0;
        stmp[tid] = v;
        __syncthreads();
        for (int off = 1; off < 512; off <<= 1) {
            int t = (tid >= off) ? stmp[tid - off] : 0;
            __syncthreads();
            stmp[tid] += t;
            __syncthreads();
        }
        if (tid < NCH) astore(&bsum[tid], stmp[tid] - v);
        signalflag(&flags[2]);
    } else {
        // ---- att1P + Wxp on the remaining workers ----
        const int AW = W - NCH - 1;          // workers > NCH
        const int aw = wid - NCH - 1;        // 0..AW-1
        if (tid < 128) {
            int k = tid >> 3, h8 = tid & 7, half = h8 >> 2, h = h8 & 3;
            const float* a1p = A1 + (size_t)half * 512 + h;
            const float* w1p = W1 + (size_t)k * 128;
            float acc = 0.f;
            for (int c = 0; c < 128; c++) acc = fmaf(w1p[c], a1p[c * 4], acc);
            m1s[tid] = acc;
        }
        __syncthreads();
        float m1r[128];
#pragma unroll
        for (int i = 0; i < 128; i++) m1r[i] = m1s[i];
        {
            int gt = aw * 512 + tid;
            int tstride = AW * 512;
            for (int n = gt; n < N; n += tstride) {
                const float4* nfr = (const float4*)(nf + (size_t)n * 16);
                float4 f0 = nfr[0], f1 = nfr[1], f2 = nfr[2], f3 = nfr[3];
                float xk[16] = {f0.x,f0.y,f0.z,f0.w, f1.x,f1.y,f1.z,f1.w,
                                f2.x,f2.y,f2.z,f2.w, f3.x,f3.y,f3.z,f3.w};
                float as0=0,as1=0,as2=0,as3=0, ad0=0,ad1=0,ad2=0,ad3=0;
#pragma unroll
                for (int k = 0; k < 16; k++) {
                    float xv = xk[k];
                    as0 = fmaf(xv, m1r[k*8+0], as0); as1 = fmaf(xv, m1r[k*8+1], as1);
                    as2 = fmaf(xv, m1r[k*8+2], as2); as3 = fmaf(xv, m1r[k*8+3], as3);
                    ad0 = fmaf(xv, m1r[k*8+4], ad0); ad1 = fmaf(xv, m1r[k*8+5], ad1);
                    ad2 = fmaf(xv, m1r[k*8+6], ad2); ad3 = fmaf(xv, m1r[k*8+7], ad3);
                }
                float4 o1; o1.x=as0; o1.y=as1; o1.z=as2; o1.w=as3;
                float4 o2; o2.x=ad0; o2.y=ad1; o2.z=ad2; o2.w=ad3;
                ((float4*)asrcP)[n] = o1;
                ((float4*)adstP)[n] = o2;
            }
        }
        {
            // Wxp = nf @ W1[:16], pair-of-waves column scheme
            int lane = tid & 63;
            int bw = aw * 8 + (tid >> 6);
            int half = bw & 1;
            int col = lane + 64 * half;
            float wreg[16];
#pragma unroll
            for (int k = 0; k < 16; k++) wreg[k] = W1[k * 128 + col];
            int nstride = AW * 4;
            for (int n = (bw >> 1); n < N; n += nstride) {
                int nu = __builtin_amdgcn_readfirstlane(n);
                const float4* xr = (const float4*)(nf + (size_t)nu * 16);
                float4 x0 = xr[0], x1 = xr[1], x2 = xr[2], x3 = xr[3];
                float acc = 0.f;
                acc = fmaf(x0.x, wreg[0],  acc); acc = fmaf(x0.y, wreg[1],  acc);
                acc = fmaf(x0.z, wreg[2],  acc); acc = fmaf(x0.w, wreg[3],  acc);
                acc = fmaf(x1.x, wreg[4],  acc); acc = fmaf(x1.y, wreg[5],  acc);
                acc = fmaf(x1.z, wreg[6],  acc); acc = fmaf(x1.w, wreg[7],  acc);
                acc = fmaf(x2.x, wreg[8],  acc); acc = fmaf(x2.y, wreg[9],  acc);
                acc = fmaf(x2.z, wreg[10], acc); acc = fmaf(x2.w, wreg[11], acc);
                acc = fmaf(x3.x, wreg[12], acc); acc = fmaf(x3.y, wreg[13], acc);
                acc = fmaf(x3.z, wreg[14], acc); acc = fmaf(x3.w, wreg[15], acc);
                Wxp[(size_t)nu * 128 + col] = acc;
            }
        }
    }

    // ---- scatter (all workers) ----
    waitflag(&flags[3], NCH);
    {
        int g = wid * 512 + tid, stride = W * 512;
        for (int e = g; e < E; e += stride) {
            int s = ei[e], d = ei[E + e];
            int pos = atomicAdd(&fill[d], 1);
            esrc[pos] = s;
        }
    }
}

// ---------------------------------------------------------------------------
// Layer-2 prep, fused: blocks [0,GB2) = GEMM Wx2 = x1 @ W2;
// blocks [GB2, GB2+AB2) = att2 projections asrc/adst = x1 @ (W2@A2).
// ---------------------------------------------------------------------------
__global__ __launch_bounds__(256) void k_l2pre(
    const float* __restrict__ X, const float* __restrict__ W2,
    const float* __restrict__ A2, float* __restrict__ Y,
    float* __restrict__ asrc, float* __restrict__ adst,
    int N, int GB2, int AB2)
{
    __shared__ float m2[1024];
    int tid = threadIdx.x;
    if ((int)blockIdx.x < GB2) {
        int lane = tid & 63;
        int gw = blockIdx.x * 4 + (tid >> 6);
        int half = gw & 1;
        int col = lane + 64 * half;
        float wreg[128];
#pragma unroll
        for (int k = 0; k < 128; k++) wreg[k] = W2[k * 128 + col];
        int nstride = GB2 * 2;
        for (int n = (gw >> 1); n < N; n += nstride) {
            int nu = __builtin_amdgcn_readfirstlane(n);
            const float* xrow = X + (size_t)nu * 128;
            float acc = 0.f;
#pragma unroll
            for (int k = 0; k < 128; k++) acc = fmaf(xrow[k], wreg[k], acc);
            Y[(size_t)nu * 128 + col] = acc;
        }
    } else {
        {
            int k = tid >> 1;
            int hpair = (tid & 1) * 4;
            const float* w2p = W2 + (size_t)k * 128;
            const float* a2p = A2 + (size_t)(tid & 1) * 512;
            float c0 = 0, c1 = 0, c2 = 0, c3 = 0;
            for (int c = 0; c < 128; c++) {
                float w = w2p[c];
                c0 = fmaf(w, a2p[c*4+0], c0);
                c1 = fmaf(w, a2p[c*4+1], c1);
                c2 = fmaf(w, a2p[c*4+2], c2);
                c3 = fmaf(w, a2p[c*4+3], c3);
            }
            m2[k*8+hpair+0] = c0; m2[k*8+hpair+1] = c1;
            m2[k*8+hpair+2] = c2; m2[k*8+hpair+3] = c3;
        }
        __syncthreads();
        int gt = (blockIdx.x - GB2) * 256 + tid;
        int tstride = AB2 * 256;
        for (int n = gt; n < N; n += tstride) {
            const float4* xr = (const float4*)(X + (size_t)n * 128);
            float s0=0,s1=0,s2=0,s3=0, d0=0,d1=0,d2=0,d3=0;
#pragma unroll 8
            for (int c4 = 0; c4 < 32; c4++) {
                float4 xv = xr[c4];
                const float4* mrow = (const float4*)&m2[(c4*4)*8];
#pragma unroll
                for (int j = 0; j < 4; j++) {
                    float x = j==0?xv.x : j==1?xv.y : j==2?xv.z : xv.w;
                    float4 ms = mrow[j*2], md = mrow[j*2+1];
                    s0 = fmaf(x, ms.x, s0); s1 = fmaf(x, ms.y, s1);
                    s2 = fmaf(x, ms.z, s2); s3 = fmaf(x, ms.w, s3);
                    d0 = fmaf(x, md.x, d0); d1 = fmaf(x, md.y, d1);
                    d2 = fmaf(x, md.z, d2); d3 = fmaf(x, md.w, d3);
                }
            }
            float4 o1; o1.x=s0; o1.y=s1; o1.z=s2; o1.w=s3;
            float4 o2; o2.x=d0; o2.y=d1; o2.z=d2; o2.w=d3;
            ((float4*)asrc)[n] = o1;
            ((float4*)adst)[n] = o2;
        }
    }
}

// ---------------------------------------------------------------------------
// Fused GAT aggregate, CSR gather, quarter-wave (16-lane group per node).
// ---------------------------------------------------------------------------
template <int LAYER1>
__global__ __launch_bounds__(256) void k_msg_csr(
    const int* __restrict__ rowptr, const int* __restrict__ esrc,
    const float* __restrict__ asrc, const float* __restrict__ adst,
    const float* __restrict__ Wx, const float* __restrict__ tsb,
    const float* __restrict__ attfix,
    float* __restrict__ out, int N)
{
    int tid = threadIdx.x;
    int lane = tid & 63;
    int grp = lane >> 4;
    int gl = lane & 15;
    int wbase = lane & 48;
    int gw = (blockIdx.x * blockDim.x + tid) >> 6;
    int waves = (gridDim.x * blockDim.x) >> 6;
    float4 tb0 = {0,0,0,0}, tb1 = {0,0,0,0};
    float cc0 = 0, cc1 = 0, cc2 = 0, cc3 = 0;
    if (LAYER1) {
        tb0 = ((const float4*)tsb)[gl*2];
        tb1 = ((const float4*)tsb)[gl*2+1];
        cc0 = attfix[0] + attfix[4];
        cc1 = attfix[1] + attfix[5];
        cc2 = attfix[2] + attfix[6];
        cc3 = attfix[3] + attfix[7];
    }
    for (int m = gw; m * 4 < N; m += waves) {
        int n = m * 4 + grp;
        bool nv = n < N;
        int beg = nv ? rowptr[n] : 0;
        int end = nv ? rowptr[n + 1] : 0;
        float4 ad = {0,0,0,0};
        if (nv) ad = ((const float4*)adst)[n];
        if (LAYER1) { ad.x += cc0; ad.y += cc1; ad.z += cc2; ad.w += cc3; }

        int e0 = beg + gl;
        bool v0 = e0 < end;
        int s0 = v0 ? esrc[e0] : 0;
        float4 a0 = ((const float4*)asrc)[s0];
        float x0 = v0 ? fexp(lrelu02(a0.x + ad.x)) : 0.f;
        float x1 = v0 ? fexp(lrelu02(a0.y + ad.y)) : 0.f;
        float x2 = v0 ? fexp(lrelu02(a0.z + ad.z)) : 0.f;
        float x3 = v0 ? fexp(lrelu02(a0.w + ad.w)) : 0.f;
        float d0 = x0, d1 = x1, d2 = x2, d3 = x3;
        for (int c = beg + 16; c < end; c += 16) {
            int e = c + gl;
            bool v = e < end;
            int s = v ? esrc[e] : 0;
            float4 a = ((const float4*)asrc)[s];
            if (v) {
                d0 += fexp(lrelu02(a.x + ad.x));
                d1 += fexp(lrelu02(a.y + ad.y));
                d2 += fexp(lrelu02(a.z + ad.z));
                d3 += fexp(lrelu02(a.w + ad.w));
            }
        }
#pragma unroll
        for (int off = 8; off; off >>= 1) {
            d0 += __shfl_xor(d0, off, 64);
            d1 += __shfl_xor(d1, off, 64);
            d2 += __shfl_xor(d2, off, 64);
            d3 += __shfl_xor(d3, off, 64);
        }
        float r0 = __builtin_amdgcn_rcpf(d0 + 2e-9f);
        float r1 = __builtin_amdgcn_rcpf(d1 + 2e-9f);
        float r2 = __builtin_amdgcn_rcpf(d2 + 2e-9f);
        float r3 = __builtin_amdgcn_rcpf(d3 + 2e-9f);

        float4 acc0, acc1;
        if (LAYER1) {
            float csum = d0*r0 + d1*r1 + d2*r2 + d3*r3;
            acc0.x = csum*tb0.x; acc0.y = csum*tb0.y; acc0.z = csum*tb0.z; acc0.w = csum*tb0.w;
            acc1.x = csum*tb1.x; acc1.y = csum*tb1.y; acc1.z = csum*tb1.z; acc1.w = csum*tb1.w;
        } else {
            acc0 = {0,0,0,0}; acc1 = {0,0,0,0};
        }

        float coef = x0*r0 + x1*r1 + x2*r2 + x3*r3;
#pragma unroll 4
        for (int jj = 0; jj < 16; ++jj) {
            float cj = __shfl(coef, wbase + jj, 64);
            if (cj > 0.f) {
                int sj = __shfl(s0, wbase + jj, 64);
                const float4* wr = (const float4*)(Wx + (size_t)sj * 128);
                float4 w0 = wr[gl*2], w1 = wr[gl*2+1];
                acc0.x = fmaf(cj, w0.x, acc0.x); acc0.y = fmaf(cj, w0.y, acc0.y);
                acc0.z = fmaf(cj, w0.z, acc0.z); acc0.w = fmaf(cj, w0.w, acc0.w);
                acc1.x = fmaf(cj, w1.x, acc1.x); acc1.y = fmaf(cj, w1.y, acc1.y);
                acc1.z = fmaf(cj, w1.z, acc1.z); acc1.w = fmaf(cj, w1.w, acc1.w);
            }
        }
        for (int c = beg + 16; c < end; c += 16) {
            int e = c + gl;
            bool v = e < end;
            int s = v ? esrc[e] : 0;
            float4 a = ((const float4*)asrc)[s];
            float cf = 0.f;
            if (v) {
                cf = fexp(lrelu02(a.x + ad.x)) * r0
                   + fexp(lrelu02(a.y + ad.y)) * r1
                   + fexp(lrelu02(a.z + ad.z)) * r2
                   + fexp(lrelu02(a.w + ad.w)) * r3;
            }
#pragma unroll 4
            for (int jj = 0; jj < 16; ++jj) {
                float cj = __shfl(cf, wbase + jj, 64);
                if (cj > 0.f) {
                    int sj = __shfl(s, wbase + jj, 64);
                    const float4* wr = (const float4*)(Wx + (size_t)sj * 128);
                    float4 w0 = wr[gl*2], w1 = wr[gl*2+1];
                    acc0.x = fmaf(cj, w0.x, acc0.x); acc0.y = fmaf(cj, w0.y, acc0.y);
                    acc0.z = fmaf(cj, w0.z, acc0.z); acc0.w = fmaf(cj, w0.w, acc0.w);
                    acc1.x = fmaf(cj, w1.x, acc1.x); acc1.y = fmaf(cj, w1.y, acc1.y);
                    acc1.z = fmaf(cj, w1.z, acc1.z); acc1.w = fmaf(cj, w1.w, acc1.w);
                }
            }
        }
        if (LAYER1) {
            acc0.x *= 0.25f; acc0.y *= 0.25f; acc0.z *= 0.25f; acc0.w *= 0.25f;
            acc1.x *= 0.25f; acc1.y *= 0.25f; acc1.z *= 0.25f; acc1.w *= 0.25f;
            acc0.x = acc0.x > 0.f ? acc0.x : expm1f(acc0.x);
            acc0.y = acc0.y > 0.f ? acc0.y : expm1f(acc0.y);
            acc0.z = acc0.z > 0.f ? acc0.z : expm1f(acc0.z);
            acc0.w = acc0.w > 0.f ? acc0.w : expm1f(acc0.w);
            acc1.x = acc1.x > 0.f ? acc1.x : expm1f(acc1.x);
            acc1.y = acc1.y > 0.f ? acc1.y : expm1f(acc1.y);
            acc1.z = acc1.z > 0.f ? acc1.z : expm1f(acc1.z);
            acc1.w = acc1.w > 0.f ? acc1.w : expm1f(acc1.w);
        }
        if (nv) {
            float4* orow = (float4*)(out + (size_t)n * 128);
            orow[gl*2] = acc0;
            orow[gl*2+1] = acc1;
        }
    }
}

// ---------------------------------------------------------------------------
// Fused ELU + FC head. Wave per node; lane owns column pair (2l, 2l+1).
// ---------------------------------------------------------------------------
__global__ __launch_bounds__(256) void k_fc(
    const float* __restrict__ acc2, const float* __restrict__ fc1w,
    const float* __restrict__ fc1b, const float* __restrict__ fc2w,
    const float* __restrict__ fc2b, float* __restrict__ out, int N)
{
    int tid = threadIdx.x;
    int lane = tid & 63;
    int gw = (blockIdx.x * blockDim.x + tid) >> 6;
    int waves = (gridDim.x * blockDim.x) >> 6;
    float w1reg[128];
#pragma unroll
    for (int c = 0; c < 128; c++) w1reg[c] = fc1w[c * 64 + lane];
    float b1v = fc1b[lane];
    float w2 = fc2w[lane];
    float b2 = fc2b[0];
    for (int n = gw; n < N; n += waves) {
        float2 xv = ((const float2*)(acc2 + (size_t)n * 128))[lane];
        float x0 = xv.x * 0.25f, x1 = xv.y * 0.25f;
        x0 = x0 > 0.f ? x0 : expm1f(x0);
        x1 = x1 > 0.f ? x1 : expm1f(x1);
        float h = b1v;
#pragma unroll
        for (int j = 0; j < 64; j++) {
            h = fmaf(readl(x0, j), w1reg[2*j],     h);
            h = fmaf(readl(x1, j), w1reg[2*j + 1], h);
        }
        float r = fmaxf(h, 0.0f) * w2;
#pragma unroll
        for (int off = 32; off; off >>= 1) r += __shfl_xor(r, off, 64);
        if (lane == 0) out[n] = r + b2;
    }
}

extern "C" void kernel_launch(void* const* d_in, const int* in_sizes, int n_in,
                              void* d_out, int out_size, void* d_ws, size_t ws_size,
                              hipStream_t stream)
{
    const float* nf   = (const float*)d_in[0];
    const int*   ei   = (const int*)  d_in[1];
    const float* ts   = (const float*)d_in[2];
    const float* Wih0 = (const float*)d_in[3];
    const float* Whh0 = (const float*)d_in[4];
    const float* b0   = (const float*)d_in[5];
    const float* Wih1 = (const float*)d_in[6];
    const float* Whh1 = (const float*)d_in[7];
    const float* b1   = (const float*)d_in[8];
    const float* W1   = (const float*)d_in[9];
    const float* A1   = (const float*)d_in[10];
    const float* W2   = (const float*)d_in[11];
    const float* A2   = (const float*)d_in[12];
    const float* fc1w = (const float*)d_in[13];
    const float* fc1b = (const float*)d_in[14];
    const float* fc2w = (const float*)d_in[15];
    const float* fc2b = (const float*)d_in[16];

    int N = in_sizes[0] / 16;
    int E = in_sizes[1] / 2;
    int T = in_sizes[2] / 3;

    char* ws = (char*)d_ws;
    size_t off = 0;
    auto alloc = [&](size_t bytes) {
        char* p = ws + off;
        off = (off + bytes + 255) & ~(size_t)255;
        return p;
    };
    float* tsb    = (float*)alloc(512);
    float* attfix = (float*)alloc(64);
    int*   flags  = (int*)  alloc(64);
    float* asrc   = (float*)alloc((size_t)N * 4 * sizeof(float));
    float* adst   = (float*)alloc((size_t)N * 4 * sizeof(float));
    int*   rowptr = (int*)  alloc((size_t)(N + 1) * sizeof(int));
    int*   esrc   = (int*)  alloc((size_t)E * sizeof(int));
    int*   degfil = (int*)  alloc((size_t)N * sizeof(int));   // deg, then fill
    int*   bsum   = (int*)  alloc(512 * sizeof(int));
    float* bufA   = (float*)alloc((size_t)N * 128 * sizeof(float));
    float* bufB   = (float*)alloc((size_t)N * 128 * sizeof(float));

    int NCH = (N + 2047) / 2048;   // scan chunks (49 for N=100k); needs NCH+2 <= 255

    // ---- zero deg + flags (graph-capturable, replay-deterministic) ----
    hipMemsetAsync(degfil, 0, (size_t)N * sizeof(int), stream);
    hipMemsetAsync(flags, 0, 64, stream);

    // ---- mega-front: LSTM || (hist -> scan -> scatter) || att1P || Wxp ----
    k_front<<<256, 512, 0, stream>>>(
        ts, Wih0, Whh0, b0, Wih1, Whh1, b1, W1, A1, tsb, attfix,
        ei, degfil, nf, bufA, asrc, adst,
        rowptr, bsum, degfil /*fill aliases deg*/, esrc, flags,
        N, E, T, NCH);

    // ---- GAT layer 1 aggregate ----
    k_msg_csr<1><<<2048, 256, 0, stream>>>(rowptr, esrc, asrc, adst, bufA, tsb, attfix, bufB, N);

    // ---- layer-2 prep: GEMM || att2 projections (fused) ----
    k_l2pre<<<1024 + 96, 256, 0, stream>>>(bufB, W2, A2, bufA, asrc, adst, N, 1024, 96);

    // ---- GAT layer 2 aggregate ----
    k_msg_csr<0><<<2048, 256, 0, stream>>>(rowptr, esrc, asrc, adst, bufA, tsb, attfix, bufB, N);

    // ---- FC head (fused ELU) ----
    k_fc<<<1024, 256, 0, stream>>>(bufB, fc1w, fc1b, fc2w, fc2b, (float*)d_out, N);
}

// Round 9
// 666.046 us; speedup vs baseline: 1.5059x; 1.1575x over previous
//
#include <hip/hip_runtime.h>
#include <math.h>

#define DEV __device__ __forceinline__

#define LOG2E 1.4426950408889634f

DEV float fexp(float x)  { return __builtin_amdgcn_exp2f(LOG2E * x); }
DEV float fsigm(float x) { return __builtin_amdgcn_rcpf(1.0f + __builtin_amdgcn_exp2f(-LOG2E * x)); }
DEV float ftanh(float x) { return 1.0f - 2.0f * __builtin_amdgcn_rcpf(__builtin_amdgcn_exp2f(2.0f * LOG2E * x) + 1.0f); }
DEV float lrelu02(float x) { return x > 0.0f ? x : 0.2f * x; }
DEV float readl(float v, int l) {
    return __int_as_float(__builtin_amdgcn_readlane(__float_as_int(v), l));
}
DEV int aload(const int* p) {
    return __hip_atomic_load(p, __ATOMIC_RELAXED, __HIP_MEMORY_SCOPE_AGENT);
}
DEV void astore(int* p, int v) {
    __hip_atomic_store(p, v, __ATOMIC_RELAXED, __HIP_MEMORY_SCOPE_AGENT);
}
// RNE float->bf16
DEV unsigned short f2bf(float f) {
    unsigned u = __float_as_uint(f);
    return (unsigned short)((u + 0x7FFFu + ((u >> 16) & 1u)) >> 16);
}
// unpack 8 bf16 (uint4) -> 2 float4
DEV void unpack8(uint4 w, float4& lo, float4& hi) {
    lo.x = __uint_as_float(w.x << 16); lo.y = __uint_as_float(w.x & 0xFFFF0000u);
    lo.z = __uint_as_float(w.y << 16); lo.w = __uint_as_float(w.y & 0xFFFF0000u);
    hi.x = __uint_as_float(w.z << 16); hi.y = __uint_as_float(w.z & 0xFFFF0000u);
    hi.z = __uint_as_float(w.w << 16); hi.w = __uint_as_float(w.w & 0xFFFF0000u);
}
// quad broadcast via DPP (lanes 4k..4k+3 all get lane 4k+i's value)
#define QB(v, ctrl) __int_as_float(__builtin_amdgcn_mov_dpp(__float_as_int(v), ctrl, 0xF, 0xF, true))

// ---------------------------------------------------------------------------
// Mega-front: 256 blocks x 512 threads, ~88KB LDS => 1 block/CU, grid == CU
// count => all blocks co-resident => flag spins deadlock-free.
//   block 0       : 2-layer LSTM (quad-gate, DPP gate exchange, 1 barrier/step)
//                   + tsb/attfix epilogue.
//   blocks 1..255 : histogram (saving epos) -> scan via flags -> scatter
//                   (atomic-free: esrc[rowptr[d]+epos[e]] = s),
//                   att1P + Wxp(bf16) on non-scan blocks in between.
// ---------------------------------------------------------------------------
__global__ __launch_bounds__(512) void k_front(
    const float* __restrict__ ts,
    const float* __restrict__ Wih0, const float* __restrict__ Whh0, const float* __restrict__ b0,
    const float* __restrict__ Wih1, const float* __restrict__ Whh1, const float* __restrict__ b1,
    const float* __restrict__ W1, const float* __restrict__ A1,
    float* __restrict__ tsb, float* __restrict__ attfix,
    const int* __restrict__ ei, int* __restrict__ deg, int* __restrict__ epos,
    const float* __restrict__ nf, unsigned short* __restrict__ Wxp,
    float* __restrict__ asrcP, float* __restrict__ adstP,
    int* __restrict__ rowptr, int* __restrict__ bsum,
    int* __restrict__ esrc, int* __restrict__ flags,
    int N, int E, int T, int NCH)
{
    __shared__ __align__(16) float h0b[2][64], h1b[2][64];
    __shared__ __align__(16) float tsbig[21504];   // 84KB pad -> 1 block/CU
    __shared__ float m1s[128];
    __shared__ int iwsum[8];
    __shared__ int stmp[512];
    const int tid = threadIdx.x;
    const int bid = blockIdx.x;

    auto signalflag = [&](int* f) {
        __syncthreads();
        if (tid == 0) {
            __threadfence();
            __hip_atomic_fetch_add(f, 1, __ATOMIC_RELEASE, __HIP_MEMORY_SCOPE_AGENT);
        }
    };
    auto waitflag = [&](int* f, int tgt) {
        if (tid == 0) {
            while (__hip_atomic_load(f, __ATOMIC_ACQUIRE, __HIP_MEMORY_SCOPE_AGENT) < tgt)
                __builtin_amdgcn_s_sleep(8);
        }
        __syncthreads();
    };

    if (bid == 0) {
        // ================= LSTM =================
        const int seg = tid >> 8;
        const int idx = tid & 255;
        const int u = idx >> 2;
        const int q = idx & 3;
        const int row = q * 64 + u;
        float* tss = tsbig;

        float wa[64], wb[64], wih[3], bias;
        if (seg == 0) {
            bias = b0[row];
            wih[0] = Wih0[row*3+0]; wih[1] = Wih0[row*3+1]; wih[2] = Wih0[row*3+2];
#pragma unroll
            for (int k = 0; k < 64; k++) wa[k] = Whh0[row * 64 + k];
#pragma unroll
            for (int k = 0; k < 64; k++) wb[k] = 0.0f;
        } else {
            bias = b1[row];
            wih[0] = wih[1] = wih[2] = 0.f;
#pragma unroll
            for (int k = 0; k < 64; k++) wa[k] = Whh1[row * 64 + k];
#pragma unroll
            for (int k = 0; k < 64; k++) wb[k] = Wih1[row * 64 + k];
        }
        for (int i = tid; i < 3 * T && i < 512; i += 512) tss[i] = ts[i];
        if (tid < 64) {
            h0b[0][tid] = 0.f; h0b[1][tid] = 0.f;
            h1b[0][tid] = 0.f; h1b[1][tid] = 0.f;
        }
        float creg = 0.0f;
        __syncthreads();

        for (int k = 0; k <= T; ++k) {
            if (seg == 0) {
                if (k < T) {
                    const float* hprev = h0b[(k + 1) & 1];
                    float a0 = bias, a1 = 0.f, a2 = 0.f, a3 = 0.f;
                    a0 = fmaf(tss[3*k+0], wih[0], a0);
                    a1 = fmaf(tss[3*k+1], wih[1], a1);
                    a2 = fmaf(tss[3*k+2], wih[2], a2);
#pragma unroll
                    for (int p = 0; p < 64; p += 16) {
                        float4 u0 = *(const float4*)&hprev[p];
                        float4 u1 = *(const float4*)&hprev[p+4];
                        float4 u2 = *(const float4*)&hprev[p+8];
                        float4 u3 = *(const float4*)&hprev[p+12];
                        a0 = fmaf(u0.x, wa[p+0],  a0); a0 = fmaf(u0.y, wa[p+1],  a0);
                        a0 = fmaf(u0.z, wa[p+2],  a0); a0 = fmaf(u0.w, wa[p+3],  a0);
                        a1 = fmaf(u1.x, wa[p+4],  a1); a1 = fmaf(u1.y, wa[p+5],  a1);
                        a1 = fmaf(u1.z, wa[p+6],  a1); a1 = fmaf(u1.w, wa[p+7],  a1);
                        a2 = fmaf(u2.x, wa[p+8],  a2); a2 = fmaf(u2.y, wa[p+9],  a2);
                        a2 = fmaf(u2.z, wa[p+10], a2); a2 = fmaf(u2.w, wa[p+11], a2);
                        a3 = fmaf(u3.x, wa[p+12], a3); a3 = fmaf(u3.y, wa[p+13], a3);
                        a3 = fmaf(u3.z, wa[p+14], a3); a3 = fmaf(u3.w, wa[p+15], a3);
                    }
                    float mine = (a0 + a1) + (a2 + a3);
                    float gi = QB(mine, 0x00);
                    float gf = QB(mine, 0x55);
                    float gg = QB(mine, 0xAA);
                    float go = QB(mine, 0xFF);
                    creg = fsigm(gf) * creg + fsigm(gi) * ftanh(gg);
                    float h = fsigm(go) * ftanh(creg);
                    if (q == 0) h0b[k & 1][u] = h;
                }
            } else {
                if (k >= 1) {
                    const float* h1prev = h1b[k & 1];
                    const float* h0in   = h0b[(k + 1) & 1];
                    float a0 = bias, a1 = 0.f, a2 = 0.f, a3 = 0.f;
#pragma unroll
                    for (int p = 0; p < 64; p += 8) {
                        float4 u0 = *(const float4*)&h1prev[p];
                        float4 u1 = *(const float4*)&h1prev[p+4];
                        a0 = fmaf(u0.x, wa[p+0], a0); a0 = fmaf(u0.y, wa[p+1], a0);
                        a0 = fmaf(u0.z, wa[p+2], a0); a0 = fmaf(u0.w, wa[p+3], a0);
                        a1 = fmaf(u1.x, wa[p+4], a1); a1 = fmaf(u1.y, wa[p+5], a1);
                        a1 = fmaf(u1.z, wa[p+6], a1); a1 = fmaf(u1.w, wa[p+7], a1);
                        float4 v0 = *(const float4*)&h0in[p];
                        float4 v1 = *(const float4*)&h0in[p+4];
                        a2 = fmaf(v0.x, wb[p+0], a2); a2 = fmaf(v0.y, wb[p+1], a2);
                        a2 = fmaf(v0.z, wb[p+2], a2); a2 = fmaf(v0.w, wb[p+3], a2);
                        a3 = fmaf(v1.x, wb[p+4], a3); a3 = fmaf(v1.y, wb[p+5], a3);
                        a3 = fmaf(v1.z, wb[p+6], a3); a3 = fmaf(v1.w, wb[p+7], a3);
                    }
                    float mine = (a0 + a1) + (a2 + a3);
                    float gi = QB(mine, 0x00);
                    float gf = QB(mine, 0x55);
                    float gg = QB(mine, 0xAA);
                    float go = QB(mine, 0xFF);
                    creg = fsigm(gf) * creg + fsigm(gi) * ftanh(gg);
                    float h = fsigm(go) * ftanh(creg);
                    if (q == 0) h1b[(k + 1) & 1][u] = h;
                }
            }
            __syncthreads();
        }
        if (tid < 128) {
            const float* hf = h1b[(T - 1) & 1];
            float acc = 0.f;
#pragma unroll
            for (int kk = 0; kk < 64; kk++)
                acc = fmaf(hf[kk], W1[(16 + kk) * 128 + tid], acc);
            tsb[tid] = acc;
            m1s[tid] = acc;
        }
        __syncthreads();
        if (tid < 8) {
            int half = tid >> 2, h = tid & 3;
            const float* a1p = A1 + (size_t)half * 512 + h;
            float acc = 0.f;
            for (int c = 0; c < 128; c++) acc = fmaf(m1s[c], a1p[c * 4], acc);
            attfix[tid] = acc;
        }
        return;
    }

    // ================= workers =================
    const int W = gridDim.x - 1;     // 255
    const int wid = bid - 1;         // 0..254

    // ---- phase H: histogram, saving within-bucket position ----
    {
        int g = wid * 512 + tid, stride = W * 512;
        for (int e = g; e < E; e += stride)
            epos[e] = atomicAdd(&deg[ei[E + e]], 1);
    }
    signalflag(&flags[0]);

    if (wid < NCH) {
        // ---- CSR scan path ----
        waitflag(&flags[0], W);
        int base = wid * 2048 + tid * 4;
        int d0 = base + 0 < N ? aload(&deg[base + 0]) : 0;
        int d1 = base + 1 < N ? aload(&deg[base + 1]) : 0;
        int d2 = base + 2 < N ? aload(&deg[base + 2]) : 0;
        int d3 = base + 3 < N ? aload(&deg[base + 3]) : 0;
        int tsum = d0 + d1 + d2 + d3;
        int lane = tid & 63, wv = tid >> 6;
        int incl = tsum;
#pragma unroll
        for (int off = 1; off < 64; off <<= 1) {
            int t = __shfl_up(incl, off, 64);
            if (lane >= off) incl += t;
        }
        if (lane == 63) iwsum[wv] = incl;
        __syncthreads();
        int woff = 0;
#pragma unroll
        for (int w = 0; w < 8; w++) if (w < wv) woff += iwsum[w];
        int tex = woff + incl - tsum;
        if (base + 0 < N) rowptr[base + 0] = tex;
        if (base + 1 < N) rowptr[base + 1] = tex + d0;
        if (base + 2 < N) rowptr[base + 2] = tex + d0 + d1;
        if (base + 3 < N) rowptr[base + 3] = tex + d0 + d1 + d2;
        if (tid == 511) astore(&bsum[wid], woff + incl);
        signalflag(&flags[1]);
        waitflag(&flags[2], 1);
        int off2 = aload(&bsum[wid]);
#pragma unroll
        for (int i = 0; i < 4; i++) {
            int idx = base + i;
            if (idx < N) {
                int v = rowptr[idx] + off2;
                astore(&rowptr[idx], v);
            }
        }
        if (wid == 0 && tid == 0) astore(&rowptr[N], E);
        signalflag(&flags[3]);
    } else if (wid == NCH) {
        // ---- scan2 ----
        waitflag(&flags[1], NCH);
        int v = tid < NCH ? aload(&bsum[tid]) : 0;
        stmp[tid] = v;
        __syncthreads();
        for (int off = 1; off < 512; off <<= 1) {
            int t = (tid >= off) ? stmp[tid - off] : 0;
            __syncthreads();
            stmp[tid] += t;
            __syncthreads();
        }
        if (tid < NCH) astore(&bsum[tid], stmp[tid] - v);
        signalflag(&flags[2]);
    } else {
        // ---- att1P + Wxp(bf16) ----
        const int AW = W - NCH - 1;
        const int aw = wid - NCH - 1;
        if (tid < 128) {
            int k = tid >> 3, h8 = tid & 7, half = h8 >> 2, h = h8 & 3;
            const float* a1p = A1 + (size_t)half * 512 + h;
            const float* w1p = W1 + (size_t)k * 128;
            float acc = 0.f;
            for (int c = 0; c < 128; c++) acc = fmaf(w1p[c], a1p[c * 4], acc);
            m1s[tid] = acc;
        }
        __syncthreads();
        float m1r[128];
#pragma unroll
        for (int i = 0; i < 128; i++) m1r[i] = m1s[i];
        {
            int gt = aw * 512 + tid;
            int tstride = AW * 512;
            for (int n = gt; n < N; n += tstride) {
                const float4* nfr = (const float4*)(nf + (size_t)n * 16);
                float4 f0 = nfr[0], f1 = nfr[1], f2 = nfr[2], f3 = nfr[3];
                float xk[16] = {f0.x,f0.y,f0.z,f0.w, f1.x,f1.y,f1.z,f1.w,
                                f2.x,f2.y,f2.z,f2.w, f3.x,f3.y,f3.z,f3.w};
                float as0=0,as1=0,as2=0,as3=0, ad0=0,ad1=0,ad2=0,ad3=0;
#pragma unroll
                for (int k = 0; k < 16; k++) {
                    float xv = xk[k];
                    as0 = fmaf(xv, m1r[k*8+0], as0); as1 = fmaf(xv, m1r[k*8+1], as1);
                    as2 = fmaf(xv, m1r[k*8+2], as2); as3 = fmaf(xv, m1r[k*8+3], as3);
                    ad0 = fmaf(xv, m1r[k*8+4], ad0); ad1 = fmaf(xv, m1r[k*8+5], ad1);
                    ad2 = fmaf(xv, m1r[k*8+6], ad2); ad3 = fmaf(xv, m1r[k*8+7], ad3);
                }
                float4 o1; o1.x=as0; o1.y=as1; o1.z=as2; o1.w=as3;
                float4 o2; o2.x=ad0; o2.y=ad1; o2.z=ad2; o2.w=ad3;
                ((float4*)asrcP)[n] = o1;
                ((float4*)adstP)[n] = o2;
            }
        }
        {
            int lane = tid & 63;
            int bw = aw * 8 + (tid >> 6);
            int half = bw & 1;
            int col = lane + 64 * half;
            float wreg[16];
#pragma unroll
            for (int k = 0; k < 16; k++) wreg[k] = W1[k * 128 + col];
            int nstride = AW * 4;
            for (int n = (bw >> 1); n < N; n += nstride) {
                int nu = __builtin_amdgcn_readfirstlane(n);
                const float4* xr = (const float4*)(nf + (size_t)nu * 16);
                float4 x0 = xr[0], x1 = xr[1], x2 = xr[2], x3 = xr[3];
                float acc = 0.f;
                acc = fmaf(x0.x, wreg[0],  acc); acc = fmaf(x0.y, wreg[1],  acc);
                acc = fmaf(x0.z, wreg[2],  acc); acc = fmaf(x0.w, wreg[3],  acc);
                acc = fmaf(x1.x, wreg[4],  acc); acc = fmaf(x1.y, wreg[5],  acc);
                acc = fmaf(x1.z, wreg[6],  acc); acc = fmaf(x1.w, wreg[7],  acc);
                acc = fmaf(x2.x, wreg[8],  acc); acc = fmaf(x2.y, wreg[9],  acc);
                acc = fmaf(x2.z, wreg[10], acc); acc = fmaf(x2.w, wreg[11], acc);
                acc = fmaf(x3.x, wreg[12], acc); acc = fmaf(x3.y, wreg[13], acc);
                acc = fmaf(x3.z, wreg[14], acc); acc = fmaf(x3.w, wreg[15], acc);
                Wxp[(size_t)nu * 128 + col] = f2bf(acc);
            }
        }
    }

    // ---- scatter (all workers, atomic-free) ----
    waitflag(&flags[3], NCH);
    {
        int g = wid * 512 + tid, stride = W * 512;
        for (int e = g; e < E; e += stride) {
            int s = ei[e], d = ei[E + e];
            esrc[aload(&rowptr[d]) + epos[e]] = s;
        }
    }
}

// ---------------------------------------------------------------------------
// Layer-2 prep: blocks [0,GB2) = GEMM Wx2 = x1 @ W2 (bf16 out);
// blocks [GB2, GB2+AB2) = att2 projections asrc/adst = x1 @ (W2@A2).
// ---------------------------------------------------------------------------
__global__ __launch_bounds__(256) void k_l2pre(
    const float* __restrict__ X, const float* __restrict__ W2,
    const float* __restrict__ A2, unsigned short* __restrict__ Y,
    float* __restrict__ asrc, float* __restrict__ adst,
    int N, int GB2, int AB2)
{
    __shared__ float m2[1024];
    int tid = threadIdx.x;
    if ((int)blockIdx.x < GB2) {
        int lane = tid & 63;
        int gw = blockIdx.x * 4 + (tid >> 6);
        int half = gw & 1;
        int col = lane + 64 * half;
        float wreg[128];
#pragma unroll
        for (int k = 0; k < 128; k++) wreg[k] = W2[k * 128 + col];
        int nstride = GB2 * 2;
        for (int n = (gw >> 1); n < N; n += nstride) {
            int nu = __builtin_amdgcn_readfirstlane(n);
            const float* xrow = X + (size_t)nu * 128;
            float acc = 0.f;
#pragma unroll
            for (int k = 0; k < 128; k++) acc = fmaf(xrow[k], wreg[k], acc);
            Y[(size_t)nu * 128 + col] = f2bf(acc);
        }
    } else {
        {
            int k = tid >> 1;
            int hpair = (tid & 1) * 4;
            const float* w2p = W2 + (size_t)k * 128;
            const float* a2p = A2 + (size_t)(tid & 1) * 512;
            float c0 = 0, c1 = 0, c2 = 0, c3 = 0;
            for (int c = 0; c < 128; c++) {
                float w = w2p[c];
                c0 = fmaf(w, a2p[c*4+0], c0);
                c1 = fmaf(w, a2p[c*4+1], c1);
                c2 = fmaf(w, a2p[c*4+2], c2);
                c3 = fmaf(w, a2p[c*4+3], c3);
            }
            m2[k*8+hpair+0] = c0; m2[k*8+hpair+1] = c1;
            m2[k*8+hpair+2] = c2; m2[k*8+hpair+3] = c3;
        }
        __syncthreads();
        int gt = (blockIdx.x - GB2) * 256 + tid;
        int tstride = AB2 * 256;
        for (int n = gt; n < N; n += tstride) {
            const float4* xr = (const float4*)(X + (size_t)n * 128);
            float s0=0,s1=0,s2=0,s3=0, d0=0,d1=0,d2=0,d3=0;
#pragma unroll 8
            for (int c4 = 0; c4 < 32; c4++) {
                float4 xv = xr[c4];
                const float4* mrow = (const float4*)&m2[(c4*4)*8];
#pragma unroll
                for (int j = 0; j < 4; j++) {
                    float x = j==0?xv.x : j==1?xv.y : j==2?xv.z : xv.w;
                    float4 ms = mrow[j*2], md = mrow[j*2+1];
                    s0 = fmaf(x, ms.x, s0); s1 = fmaf(x, ms.y, s1);
                    s2 = fmaf(x, ms.z, s2); s3 = fmaf(x, ms.w, s3);
                    d0 = fmaf(x, md.x, d0); d1 = fmaf(x, md.y, d1);
                    d2 = fmaf(x, md.z, d2); d3 = fmaf(x, md.w, d3);
                }
            }
            float4 o1; o1.x=s0; o1.y=s1; o1.z=s2; o1.w=s3;
            float4 o2; o2.x=d0; o2.y=d1; o2.z=d2; o2.w=d3;
            ((float4*)asrc)[n] = o1;
            ((float4*)adst)[n] = o2;
        }
    }
}

// ---------------------------------------------------------------------------
// Fused GAT aggregate, CSR gather, quarter-wave; Wx rows are bf16 (256B).
// ---------------------------------------------------------------------------
template <int LAYER1>
__global__ __launch_bounds__(256) void k_msg_csr(
    const int* __restrict__ rowptr, const int* __restrict__ esrc,
    const float* __restrict__ asrc, const float* __restrict__ adst,
    const unsigned short* __restrict__ Wx, const float* __restrict__ tsb,
    const float* __restrict__ attfix,
    float* __restrict__ out, int N)
{
    int tid = threadIdx.x;
    int lane = tid & 63;
    int grp = lane >> 4;
    int gl = lane & 15;
    int wbase = lane & 48;
    int gw = (blockIdx.x * blockDim.x + tid) >> 6;
    int waves = (gridDim.x * blockDim.x) >> 6;
    float4 tb0 = {0,0,0,0}, tb1 = {0,0,0,0};
    float cc0 = 0, cc1 = 0, cc2 = 0, cc3 = 0;
    if (LAYER1) {
        tb0 = ((const float4*)tsb)[gl*2];
        tb1 = ((const float4*)tsb)[gl*2+1];
        cc0 = attfix[0] + attfix[4];
        cc1 = attfix[1] + attfix[5];
        cc2 = attfix[2] + attfix[6];
        cc3 = attfix[3] + attfix[7];
    }
    for (int m = gw; m * 4 < N; m += waves) {
        int n = m * 4 + grp;
        bool nv = n < N;
        int beg = nv ? rowptr[n] : 0;
        int end = nv ? rowptr[n + 1] : 0;
        float4 ad = {0,0,0,0};
        if (nv) ad = ((const float4*)adst)[n];
        if (LAYER1) { ad.x += cc0; ad.y += cc1; ad.z += cc2; ad.w += cc3; }

        int e0 = beg + gl;
        bool v0 = e0 < end;
        int s0 = v0 ? esrc[e0] : 0;
        float4 a0 = ((const float4*)asrc)[s0];
        float x0 = v0 ? fexp(lrelu02(a0.x + ad.x)) : 0.f;
        float x1 = v0 ? fexp(lrelu02(a0.y + ad.y)) : 0.f;
        float x2 = v0 ? fexp(lrelu02(a0.z + ad.z)) : 0.f;
        float x3 = v0 ? fexp(lrelu02(a0.w + ad.w)) : 0.f;
        float d0 = x0, d1 = x1, d2 = x2, d3 = x3;
        for (int c = beg + 16; c < end; c += 16) {
            int e = c + gl;
            bool v = e < end;
            int s = v ? esrc[e] : 0;
            float4 a = ((const float4*)asrc)[s];
            if (v) {
                d0 += fexp(lrelu02(a.x + ad.x));
                d1 += fexp(lrelu02(a.y + ad.y));
                d2 += fexp(lrelu02(a.z + ad.z));
                d3 += fexp(lrelu02(a.w + ad.w));
            }
        }
#pragma unroll
        for (int off = 8; off; off >>= 1) {
            d0 += __shfl_xor(d0, off, 64);
            d1 += __shfl_xor(d1, off, 64);
            d2 += __shfl_xor(d2, off, 64);
            d3 += __shfl_xor(d3, off, 64);
        }
        float r0 = __builtin_amdgcn_rcpf(d0 + 2e-9f);
        float r1 = __builtin_amdgcn_rcpf(d1 + 2e-9f);
        float r2 = __builtin_amdgcn_rcpf(d2 + 2e-9f);
        float r3 = __builtin_amdgcn_rcpf(d3 + 2e-9f);

        float4 acc0, acc1;
        if (LAYER1) {
            float csum = d0*r0 + d1*r1 + d2*r2 + d3*r3;
            acc0.x = csum*tb0.x; acc0.y = csum*tb0.y; acc0.z = csum*tb0.z; acc0.w = csum*tb0.w;
            acc1.x = csum*tb1.x; acc1.y = csum*tb1.y; acc1.z = csum*tb1.z; acc1.w = csum*tb1.w;
        } else {
            acc0 = {0,0,0,0}; acc1 = {0,0,0,0};
        }

        float coef = x0*r0 + x1*r1 + x2*r2 + x3*r3;
#pragma unroll 4
        for (int jj = 0; jj < 16; ++jj) {
            float cj = __shfl(coef, wbase + jj, 64);
            if (cj > 0.f) {
                int sj = __shfl(s0, wbase + jj, 64);
                uint4 w = ((const uint4*)(Wx + (size_t)sj * 128))[gl];
                float4 lo, hi; unpack8(w, lo, hi);
                acc0.x = fmaf(cj, lo.x, acc0.x); acc0.y = fmaf(cj, lo.y, acc0.y);
                acc0.z = fmaf(cj, lo.z, acc0.z); acc0.w = fmaf(cj, lo.w, acc0.w);
                acc1.x = fmaf(cj, hi.x, acc1.x); acc1.y = fmaf(cj, hi.y, acc1.y);
                acc1.z = fmaf(cj, hi.z, acc1.z); acc1.w = fmaf(cj, hi.w, acc1.w);
            }
        }
        for (int c = beg + 16; c < end; c += 16) {
            int e = c + gl;
            bool v = e < end;
            int s = v ? esrc[e] : 0;
            float4 a = ((const float4*)asrc)[s];
            float cf = 0.f;
            if (v) {
                cf = fexp(lrelu02(a.x + ad.x)) * r0
                   + fexp(lrelu02(a.y + ad.y)) * r1
                   + fexp(lrelu02(a.z + ad.z)) * r2
                   + fexp(lrelu02(a.w + ad.w)) * r3;
            }
#pragma unroll 4
            for (int jj = 0; jj < 16; ++jj) {
                float cj = __shfl(cf, wbase + jj, 64);
                if (cj > 0.f) {
                    int sj = __shfl(s, wbase + jj, 64);
                    uint4 w = ((const uint4*)(Wx + (size_t)sj * 128))[gl];
                    float4 lo, hi; unpack8(w, lo, hi);
                    acc0.x = fmaf(cj, lo.x, acc0.x); acc0.y = fmaf(cj, lo.y, acc0.y);
                    acc0.z = fmaf(cj, lo.z, acc0.z); acc0.w = fmaf(cj, lo.w, acc0.w);
                    acc1.x = fmaf(cj, hi.x, acc1.x); acc1.y = fmaf(cj, hi.y, acc1.y);
                    acc1.z = fmaf(cj, hi.z, acc1.z); acc1.w = fmaf(cj, hi.w, acc1.w);
                }
            }
        }
        if (LAYER1) {
            acc0.x *= 0.25f; acc0.y *= 0.25f; acc0.z *= 0.25f; acc0.w *= 0.25f;
            acc1.x *= 0.25f; acc1.y *= 0.25f; acc1.z *= 0.25f; acc1.w *= 0.25f;
            acc0.x = acc0.x > 0.f ? acc0.x : expm1f(acc0.x);
            acc0.y = acc0.y > 0.f ? acc0.y : expm1f(acc0.y);
            acc0.z = acc0.z > 0.f ? acc0.z : expm1f(acc0.z);
            acc0.w = acc0.w > 0.f ? acc0.w : expm1f(acc0.w);
            acc1.x = acc1.x > 0.f ? acc1.x : expm1f(acc1.x);
            acc1.y = acc1.y > 0.f ? acc1.y : expm1f(acc1.y);
            acc1.z = acc1.z > 0.f ? acc1.z : expm1f(acc1.z);
            acc1.w = acc1.w > 0.f ? acc1.w : expm1f(acc1.w);
        }
        if (nv) {
            float4* orow = (float4*)(out + (size_t)n * 128);
            orow[gl*2] = acc0;
            orow[gl*2+1] = acc1;
        }
    }
}

// ---------------------------------------------------------------------------
// Fused ELU + FC head. Wave per node; lane owns column pair (2l, 2l+1).
// ---------------------------------------------------------------------------
__global__ __launch_bounds__(256) void k_fc(
    const float* __restrict__ acc2, const float* __restrict__ fc1w,
    const float* __restrict__ fc1b, const float* __restrict__ fc2w,
    const float* __restrict__ fc2b, float* __restrict__ out, int N)
{
    int tid = threadIdx.x;
    int lane = tid & 63;
    int gw = (blockIdx.x * blockDim.x + tid) >> 6;
    int waves = (gridDim.x * blockDim.x) >> 6;
    float w1reg[128];
#pragma unroll
    for (int c = 0; c < 128; c++) w1reg[c] = fc1w[c * 64 + lane];
    float b1v = fc1b[lane];
    float w2 = fc2w[lane];
    float b2 = fc2b[0];
    for (int n = gw; n < N; n += waves) {
        float2 xv = ((const float2*)(acc2 + (size_t)n * 128))[lane];
        float x0 = xv.x * 0.25f, x1 = xv.y * 0.25f;
        x0 = x0 > 0.f ? x0 : expm1f(x0);
        x1 = x1 > 0.f ? x1 : expm1f(x1);
        float h = b1v;
#pragma unroll
        for (int j = 0; j < 64; j++) {
            h = fmaf(readl(x0, j), w1reg[2*j],     h);
            h = fmaf(readl(x1, j), w1reg[2*j + 1], h);
        }
        float r = fmaxf(h, 0.0f) * w2;
#pragma unroll
        for (int off = 32; off; off >>= 1) r += __shfl_xor(r, off, 64);
        if (lane == 0) out[n] = r + b2;
    }
}

extern "C" void kernel_launch(void* const* d_in, const int* in_sizes, int n_in,
                              void* d_out, int out_size, void* d_ws, size_t ws_size,
                              hipStream_t stream)
{
    const float* nf   = (const float*)d_in[0];
    const int*   ei   = (const int*)  d_in[1];
    const float* ts   = (const float*)d_in[2];
    const float* Wih0 = (const float*)d_in[3];
    const float* Whh0 = (const float*)d_in[4];
    const float* b0   = (const float*)d_in[5];
    const float* Wih1 = (const float*)d_in[6];
    const float* Whh1 = (const float*)d_in[7];
    const float* b1   = (const float*)d_in[8];
    const float* W1   = (const float*)d_in[9];
    const float* A1   = (const float*)d_in[10];
    const float* W2   = (const float*)d_in[11];
    const float* A2   = (const float*)d_in[12];
    const float* fc1w = (const float*)d_in[13];
    const float* fc1b = (const float*)d_in[14];
    const float* fc2w = (const float*)d_in[15];
    const float* fc2b = (const float*)d_in[16];

    int N = in_sizes[0] / 16;
    int E = in_sizes[1] / 2;
    int T = in_sizes[2] / 3;

    char* ws = (char*)d_ws;
    size_t off = 0;
    auto alloc = [&](size_t bytes) {
        char* p = ws + off;
        off = (off + bytes + 255) & ~(size_t)255;
        return p;
    };
    float* tsb    = (float*)alloc(512);
    float* attfix = (float*)alloc(64);
    int*   flags  = (int*)  alloc(64);
    float* asrc   = (float*)alloc((size_t)N * 4 * sizeof(float));
    float* adst   = (float*)alloc((size_t)N * 4 * sizeof(float));
    int*   rowptr = (int*)  alloc((size_t)(N + 1) * sizeof(int));
    int*   esrc   = (int*)  alloc((size_t)E * sizeof(int));
    int*   epos   = (int*)  alloc((size_t)E * sizeof(int));
    int*   deg    = (int*)  alloc((size_t)N * sizeof(int));
    int*   bsum   = (int*)  alloc(512 * sizeof(int));
    unsigned short* bufA = (unsigned short*)alloc((size_t)N * 128 * sizeof(unsigned short));
    float* bufB   = (float*)alloc((size_t)N * 128 * sizeof(float));

    int NCH = (N + 2047) / 2048;   // 49 for N=100k; needs NCH+2 <= 255

    hipMemsetAsync(deg, 0, (size_t)N * sizeof(int), stream);
    hipMemsetAsync(flags, 0, 64, stream);

    // ---- mega-front: LSTM || (hist+epos -> scan -> scatter) || att1P || Wxp(bf16) ----
    k_front<<<256, 512, 0, stream>>>(
        ts, Wih0, Whh0, b0, Wih1, Whh1, b1, W1, A1, tsb, attfix,
        ei, deg, epos, nf, bufA, asrc, adst,
        rowptr, bsum, esrc, flags,
        N, E, T, NCH);

    // ---- GAT layer 1 aggregate ----
    k_msg_csr<1><<<2048, 256, 0, stream>>>(rowptr, esrc, asrc, adst, bufA, tsb, attfix, bufB, N);

    // ---- layer-2 prep: GEMM(bf16 out) || att2 projections ----
    k_l2pre<<<1024 + 96, 256, 0, stream>>>(bufB, W2, A2, bufA, asrc, adst, N, 1024, 96);

    // ---- GAT layer 2 aggregate ----
    k_msg_csr<0><<<2048, 256, 0, stream>>>(rowptr, esrc, asrc, adst, bufA, tsb, attfix, bufB, N);

    // ---- FC head (fused ELU) ----
    k_fc<<<1024, 256, 0, stream>>>(bufB, fc1w, fc1b, fc2w, fc2b, (float*)d_out, N);
}

// Round 10
// 664.989 us; speedup vs baseline: 1.5083x; 1.0016x over previous
//
#include <hip/hip_runtime.h>
#include <math.h>

#define DEV __device__ __forceinline__

#define LOG2E 1.4426950408889634f

DEV float fexp(float x)  { return __builtin_amdgcn_exp2f(LOG2E * x); }
DEV float fsigm(float x) { return __builtin_amdgcn_rcpf(1.0f + __builtin_amdgcn_exp2f(-LOG2E * x)); }
DEV float ftanh(float x) { return 1.0f - 2.0f * __builtin_amdgcn_rcpf(__builtin_amdgcn_exp2f(2.0f * LOG2E * x) + 1.0f); }
DEV float lrelu02(float x) { return x > 0.0f ? x : 0.2f * x; }
DEV int aload(const int* p) {
    return __hip_atomic_load(p, __ATOMIC_RELAXED, __HIP_MEMORY_SCOPE_AGENT);
}
DEV void astore(int* p, int v) {
    __hip_atomic_store(p, v, __ATOMIC_RELAXED, __HIP_MEMORY_SCOPE_AGENT);
}
DEV unsigned short f2bf(float f) {
    unsigned u = __float_as_uint(f);
    return (unsigned short)((u + 0x7FFFu + ((u >> 16) & 1u)) >> 16);
}
DEV void unpack8(uint4 w, float4& lo, float4& hi) {
    lo.x = __uint_as_float(w.x << 16); lo.y = __uint_as_float(w.x & 0xFFFF0000u);
    lo.z = __uint_as_float(w.y << 16); lo.w = __uint_as_float(w.y & 0xFFFF0000u);
    hi.x = __uint_as_float(w.z << 16); hi.y = __uint_as_float(w.z & 0xFFFF0000u);
    hi.z = __uint_as_float(w.w << 16); hi.w = __uint_as_float(w.w & 0xFFFF0000u);
}
#define QB(v, ctrl) __int_as_float(__builtin_amdgcn_mov_dpp(__float_as_int(v), ctrl, 0xF, 0xF, true))

// ---------------------------------------------------------------------------
// Mega-front (unchanged structure from r9) + scan2 block also computes
// M2 = W2@A2 (128x8) into m2g after its scan work (concurrent with LSTM).
// ---------------------------------------------------------------------------
__global__ __launch_bounds__(512) void k_front(
    const float* __restrict__ ts,
    const float* __restrict__ Wih0, const float* __restrict__ Whh0, const float* __restrict__ b0,
    const float* __restrict__ Wih1, const float* __restrict__ Whh1, const float* __restrict__ b1,
    const float* __restrict__ W1, const float* __restrict__ A1,
    const float* __restrict__ W2, const float* __restrict__ A2,
    float* __restrict__ tsb, float* __restrict__ attfix, float* __restrict__ m2g,
    const int* __restrict__ ei, int* __restrict__ deg, int* __restrict__ epos,
    const float* __restrict__ nf, unsigned short* __restrict__ Wxp,
    float* __restrict__ asrcP, float* __restrict__ adstP,
    int* __restrict__ rowptr, int* __restrict__ bsum,
    int* __restrict__ esrc, int* __restrict__ flags,
    int N, int E, int T, int NCH)
{
    __shared__ __align__(16) float h0b[2][64], h1b[2][64];
    __shared__ __align__(16) float tsbig[21504];   // 84KB pad -> 1 block/CU
    __shared__ float m1s[128];
    __shared__ int iwsum[8];
    __shared__ int stmp[512];
    const int tid = threadIdx.x;
    const int bid = blockIdx.x;

    auto signalflag = [&](int* f) {
        __syncthreads();
        if (tid == 0) {
            __threadfence();
            __hip_atomic_fetch_add(f, 1, __ATOMIC_RELEASE, __HIP_MEMORY_SCOPE_AGENT);
        }
    };
    auto waitflag = [&](int* f, int tgt) {
        if (tid == 0) {
            while (__hip_atomic_load(f, __ATOMIC_ACQUIRE, __HIP_MEMORY_SCOPE_AGENT) < tgt)
                __builtin_amdgcn_s_sleep(8);
        }
        __syncthreads();
    };

    if (bid == 0) {
        // ================= LSTM =================
        const int seg = tid >> 8;
        const int idx = tid & 255;
        const int u = idx >> 2;
        const int q = idx & 3;
        const int row = q * 64 + u;
        float* tss = tsbig;

        float wa[64], wb[64], wih[3], bias;
        if (seg == 0) {
            bias = b0[row];
            wih[0] = Wih0[row*3+0]; wih[1] = Wih0[row*3+1]; wih[2] = Wih0[row*3+2];
#pragma unroll
            for (int k = 0; k < 64; k++) wa[k] = Whh0[row * 64 + k];
#pragma unroll
            for (int k = 0; k < 64; k++) wb[k] = 0.0f;
        } else {
            bias = b1[row];
            wih[0] = wih[1] = wih[2] = 0.f;
#pragma unroll
            for (int k = 0; k < 64; k++) wa[k] = Whh1[row * 64 + k];
#pragma unroll
            for (int k = 0; k < 64; k++) wb[k] = Wih1[row * 64 + k];
        }
        for (int i = tid; i < 3 * T && i < 512; i += 512) tss[i] = ts[i];
        if (tid < 64) {
            h0b[0][tid] = 0.f; h0b[1][tid] = 0.f;
            h1b[0][tid] = 0.f; h1b[1][tid] = 0.f;
        }
        float creg = 0.0f;
        __syncthreads();

        for (int k = 0; k <= T; ++k) {
            if (seg == 0) {
                if (k < T) {
                    const float* hprev = h0b[(k + 1) & 1];
                    float a0 = bias, a1 = 0.f, a2 = 0.f, a3 = 0.f;
                    a0 = fmaf(tss[3*k+0], wih[0], a0);
                    a1 = fmaf(tss[3*k+1], wih[1], a1);
                    a2 = fmaf(tss[3*k+2], wih[2], a2);
#pragma unroll
                    for (int p = 0; p < 64; p += 16) {
                        float4 u0 = *(const float4*)&hprev[p];
                        float4 u1 = *(const float4*)&hprev[p+4];
                        float4 u2 = *(const float4*)&hprev[p+8];
                        float4 u3 = *(const float4*)&hprev[p+12];
                        a0 = fmaf(u0.x, wa[p+0],  a0); a0 = fmaf(u0.y, wa[p+1],  a0);
                        a0 = fmaf(u0.z, wa[p+2],  a0); a0 = fmaf(u0.w, wa[p+3],  a0);
                        a1 = fmaf(u1.x, wa[p+4],  a1); a1 = fmaf(u1.y, wa[p+5],  a1);
                        a1 = fmaf(u1.z, wa[p+6],  a1); a1 = fmaf(u1.w, wa[p+7],  a1);
                        a2 = fmaf(u2.x, wa[p+8],  a2); a2 = fmaf(u2.y, wa[p+9],  a2);
                        a2 = fmaf(u2.z, wa[p+10], a2); a2 = fmaf(u2.w, wa[p+11], a2);
                        a3 = fmaf(u3.x, wa[p+12], a3); a3 = fmaf(u3.y, wa[p+13], a3);
                        a3 = fmaf(u3.z, wa[p+14], a3); a3 = fmaf(u3.w, wa[p+15], a3);
                    }
                    float mine = (a0 + a1) + (a2 + a3);
                    float gi = QB(mine, 0x00);
                    float gf = QB(mine, 0x55);
                    float gg = QB(mine, 0xAA);
                    float go = QB(mine, 0xFF);
                    creg = fsigm(gf) * creg + fsigm(gi) * ftanh(gg);
                    float h = fsigm(go) * ftanh(creg);
                    if (q == 0) h0b[k & 1][u] = h;
                }
            } else {
                if (k >= 1) {
                    const float* h1prev = h1b[k & 1];
                    const float* h0in   = h0b[(k + 1) & 1];
                    float a0 = bias, a1 = 0.f, a2 = 0.f, a3 = 0.f;
#pragma unroll
                    for (int p = 0; p < 64; p += 8) {
                        float4 u0 = *(const float4*)&h1prev[p];
                        float4 u1 = *(const float4*)&h1prev[p+4];
                        a0 = fmaf(u0.x, wa[p+0], a0); a0 = fmaf(u0.y, wa[p+1], a0);
                        a0 = fmaf(u0.z, wa[p+2], a0); a0 = fmaf(u0.w, wa[p+3], a0);
                        a1 = fmaf(u1.x, wa[p+4], a1); a1 = fmaf(u1.y, wa[p+5], a1);
                        a1 = fmaf(u1.z, wa[p+6], a1); a1 = fmaf(u1.w, wa[p+7], a1);
                        float4 v0 = *(const float4*)&h0in[p];
                        float4 v1 = *(const float4*)&h0in[p+4];
                        a2 = fmaf(v0.x, wb[p+0], a2); a2 = fmaf(v0.y, wb[p+1], a2);
                        a2 = fmaf(v0.z, wb[p+2], a2); a2 = fmaf(v0.w, wb[p+3], a2);
                        a3 = fmaf(v1.x, wb[p+4], a3); a3 = fmaf(v1.y, wb[p+5], a3);
                        a3 = fmaf(v1.z, wb[p+6], a3); a3 = fmaf(v1.w, wb[p+7], a3);
                    }
                    float mine = (a0 + a1) + (a2 + a3);
                    float gi = QB(mine, 0x00);
                    float gf = QB(mine, 0x55);
                    float gg = QB(mine, 0xAA);
                    float go = QB(mine, 0xFF);
                    creg = fsigm(gf) * creg + fsigm(gi) * ftanh(gg);
                    float h = fsigm(go) * ftanh(creg);
                    if (q == 0) h1b[(k + 1) & 1][u] = h;
                }
            }
            __syncthreads();
        }
        if (tid < 128) {
            const float* hf = h1b[(T - 1) & 1];
            float acc = 0.f;
#pragma unroll
            for (int kk = 0; kk < 64; kk++)
                acc = fmaf(hf[kk], W1[(16 + kk) * 128 + tid], acc);
            tsb[tid] = acc;
            m1s[tid] = acc;
        }
        __syncthreads();
        if (tid < 8) {
            int half = tid >> 2, h = tid & 3;
            const float* a1p = A1 + (size_t)half * 512 + h;
            float acc = 0.f;
            for (int c = 0; c < 128; c++) acc = fmaf(m1s[c], a1p[c * 4], acc);
            attfix[tid] = acc;
        }
        return;
    }

    // ================= workers =================
    const int W = gridDim.x - 1;
    const int wid = bid - 1;

    {
        int g = wid * 512 + tid, stride = W * 512;
        for (int e = g; e < E; e += stride)
            epos[e] = atomicAdd(&deg[ei[E + e]], 1);
    }
    signalflag(&flags[0]);

    if (wid < NCH) {
        waitflag(&flags[0], W);
        int base = wid * 2048 + tid * 4;
        int d0 = base + 0 < N ? aload(&deg[base + 0]) : 0;
        int d1 = base + 1 < N ? aload(&deg[base + 1]) : 0;
        int d2 = base + 2 < N ? aload(&deg[base + 2]) : 0;
        int d3 = base + 3 < N ? aload(&deg[base + 3]) : 0;
        int tsum = d0 + d1 + d2 + d3;
        int lane = tid & 63, wv = tid >> 6;
        int incl = tsum;
#pragma unroll
        for (int off = 1; off < 64; off <<= 1) {
            int t = __shfl_up(incl, off, 64);
            if (lane >= off) incl += t;
        }
        if (lane == 63) iwsum[wv] = incl;
        __syncthreads();
        int woff = 0;
#pragma unroll
        for (int w = 0; w < 8; w++) if (w < wv) woff += iwsum[w];
        int tex = woff + incl - tsum;
        if (base + 0 < N) rowptr[base + 0] = tex;
        if (base + 1 < N) rowptr[base + 1] = tex + d0;
        if (base + 2 < N) rowptr[base + 2] = tex + d0 + d1;
        if (base + 3 < N) rowptr[base + 3] = tex + d0 + d1 + d2;
        if (tid == 511) astore(&bsum[wid], woff + incl);
        signalflag(&flags[1]);
        waitflag(&flags[2], 1);
        int off2 = aload(&bsum[wid]);
#pragma unroll
        for (int i = 0; i < 4; i++) {
            int idx = base + i;
            if (idx < N) {
                int v = rowptr[idx] + off2;
                astore(&rowptr[idx], v);
            }
        }
        if (wid == 0 && tid == 0) astore(&rowptr[N], E);
        signalflag(&flags[3]);
    } else if (wid == NCH) {
        waitflag(&flags[1], NCH);
        int v = tid < NCH ? aload(&bsum[tid]) : 0;
        stmp[tid] = v;
        __syncthreads();
        for (int off = 1; off < 512; off <<= 1) {
            int t = (tid >= off) ? stmp[tid - off] : 0;
            __syncthreads();
            stmp[tid] += t;
            __syncthreads();
        }
        if (tid < NCH) astore(&bsum[tid], stmp[tid] - v);
        signalflag(&flags[2]);
        // ---- compute M2 = W2@A2 (128 x 8) while LSTM still runs ----
#pragma unroll
        for (int e = tid; e < 1024; e += 512) {
            int k = e >> 3, h8 = e & 7, half = h8 >> 2, h = h8 & 3;
            const float* w2p = W2 + (size_t)k * 128;
            const float* a2p = A2 + (size_t)half * 512 + h;
            float acc = 0.f;
            for (int c = 0; c < 128; c++) acc = fmaf(w2p[c], a2p[c * 4], acc);
            m2g[e] = acc;
        }
    } else {
        const int AW = W - NCH - 1;
        const int aw = wid - NCH - 1;
        if (tid < 128) {
            int k = tid >> 3, h8 = tid & 7, half = h8 >> 2, h = h8 & 3;
            const float* a1p = A1 + (size_t)half * 512 + h;
            const float* w1p = W1 + (size_t)k * 128;
            float acc = 0.f;
            for (int c = 0; c < 128; c++) acc = fmaf(w1p[c], a1p[c * 4], acc);
            m1s[tid] = acc;
        }
        __syncthreads();
        float m1r[128];
#pragma unroll
        for (int i = 0; i < 128; i++) m1r[i] = m1s[i];
        {
            int gt = aw * 512 + tid;
            int tstride = AW * 512;
            for (int n = gt; n < N; n += tstride) {
                const float4* nfr = (const float4*)(nf + (size_t)n * 16);
                float4 f0 = nfr[0], f1 = nfr[1], f2 = nfr[2], f3 = nfr[3];
                float xk[16] = {f0.x,f0.y,f0.z,f0.w, f1.x,f1.y,f1.z,f1.w,
                                f2.x,f2.y,f2.z,f2.w, f3.x,f3.y,f3.z,f3.w};
                float as0=0,as1=0,as2=0,as3=0, ad0=0,ad1=0,ad2=0,ad3=0;
#pragma unroll
                for (int k = 0; k < 16; k++) {
                    float xv = xk[k];
                    as0 = fmaf(xv, m1r[k*8+0], as0); as1 = fmaf(xv, m1r[k*8+1], as1);
                    as2 = fmaf(xv, m1r[k*8+2], as2); as3 = fmaf(xv, m1r[k*8+3], as3);
                    ad0 = fmaf(xv, m1r[k*8+4], ad0); ad1 = fmaf(xv, m1r[k*8+5], ad1);
                    ad2 = fmaf(xv, m1r[k*8+6], ad2); ad3 = fmaf(xv, m1r[k*8+7], ad3);
                }
                float4 o1; o1.x=as0; o1.y=as1; o1.z=as2; o1.w=as3;
                float4 o2; o2.x=ad0; o2.y=ad1; o2.z=ad2; o2.w=ad3;
                ((float4*)asrcP)[n] = o1;
                ((float4*)adstP)[n] = o2;
            }
        }
        {
            int lane = tid & 63;
            int bw = aw * 8 + (tid >> 6);
            int half = bw & 1;
            int col = lane + 64 * half;
            float wreg[16];
#pragma unroll
            for (int k = 0; k < 16; k++) wreg[k] = W1[k * 128 + col];
            int nstride = AW * 4;
            for (int n = (bw >> 1); n < N; n += nstride) {
                int nu = __builtin_amdgcn_readfirstlane(n);
                const float4* xr = (const float4*)(nf + (size_t)nu * 16);
                float4 x0 = xr[0], x1 = xr[1], x2 = xr[2], x3 = xr[3];
                float acc = 0.f;
                acc = fmaf(x0.x, wreg[0],  acc); acc = fmaf(x0.y, wreg[1],  acc);
                acc = fmaf(x0.z, wreg[2],  acc); acc = fmaf(x0.w, wreg[3],  acc);
                acc = fmaf(x1.x, wreg[4],  acc); acc = fmaf(x1.y, wreg[5],  acc);
                acc = fmaf(x1.z, wreg[6],  acc); acc = fmaf(x1.w, wreg[7],  acc);
                acc = fmaf(x2.x, wreg[8],  acc); acc = fmaf(x2.y, wreg[9],  acc);
                acc = fmaf(x2.z, wreg[10], acc); acc = fmaf(x2.w, wreg[11], acc);
                acc = fmaf(x3.x, wreg[12], acc); acc = fmaf(x3.y, wreg[13], acc);
                acc = fmaf(x3.z, wreg[14], acc); acc = fmaf(x3.w, wreg[15], acc);
                Wxp[(size_t)nu * 128 + col] = f2bf(acc);
            }
        }
    }

    waitflag(&flags[3], NCH);
    {
        int g = wid * 512 + tid, stride = W * 512;
        for (int e = g; e < E; e += stride) {
            int s = ei[e], d = ei[E + e];
            esrc[aload(&rowptr[d]) + epos[e]] = s;
        }
    }
}

// ---------------------------------------------------------------------------
// Fused GAT layer-1 aggregate + layer-2 projections. Quarter-wave groups.
// After the aggregate, x1 row (16 lanes x 8 cols, in regs) is broadcast via
// padded LDS xbuf (wave-synchronous) and multiplied by W2 (bf16, LDS) to
// produce Wx2 (bf16) and by M2 (LDS) to produce asrc2/adst2. No x1
// materialization; k_l2pre eliminated.
// ---------------------------------------------------------------------------
__global__ __launch_bounds__(512) void k_msg1(
    const int* __restrict__ rowptr, const int* __restrict__ esrc,
    const float* __restrict__ asrc, const float* __restrict__ adst,
    const unsigned short* __restrict__ Wx, const float* __restrict__ tsb,
    const float* __restrict__ attfix,
    const float* __restrict__ W2, const float* __restrict__ m2g,
    unsigned short* __restrict__ Wx2, float* __restrict__ asrc2,
    float* __restrict__ adst2, int N)
{
    __shared__ unsigned short w2s[16384];   // 32KB: W2 bf16 [k][c]
    __shared__ float m2p[128 * 9];          // padded M2
    __shared__ float xbuf[8 * 4 * 129];     // wave x group x (128 + pad)
    int tid = threadIdx.x;
    for (int i = tid; i < 16384; i += 512) w2s[i] = f2bf(W2[i]);
    for (int i = tid; i < 1024; i += 512) m2p[(i >> 3) * 9 + (i & 7)] = m2g[i];
    __syncthreads();

    int lane = tid & 63;
    int grp = lane >> 4;
    int gl = lane & 15;
    int wbase = lane & 48;
    int wv = tid >> 6;
    float* xb = &xbuf[(wv * 4 + grp) * 129];
    int gw = (blockIdx.x * blockDim.x + tid) >> 6;
    int waves = (gridDim.x * blockDim.x) >> 6;

    float4 tb0 = ((const float4*)tsb)[gl*2];
    float4 tb1 = ((const float4*)tsb)[gl*2+1];
    float cc0 = attfix[0] + attfix[4];
    float cc1 = attfix[1] + attfix[5];
    float cc2 = attfix[2] + attfix[6];
    float cc3 = attfix[3] + attfix[7];

    for (int m = gw; m * 4 < N; m += waves) {
        int n = m * 4 + grp;
        bool nv = n < N;
        int beg = nv ? rowptr[n] : 0;
        int end = nv ? rowptr[n + 1] : 0;
        float4 ad = {0,0,0,0};
        if (nv) ad = ((const float4*)adst)[n];
        ad.x += cc0; ad.y += cc1; ad.z += cc2; ad.w += cc3;

        int e0 = beg + gl;
        bool v0 = e0 < end;
        int s0 = v0 ? esrc[e0] : 0;
        float4 a0 = ((const float4*)asrc)[s0];
        float x0 = v0 ? fexp(lrelu02(a0.x + ad.x)) : 0.f;
        float x1 = v0 ? fexp(lrelu02(a0.y + ad.y)) : 0.f;
        float x2 = v0 ? fexp(lrelu02(a0.z + ad.z)) : 0.f;
        float x3 = v0 ? fexp(lrelu02(a0.w + ad.w)) : 0.f;
        float d0 = x0, d1 = x1, d2 = x2, d3 = x3;
        for (int c = beg + 16; c < end; c += 16) {
            int e = c + gl;
            bool v = e < end;
            int s = v ? esrc[e] : 0;
            float4 a = ((const float4*)asrc)[s];
            if (v) {
                d0 += fexp(lrelu02(a.x + ad.x));
                d1 += fexp(lrelu02(a.y + ad.y));
                d2 += fexp(lrelu02(a.z + ad.z));
                d3 += fexp(lrelu02(a.w + ad.w));
            }
        }
#pragma unroll
        for (int off = 8; off; off >>= 1) {
            d0 += __shfl_xor(d0, off, 64);
            d1 += __shfl_xor(d1, off, 64);
            d2 += __shfl_xor(d2, off, 64);
            d3 += __shfl_xor(d3, off, 64);
        }
        float r0 = __builtin_amdgcn_rcpf(d0 + 2e-9f);
        float r1 = __builtin_amdgcn_rcpf(d1 + 2e-9f);
        float r2 = __builtin_amdgcn_rcpf(d2 + 2e-9f);
        float r3 = __builtin_amdgcn_rcpf(d3 + 2e-9f);

        float csum = d0*r0 + d1*r1 + d2*r2 + d3*r3;
        float4 acc0, acc1;
        acc0.x = csum*tb0.x; acc0.y = csum*tb0.y; acc0.z = csum*tb0.z; acc0.w = csum*tb0.w;
        acc1.x = csum*tb1.x; acc1.y = csum*tb1.y; acc1.z = csum*tb1.z; acc1.w = csum*tb1.w;

        float coef = x0*r0 + x1*r1 + x2*r2 + x3*r3;
#pragma unroll 4
        for (int jj = 0; jj < 16; ++jj) {
            float cj = __shfl(coef, wbase + jj, 64);
            if (cj > 0.f) {
                int sj = __shfl(s0, wbase + jj, 64);
                uint4 w = ((const uint4*)(Wx + (size_t)sj * 128))[gl];
                float4 lo, hi; unpack8(w, lo, hi);
                acc0.x = fmaf(cj, lo.x, acc0.x); acc0.y = fmaf(cj, lo.y, acc0.y);
                acc0.z = fmaf(cj, lo.z, acc0.z); acc0.w = fmaf(cj, lo.w, acc0.w);
                acc1.x = fmaf(cj, hi.x, acc1.x); acc1.y = fmaf(cj, hi.y, acc1.y);
                acc1.z = fmaf(cj, hi.z, acc1.z); acc1.w = fmaf(cj, hi.w, acc1.w);
            }
        }
        for (int c = beg + 16; c < end; c += 16) {
            int e = c + gl;
            bool v = e < end;
            int s = v ? esrc[e] : 0;
            float4 a = ((const float4*)asrc)[s];
            float cf = 0.f;
            if (v) {
                cf = fexp(lrelu02(a.x + ad.x)) * r0
                   + fexp(lrelu02(a.y + ad.y)) * r1
                   + fexp(lrelu02(a.z + ad.z)) * r2
                   + fexp(lrelu02(a.w + ad.w)) * r3;
            }
#pragma unroll 4
            for (int jj = 0; jj < 16; ++jj) {
                float cj = __shfl(cf, wbase + jj, 64);
                if (cj > 0.f) {
                    int sj = __shfl(s, wbase + jj, 64);
                    uint4 w = ((const uint4*)(Wx + (size_t)sj * 128))[gl];
                    float4 lo, hi; unpack8(w, lo, hi);
                    acc0.x = fmaf(cj, lo.x, acc0.x); acc0.y = fmaf(cj, lo.y, acc0.y);
                    acc0.z = fmaf(cj, lo.z, acc0.z); acc0.w = fmaf(cj, lo.w, acc0.w);
                    acc1.x = fmaf(cj, hi.x, acc1.x); acc1.y = fmaf(cj, hi.y, acc1.y);
                    acc1.z = fmaf(cj, hi.z, acc1.z); acc1.w = fmaf(cj, hi.w, acc1.w);
                }
            }
        }
        // x1 = elu(acc/4)
        acc0.x *= 0.25f; acc0.y *= 0.25f; acc0.z *= 0.25f; acc0.w *= 0.25f;
        acc1.x *= 0.25f; acc1.y *= 0.25f; acc1.z *= 0.25f; acc1.w *= 0.25f;
        acc0.x = acc0.x > 0.f ? acc0.x : expm1f(acc0.x);
        acc0.y = acc0.y > 0.f ? acc0.y : expm1f(acc0.y);
        acc0.z = acc0.z > 0.f ? acc0.z : expm1f(acc0.z);
        acc0.w = acc0.w > 0.f ? acc0.w : expm1f(acc0.w);
        acc1.x = acc1.x > 0.f ? acc1.x : expm1f(acc1.x);
        acc1.y = acc1.y > 0.f ? acc1.y : expm1f(acc1.y);
        acc1.z = acc1.z > 0.f ? acc1.z : expm1f(acc1.z);
        acc1.w = acc1.w > 0.f ? acc1.w : expm1f(acc1.w);

        // broadcast x1 row via LDS (wave-synchronous)
        xb[gl*8+0] = acc0.x; xb[gl*8+1] = acc0.y; xb[gl*8+2] = acc0.z; xb[gl*8+3] = acc0.w;
        xb[gl*8+4] = acc1.x; xb[gl*8+5] = acc1.y; xb[gl*8+6] = acc1.z; xb[gl*8+7] = acc1.w;

        // Wx2[n][8gl..8gl+8) = sum_k x1[k] * W2[k][c]
        float4 wa0 = {0,0,0,0}, wa1 = {0,0,0,0};
        for (int k = 0; k < 128; ++k) {
            float xk = xb[k];
            uint4 w = *(const uint4*)&w2s[k * 128 + 8 * gl];
            float4 lo, hi; unpack8(w, lo, hi);
            wa0.x = fmaf(xk, lo.x, wa0.x); wa0.y = fmaf(xk, lo.y, wa0.y);
            wa0.z = fmaf(xk, lo.z, wa0.z); wa0.w = fmaf(xk, lo.w, wa0.w);
            wa1.x = fmaf(xk, hi.x, wa1.x); wa1.y = fmaf(xk, hi.y, wa1.y);
            wa1.z = fmaf(xk, hi.z, wa1.z); wa1.w = fmaf(xk, hi.w, wa1.w);
        }
        // att2 partials over own k-range (x values are in regs)
        float aacc[8] = {0,0,0,0,0,0,0,0};
        float xo[8] = {acc0.x,acc0.y,acc0.z,acc0.w, acc1.x,acc1.y,acc1.z,acc1.w};
#pragma unroll
        for (int kk = 0; kk < 8; ++kk) {
            const float* mrow = &m2p[(8 * gl + kk) * 9];
            float xv = xo[kk];
#pragma unroll
            for (int h = 0; h < 8; ++h) aacc[h] = fmaf(xv, mrow[h], aacc[h]);
        }
#pragma unroll
        for (int off = 8; off; off >>= 1) {
#pragma unroll
            for (int h = 0; h < 8; ++h) aacc[h] += __shfl_xor(aacc[h], off, 64);
        }
        if (nv) {
            unsigned short* wrow = Wx2 + (size_t)n * 128 + 8 * gl;
            uint4 o;
            o.x = (unsigned)f2bf(wa0.x) | ((unsigned)f2bf(wa0.y) << 16);
            o.y = (unsigned)f2bf(wa0.z) | ((unsigned)f2bf(wa0.w) << 16);
            o.z = (unsigned)f2bf(wa1.x) | ((unsigned)f2bf(wa1.y) << 16);
            o.w = (unsigned)f2bf(wa1.z) | ((unsigned)f2bf(wa1.w) << 16);
            *(uint4*)wrow = o;
            if (gl == 0) {
                float4 o1; o1.x = aacc[0]; o1.y = aacc[1]; o1.z = aacc[2]; o1.w = aacc[3];
                float4 o2; o2.x = aacc[4]; o2.y = aacc[5]; o2.z = aacc[6]; o2.w = aacc[7];
                ((float4*)asrc2)[n] = o1;
                ((float4*)adst2)[n] = o2;
            }
        }
    }
}

// ---------------------------------------------------------------------------
// Fused GAT layer-2 aggregate + FC head. Writes only out[N].
// ---------------------------------------------------------------------------
__global__ __launch_bounds__(512) void k_msg0(
    const int* __restrict__ rowptr, const int* __restrict__ esrc,
    const float* __restrict__ asrc, const float* __restrict__ adst,
    const unsigned short* __restrict__ Wx,
    const float* __restrict__ fc1w, const float* __restrict__ fc1b,
    const float* __restrict__ fc2w, const float* __restrict__ fc2b,
    float* __restrict__ out, int N)
{
    __shared__ float fc1s[8192];            // 32KB: fc1w [c][j]
    __shared__ float xbuf[8 * 4 * 129];
    int tid = threadIdx.x;
    for (int i = tid; i < 8192; i += 512) fc1s[i] = fc1w[i];
    __syncthreads();

    int lane = tid & 63;
    int grp = lane >> 4;
    int gl = lane & 15;
    int wbase = lane & 48;
    int wv = tid >> 6;
    float* xb = &xbuf[(wv * 4 + grp) * 129];
    int gw = (blockIdx.x * blockDim.x + tid) >> 6;
    int waves = (gridDim.x * blockDim.x) >> 6;

    float4 b1v = *(const float4*)&fc1b[4 * gl];
    float4 w2v = *(const float4*)&fc2w[4 * gl];
    float b2 = fc2b[0];

    for (int m = gw; m * 4 < N; m += waves) {
        int n = m * 4 + grp;
        bool nv = n < N;
        int beg = nv ? rowptr[n] : 0;
        int end = nv ? rowptr[n + 1] : 0;
        float4 ad = {0,0,0,0};
        if (nv) ad = ((const float4*)adst)[n];

        int e0 = beg + gl;
        bool v0 = e0 < end;
        int s0 = v0 ? esrc[e0] : 0;
        float4 a0 = ((const float4*)asrc)[s0];
        float x0 = v0 ? fexp(lrelu02(a0.x + ad.x)) : 0.f;
        float x1 = v0 ? fexp(lrelu02(a0.y + ad.y)) : 0.f;
        float x2 = v0 ? fexp(lrelu02(a0.z + ad.z)) : 0.f;
        float x3 = v0 ? fexp(lrelu02(a0.w + ad.w)) : 0.f;
        float d0 = x0, d1 = x1, d2 = x2, d3 = x3;
        for (int c = beg + 16; c < end; c += 16) {
            int e = c + gl;
            bool v = e < end;
            int s = v ? esrc[e] : 0;
            float4 a = ((const float4*)asrc)[s];
            if (v) {
                d0 += fexp(lrelu02(a.x + ad.x));
                d1 += fexp(lrelu02(a.y + ad.y));
                d2 += fexp(lrelu02(a.z + ad.z));
                d3 += fexp(lrelu02(a.w + ad.w));
            }
        }
#pragma unroll
        for (int off = 8; off; off >>= 1) {
            d0 += __shfl_xor(d0, off, 64);
            d1 += __shfl_xor(d1, off, 64);
            d2 += __shfl_xor(d2, off, 64);
            d3 += __shfl_xor(d3, off, 64);
        }
        float r0 = __builtin_amdgcn_rcpf(d0 + 2e-9f);
        float r1 = __builtin_amdgcn_rcpf(d1 + 2e-9f);
        float r2 = __builtin_amdgcn_rcpf(d2 + 2e-9f);
        float r3 = __builtin_amdgcn_rcpf(d3 + 2e-9f);

        float4 acc0 = {0,0,0,0}, acc1 = {0,0,0,0};
        float coef = x0*r0 + x1*r1 + x2*r2 + x3*r3;
#pragma unroll 4
        for (int jj = 0; jj < 16; ++jj) {
            float cj = __shfl(coef, wbase + jj, 64);
            if (cj > 0.f) {
                int sj = __shfl(s0, wbase + jj, 64);
                uint4 w = ((const uint4*)(Wx + (size_t)sj * 128))[gl];
                float4 lo, hi; unpack8(w, lo, hi);
                acc0.x = fmaf(cj, lo.x, acc0.x); acc0.y = fmaf(cj, lo.y, acc0.y);
                acc0.z = fmaf(cj, lo.z, acc0.z); acc0.w = fmaf(cj, lo.w, acc0.w);
                acc1.x = fmaf(cj, hi.x, acc1.x); acc1.y = fmaf(cj, hi.y, acc1.y);
                acc1.z = fmaf(cj, hi.z, acc1.z); acc1.w = fmaf(cj, hi.w, acc1.w);
            }
        }
        for (int c = beg + 16; c < end; c += 16) {
            int e = c + gl;
            bool v = e < end;
            int s = v ? esrc[e] : 0;
            float4 a = ((const float4*)asrc)[s];
            float cf = 0.f;
            if (v) {
                cf = fexp(lrelu02(a.x + ad.x)) * r0
                   + fexp(lrelu02(a.y + ad.y)) * r1
                   + fexp(lrelu02(a.z + ad.z)) * r2
                   + fexp(lrelu02(a.w + ad.w)) * r3;
            }
#pragma unroll 4
            for (int jj = 0; jj < 16; ++jj) {
                float cj = __shfl(cf, wbase + jj, 64);
                if (cj > 0.f) {
                    int sj = __shfl(s, wbase + jj, 64);
                    uint4 w = ((const uint4*)(Wx + (size_t)sj * 128))[gl];
                    float4 lo, hi; unpack8(w, lo, hi);
                    acc0.x = fmaf(cj, lo.x, acc0.x); acc0.y = fmaf(cj, lo.y, acc0.y);
                    acc0.z = fmaf(cj, lo.z, acc0.z); acc0.w = fmaf(cj, lo.w, acc0.w);
                    acc1.x = fmaf(cj, hi.x, acc1.x); acc1.y = fmaf(cj, hi.y, acc1.y);
                    acc1.z = fmaf(cj, hi.z, acc1.z); acc1.w = fmaf(cj, hi.w, acc1.w);
                }
            }
        }
        // x = elu(acc/4); broadcast via LDS; h = relu(x@fc1 + b1); out = h@fc2 + b2
        acc0.x *= 0.25f; acc0.y *= 0.25f; acc0.z *= 0.25f; acc0.w *= 0.25f;
        acc1.x *= 0.25f; acc1.y *= 0.25f; acc1.z *= 0.25f; acc1.w *= 0.25f;
        acc0.x = acc0.x > 0.f ? acc0.x : expm1f(acc0.x);
        acc0.y = acc0.y > 0.f ? acc0.y : expm1f(acc0.y);
        acc0.z = acc0.z > 0.f ? acc0.z : expm1f(acc0.z);
        acc0.w = acc0.w > 0.f ? acc0.w : expm1f(acc0.w);
        acc1.x = acc1.x > 0.f ? acc1.x : expm1f(acc1.x);
        acc1.y = acc1.y > 0.f ? acc1.y : expm1f(acc1.y);
        acc1.z = acc1.z > 0.f ? acc1.z : expm1f(acc1.z);
        acc1.w = acc1.w > 0.f ? acc1.w : expm1f(acc1.w);
        xb[gl*8+0] = acc0.x; xb[gl*8+1] = acc0.y; xb[gl*8+2] = acc0.z; xb[gl*8+3] = acc0.w;
        xb[gl*8+4] = acc1.x; xb[gl*8+5] = acc1.y; xb[gl*8+6] = acc1.z; xb[gl*8+7] = acc1.w;

        float4 hacc = b1v;
        for (int k = 0; k < 128; ++k) {
            float xk = xb[k];
            float4 w = *(const float4*)&fc1s[k * 64 + 4 * gl];
            hacc.x = fmaf(xk, w.x, hacc.x); hacc.y = fmaf(xk, w.y, hacc.y);
            hacc.z = fmaf(xk, w.z, hacc.z); hacc.w = fmaf(xk, w.w, hacc.w);
        }
        float r = fmaxf(hacc.x, 0.f) * w2v.x + fmaxf(hacc.y, 0.f) * w2v.y
                + fmaxf(hacc.z, 0.f) * w2v.z + fmaxf(hacc.w, 0.f) * w2v.w;
#pragma unroll
        for (int off = 8; off; off >>= 1) r += __shfl_xor(r, off, 64);
        if (nv && gl == 0) out[n] = r + b2;
    }
}

extern "C" void kernel_launch(void* const* d_in, const int* in_sizes, int n_in,
                              void* d_out, int out_size, void* d_ws, size_t ws_size,
                              hipStream_t stream)
{
    const float* nf   = (const float*)d_in[0];
    const int*   ei   = (const int*)  d_in[1];
    const float* ts   = (const float*)d_in[2];
    const float* Wih0 = (const float*)d_in[3];
    const float* Whh0 = (const float*)d_in[4];
    const float* b0   = (const float*)d_in[5];
    const float* Wih1 = (const float*)d_in[6];
    const float* Whh1 = (const float*)d_in[7];
    const float* b1   = (const float*)d_in[8];
    const float* W1   = (const float*)d_in[9];
    const float* A1   = (const float*)d_in[10];
    const float* W2   = (const float*)d_in[11];
    const float* A2   = (const float*)d_in[12];
    const float* fc1w = (const float*)d_in[13];
    const float* fc1b = (const float*)d_in[14];
    const float* fc2w = (const float*)d_in[15];
    const float* fc2b = (const float*)d_in[16];

    int N = in_sizes[0] / 16;
    int E = in_sizes[1] / 2;
    int T = in_sizes[2] / 3;

    char* ws = (char*)d_ws;
    size_t off = 0;
    auto alloc = [&](size_t bytes) {
        char* p = ws + off;
        off = (off + bytes + 255) & ~(size_t)255;
        return p;
    };
    float* tsb    = (float*)alloc(512);
    float* attfix = (float*)alloc(64);
    int*   flags  = (int*)  alloc(64);
    float* m2g    = (float*)alloc(1024 * sizeof(float));
    float* asrc   = (float*)alloc((size_t)N * 4 * sizeof(float));
    float* adst   = (float*)alloc((size_t)N * 4 * sizeof(float));
    float* asrc2  = (float*)alloc((size_t)N * 4 * sizeof(float));
    float* adst2  = (float*)alloc((size_t)N * 4 * sizeof(float));
    int*   rowptr = (int*)  alloc((size_t)(N + 1) * sizeof(int));
    int*   esrc   = (int*)  alloc((size_t)E * sizeof(int));
    int*   epos   = (int*)  alloc((size_t)E * sizeof(int));
    int*   deg    = (int*)  alloc((size_t)N * sizeof(int));
    int*   bsum   = (int*)  alloc(512 * sizeof(int));
    unsigned short* bufA = (unsigned short*)alloc((size_t)N * 128 * sizeof(unsigned short));
    unsigned short* bufC = (unsigned short*)alloc((size_t)N * 128 * sizeof(unsigned short));

    int NCH = (N + 2047) / 2048;

    hipMemsetAsync(deg, 0, (size_t)N * sizeof(int), stream);
    hipMemsetAsync(flags, 0, 64, stream);

    // ---- mega-front: LSTM || (hist -> scan -> scatter) || att1P || Wxp(bf16) || M2 ----
    k_front<<<256, 512, 0, stream>>>(
        ts, Wih0, Whh0, b0, Wih1, Whh1, b1, W1, A1, W2, A2,
        tsb, attfix, m2g,
        ei, deg, epos, nf, bufA, asrc, adst,
        rowptr, bsum, esrc, flags,
        N, E, T, NCH);

    // ---- layer-1 aggregate + layer-2 projections (fused) ----
    k_msg1<<<512, 512, 0, stream>>>(rowptr, esrc, asrc, adst, bufA, tsb, attfix,
                                    W2, m2g, bufC, asrc2, adst2, N);

    // ---- layer-2 aggregate + FC head (fused) ----
    k_msg0<<<768, 512, 0, stream>>>(rowptr, esrc, asrc2, adst2, bufC,
                                    fc1w, fc1b, fc2w, fc2b, (float*)d_out, N);
}

// Round 11
// 559.228 us; speedup vs baseline: 1.7936x; 1.1891x over previous
//
#include <hip/hip_runtime.h>
#include <math.h>

#define DEV __device__ __forceinline__

#define LOG2E 1.4426950408889634f

DEV float fexp(float x)  { return __builtin_amdgcn_exp2f(LOG2E * x); }
DEV float fsigm(float x) { return __builtin_amdgcn_rcpf(1.0f + __builtin_amdgcn_exp2f(-LOG2E * x)); }
DEV float ftanh(float x) { return 1.0f - 2.0f * __builtin_amdgcn_rcpf(__builtin_amdgcn_exp2f(2.0f * LOG2E * x) + 1.0f); }
DEV float lrelu02(float x) { return x > 0.0f ? x : 0.2f * x; }
DEV int aload(const int* p) {
    return __hip_atomic_load(p, __ATOMIC_RELAXED, __HIP_MEMORY_SCOPE_AGENT);
}
DEV void astore(int* p, int v) {
    __hip_atomic_store(p, v, __ATOMIC_RELAXED, __HIP_MEMORY_SCOPE_AGENT);
}
DEV unsigned short f2bf(float f) {
    unsigned u = __float_as_uint(f);
    return (unsigned short)((u + 0x7FFFu + ((u >> 16) & 1u)) >> 16);
}
DEV void unpack8(uint4 w, float4& lo, float4& hi) {
    lo.x = __uint_as_float(w.x << 16); lo.y = __uint_as_float(w.x & 0xFFFF0000u);
    lo.z = __uint_as_float(w.y << 16); lo.w = __uint_as_float(w.y & 0xFFFF0000u);
    hi.x = __uint_as_float(w.z << 16); hi.y = __uint_as_float(w.z & 0xFFFF0000u);
    hi.z = __uint_as_float(w.w << 16); hi.w = __uint_as_float(w.w & 0xFFFF0000u);
}
#define QB(v, ctrl) __int_as_float(__builtin_amdgcn_mov_dpp(__float_as_int(v), ctrl, 0xF, 0xF, true))

// ---------------------------------------------------------------------------
// Mega-front (unchanged from r10): LSTM (block 0) || hist->scan->scatter ||
// att1P || Wxp(bf16) || M2. 84KB LDS pad -> 1 block/CU, all co-resident.
// ---------------------------------------------------------------------------
__global__ __launch_bounds__(512) void k_front(
    const float* __restrict__ ts,
    const float* __restrict__ Wih0, const float* __restrict__ Whh0, const float* __restrict__ b0,
    const float* __restrict__ Wih1, const float* __restrict__ Whh1, const float* __restrict__ b1,
    const float* __restrict__ W1, const float* __restrict__ A1,
    const float* __restrict__ W2, const float* __restrict__ A2,
    float* __restrict__ tsb, float* __restrict__ attfix, float* __restrict__ m2g,
    const int* __restrict__ ei, int* __restrict__ deg, int* __restrict__ epos,
    const float* __restrict__ nf, unsigned short* __restrict__ Wxp,
    float* __restrict__ asrcP, float* __restrict__ adstP,
    int* __restrict__ rowptr, int* __restrict__ bsum,
    int* __restrict__ esrc, int* __restrict__ flags,
    int N, int E, int T, int NCH)
{
    __shared__ __align__(16) float h0b[2][64], h1b[2][64];
    __shared__ __align__(16) float tsbig[21504];   // 84KB pad -> 1 block/CU
    __shared__ float m1s[128];
    __shared__ int iwsum[8];
    __shared__ int stmp[512];
    const int tid = threadIdx.x;
    const int bid = blockIdx.x;

    auto signalflag = [&](int* f) {
        __syncthreads();
        if (tid == 0) {
            __threadfence();
            __hip_atomic_fetch_add(f, 1, __ATOMIC_RELEASE, __HIP_MEMORY_SCOPE_AGENT);
        }
    };
    auto waitflag = [&](int* f, int tgt) {
        if (tid == 0) {
            while (__hip_atomic_load(f, __ATOMIC_ACQUIRE, __HIP_MEMORY_SCOPE_AGENT) < tgt)
                __builtin_amdgcn_s_sleep(8);
        }
        __syncthreads();
    };

    if (bid == 0) {
        // ================= LSTM =================
        const int seg = tid >> 8;
        const int idx = tid & 255;
        const int u = idx >> 2;
        const int q = idx & 3;
        const int row = q * 64 + u;
        float* tss = tsbig;

        float wa[64], wb[64], wih[3], bias;
        if (seg == 0) {
            bias = b0[row];
            wih[0] = Wih0[row*3+0]; wih[1] = Wih0[row*3+1]; wih[2] = Wih0[row*3+2];
#pragma unroll
            for (int k = 0; k < 64; k++) wa[k] = Whh0[row * 64 + k];
#pragma unroll
            for (int k = 0; k < 64; k++) wb[k] = 0.0f;
        } else {
            bias = b1[row];
            wih[0] = wih[1] = wih[2] = 0.f;
#pragma unroll
            for (int k = 0; k < 64; k++) wa[k] = Whh1[row * 64 + k];
#pragma unroll
            for (int k = 0; k < 64; k++) wb[k] = Wih1[row * 64 + k];
        }
        for (int i = tid; i < 3 * T && i < 512; i += 512) tss[i] = ts[i];
        if (tid < 64) {
            h0b[0][tid] = 0.f; h0b[1][tid] = 0.f;
            h1b[0][tid] = 0.f; h1b[1][tid] = 0.f;
        }
        float creg = 0.0f;
        __syncthreads();

        for (int k = 0; k <= T; ++k) {
            if (seg == 0) {
                if (k < T) {
                    const float* hprev = h0b[(k + 1) & 1];
                    float a0 = bias, a1 = 0.f, a2 = 0.f, a3 = 0.f;
                    a0 = fmaf(tss[3*k+0], wih[0], a0);
                    a1 = fmaf(tss[3*k+1], wih[1], a1);
                    a2 = fmaf(tss[3*k+2], wih[2], a2);
#pragma unroll
                    for (int p = 0; p < 64; p += 16) {
                        float4 u0 = *(const float4*)&hprev[p];
                        float4 u1 = *(const float4*)&hprev[p+4];
                        float4 u2 = *(const float4*)&hprev[p+8];
                        float4 u3 = *(const float4*)&hprev[p+12];
                        a0 = fmaf(u0.x, wa[p+0],  a0); a0 = fmaf(u0.y, wa[p+1],  a0);
                        a0 = fmaf(u0.z, wa[p+2],  a0); a0 = fmaf(u0.w, wa[p+3],  a0);
                        a1 = fmaf(u1.x, wa[p+4],  a1); a1 = fmaf(u1.y, wa[p+5],  a1);
                        a1 = fmaf(u1.z, wa[p+6],  a1); a1 = fmaf(u1.w, wa[p+7],  a1);
                        a2 = fmaf(u2.x, wa[p+8],  a2); a2 = fmaf(u2.y, wa[p+9],  a2);
                        a2 = fmaf(u2.z, wa[p+10], a2); a2 = fmaf(u2.w, wa[p+11], a2);
                        a3 = fmaf(u3.x, wa[p+12], a3); a3 = fmaf(u3.y, wa[p+13], a3);
                        a3 = fmaf(u3.z, wa[p+14], a3); a3 = fmaf(u3.w, wa[p+15], a3);
                    }
                    float mine = (a0 + a1) + (a2 + a3);
                    float gi = QB(mine, 0x00);
                    float gf = QB(mine, 0x55);
                    float gg = QB(mine, 0xAA);
                    float go = QB(mine, 0xFF);
                    creg = fsigm(gf) * creg + fsigm(gi) * ftanh(gg);
                    float h = fsigm(go) * ftanh(creg);
                    if (q == 0) h0b[k & 1][u] = h;
                }
            } else {
                if (k >= 1) {
                    const float* h1prev = h1b[k & 1];
                    const float* h0in   = h0b[(k + 1) & 1];
                    float a0 = bias, a1 = 0.f, a2 = 0.f, a3 = 0.f;
#pragma unroll
                    for (int p = 0; p < 64; p += 8) {
                        float4 u0 = *(const float4*)&h1prev[p];
                        float4 u1 = *(const float4*)&h1prev[p+4];
                        a0 = fmaf(u0.x, wa[p+0], a0); a0 = fmaf(u0.y, wa[p+1], a0);
                        a0 = fmaf(u0.z, wa[p+2], a0); a0 = fmaf(u0.w, wa[p+3], a0);
                        a1 = fmaf(u1.x, wa[p+4], a1); a1 = fmaf(u1.y, wa[p+5], a1);
                        a1 = fmaf(u1.z, wa[p+6], a1); a1 = fmaf(u1.w, wa[p+7], a1);
                        float4 v0 = *(const float4*)&h0in[p];
                        float4 v1 = *(const float4*)&h0in[p+4];
                        a2 = fmaf(v0.x, wb[p+0], a2); a2 = fmaf(v0.y, wb[p+1], a2);
                        a2 = fmaf(v0.z, wb[p+2], a2); a2 = fmaf(v0.w, wb[p+3], a2);
                        a3 = fmaf(v1.x, wb[p+4], a3); a3 = fmaf(v1.y, wb[p+5], a3);
                        a3 = fmaf(v1.z, wb[p+6], a3); a3 = fmaf(v1.w, wb[p+7], a3);
                    }
                    float mine = (a0 + a1) + (a2 + a3);
                    float gi = QB(mine, 0x00);
                    float gf = QB(mine, 0x55);
                    float gg = QB(mine, 0xAA);
                    float go = QB(mine, 0xFF);
                    creg = fsigm(gf) * creg + fsigm(gi) * ftanh(gg);
                    float h = fsigm(go) * ftanh(creg);
                    if (q == 0) h1b[(k + 1) & 1][u] = h;
                }
            }
            __syncthreads();
        }
        if (tid < 128) {
            const float* hf = h1b[(T - 1) & 1];
            float acc = 0.f;
#pragma unroll
            for (int kk = 0; kk < 64; kk++)
                acc = fmaf(hf[kk], W1[(16 + kk) * 128 + tid], acc);
            tsb[tid] = acc;
            m1s[tid] = acc;
        }
        __syncthreads();
        if (tid < 8) {
            int half = tid >> 2, h = tid & 3;
            const float* a1p = A1 + (size_t)half * 512 + h;
            float acc = 0.f;
            for (int c = 0; c < 128; c++) acc = fmaf(m1s[c], a1p[c * 4], acc);
            attfix[tid] = acc;
        }
        return;
    }

    // ================= workers =================
    const int W = gridDim.x - 1;
    const int wid = bid - 1;

    {
        int g = wid * 512 + tid, stride = W * 512;
        for (int e = g; e < E; e += stride)
            epos[e] = atomicAdd(&deg[ei[E + e]], 1);
    }
    signalflag(&flags[0]);

    if (wid < NCH) {
        waitflag(&flags[0], W);
        int base = wid * 2048 + tid * 4;
        int d0 = base + 0 < N ? aload(&deg[base + 0]) : 0;
        int d1 = base + 1 < N ? aload(&deg[base + 1]) : 0;
        int d2 = base + 2 < N ? aload(&deg[base + 2]) : 0;
        int d3 = base + 3 < N ? aload(&deg[base + 3]) : 0;
        int tsum = d0 + d1 + d2 + d3;
        int lane = tid & 63, wv = tid >> 6;
        int incl = tsum;
#pragma unroll
        for (int off = 1; off < 64; off <<= 1) {
            int t = __shfl_up(incl, off, 64);
            if (lane >= off) incl += t;
        }
        if (lane == 63) iwsum[wv] = incl;
        __syncthreads();
        int woff = 0;
#pragma unroll
        for (int w = 0; w < 8; w++) if (w < wv) woff += iwsum[w];
        int tex = woff + incl - tsum;
        if (base + 0 < N) rowptr[base + 0] = tex;
        if (base + 1 < N) rowptr[base + 1] = tex + d0;
        if (base + 2 < N) rowptr[base + 2] = tex + d0 + d1;
        if (base + 3 < N) rowptr[base + 3] = tex + d0 + d1 + d2;
        if (tid == 511) astore(&bsum[wid], woff + incl);
        signalflag(&flags[1]);
        waitflag(&flags[2], 1);
        int off2 = aload(&bsum[wid]);
#pragma unroll
        for (int i = 0; i < 4; i++) {
            int idx = base + i;
            if (idx < N) {
                int v = rowptr[idx] + off2;
                astore(&rowptr[idx], v);
            }
        }
        if (wid == 0 && tid == 0) astore(&rowptr[N], E);
        signalflag(&flags[3]);
    } else if (wid == NCH) {
        waitflag(&flags[1], NCH);
        int v = tid < NCH ? aload(&bsum[tid]) : 0;
        stmp[tid] = v;
        __syncthreads();
        for (int off = 1; off < 512; off <<= 1) {
            int t = (tid >= off) ? stmp[tid - off] : 0;
            __syncthreads();
            stmp[tid] += t;
            __syncthreads();
        }
        if (tid < NCH) astore(&bsum[tid], stmp[tid] - v);
        signalflag(&flags[2]);
        // ---- compute M2 = W2@A2 (128 x 8) while LSTM still runs ----
#pragma unroll
        for (int e = tid; e < 1024; e += 512) {
            int k = e >> 3, h8 = e & 7, half = h8 >> 2, h = h8 & 3;
            const float* w2p = W2 + (size_t)k * 128;
            const float* a2p = A2 + (size_t)half * 512 + h;
            float acc = 0.f;
            for (int c = 0; c < 128; c++) acc = fmaf(w2p[c], a2p[c * 4], acc);
            m2g[e] = acc;
        }
    } else {
        const int AW = W - NCH - 1;
        const int aw = wid - NCH - 1;
        if (tid < 128) {
            int k = tid >> 3, h8 = tid & 7, half = h8 >> 2, h = h8 & 3;
            const float* a1p = A1 + (size_t)half * 512 + h;
            const float* w1p = W1 + (size_t)k * 128;
            float acc = 0.f;
            for (int c = 0; c < 128; c++) acc = fmaf(w1p[c], a1p[c * 4], acc);
            m1s[tid] = acc;
        }
        __syncthreads();
        float m1r[128];
#pragma unroll
        for (int i = 0; i < 128; i++) m1r[i] = m1s[i];
        {
            int gt = aw * 512 + tid;
            int tstride = AW * 512;
            for (int n = gt; n < N; n += tstride) {
                const float4* nfr = (const float4*)(nf + (size_t)n * 16);
                float4 f0 = nfr[0], f1 = nfr[1], f2 = nfr[2], f3 = nfr[3];
                float xk[16] = {f0.x,f0.y,f0.z,f0.w, f1.x,f1.y,f1.z,f1.w,
                                f2.x,f2.y,f2.z,f2.w, f3.x,f3.y,f3.z,f3.w};
                float as0=0,as1=0,as2=0,as3=0, ad0=0,ad1=0,ad2=0,ad3=0;
#pragma unroll
                for (int k = 0; k < 16; k++) {
                    float xv = xk[k];
                    as0 = fmaf(xv, m1r[k*8+0], as0); as1 = fmaf(xv, m1r[k*8+1], as1);
                    as2 = fmaf(xv, m1r[k*8+2], as2); as3 = fmaf(xv, m1r[k*8+3], as3);
                    ad0 = fmaf(xv, m1r[k*8+4], ad0); ad1 = fmaf(xv, m1r[k*8+5], ad1);
                    ad2 = fmaf(xv, m1r[k*8+6], ad2); ad3 = fmaf(xv, m1r[k*8+7], ad3);
                }
                float4 o1; o1.x=as0; o1.y=as1; o1.z=as2; o1.w=as3;
                float4 o2; o2.x=ad0; o2.y=ad1; o2.z=ad2; o2.w=ad3;
                ((float4*)asrcP)[n] = o1;
                ((float4*)adstP)[n] = o2;
            }
        }
        {
            int lane = tid & 63;
            int bw = aw * 8 + (tid >> 6);
            int half = bw & 1;
            int col = lane + 64 * half;
            float wreg[16];
#pragma unroll
            for (int k = 0; k < 16; k++) wreg[k] = W1[k * 128 + col];
            int nstride = AW * 4;
            for (int n = (bw >> 1); n < N; n += nstride) {
                int nu = __builtin_amdgcn_readfirstlane(n);
                const float4* xr = (const float4*)(nf + (size_t)nu * 16);
                float4 x0 = xr[0], x1 = xr[1], x2 = xr[2], x3 = xr[3];
                float acc = 0.f;
                acc = fmaf(x0.x, wreg[0],  acc); acc = fmaf(x0.y, wreg[1],  acc);
                acc = fmaf(x0.z, wreg[2],  acc); acc = fmaf(x0.w, wreg[3],  acc);
                acc = fmaf(x1.x, wreg[4],  acc); acc = fmaf(x1.y, wreg[5],  acc);
                acc = fmaf(x1.z, wreg[6],  acc); acc = fmaf(x1.w, wreg[7],  acc);
                acc = fmaf(x2.x, wreg[8],  acc); acc = fmaf(x2.y, wreg[9],  acc);
                acc = fmaf(x2.z, wreg[10], acc); acc = fmaf(x2.w, wreg[11], acc);
                acc = fmaf(x3.x, wreg[12], acc); acc = fmaf(x3.y, wreg[13], acc);
                acc = fmaf(x3.z, wreg[14], acc); acc = fmaf(x3.w, wreg[15], acc);
                Wxp[(size_t)nu * 128 + col] = f2bf(acc);
            }
        }
    }

    waitflag(&flags[3], NCH);
    {
        int g = wid * 512 + tid, stride = W * 512;
        for (int e = g; e < E; e += stride) {
            int s = ei[e], d = ei[E + e];
            esrc[aload(&rowptr[d]) + epos[e]] = s;
        }
    }
}

// ---------------------------------------------------------------------------
// Fused GAT layer-1 aggregate + layer-2 projections. No xbuf: x1 row is
// broadcast via __shfl from owner lanes. LDS = w2s(32K) + m2p(4.6K) only.
// __launch_bounds__(512,8) clamps VGPR<=64 for 8 waves/SIMD eligibility.
// ---------------------------------------------------------------------------
__global__ __launch_bounds__(512, 8) void k_msg1(
    const int* __restrict__ rowptr, const int* __restrict__ esrc,
    const float* __restrict__ asrc, const float* __restrict__ adst,
    const unsigned short* __restrict__ Wx, const float* __restrict__ tsb,
    const float* __restrict__ attfix,
    const float* __restrict__ W2, const float* __restrict__ m2g,
    unsigned short* __restrict__ Wx2, float* __restrict__ asrc2,
    float* __restrict__ adst2, int N)
{
    __shared__ unsigned short w2s[16384];   // 32KB: W2 bf16 [k][c]
    __shared__ float m2p[128 * 9];          // padded M2
    int tid = threadIdx.x;
    for (int i = tid; i < 16384; i += 512) w2s[i] = f2bf(W2[i]);
    for (int i = tid; i < 1024; i += 512) m2p[(i >> 3) * 9 + (i & 7)] = m2g[i];
    __syncthreads();

    int lane = tid & 63;
    int grp = lane >> 4;
    int gl = lane & 15;
    int wbase = lane & 48;
    int gw = (blockIdx.x * blockDim.x + tid) >> 6;
    int waves = (gridDim.x * blockDim.x) >> 6;

    float4 tb0 = ((const float4*)tsb)[gl*2];
    float4 tb1 = ((const float4*)tsb)[gl*2+1];
    float cc0 = attfix[0] + attfix[4];
    float cc1 = attfix[1] + attfix[5];
    float cc2 = attfix[2] + attfix[6];
    float cc3 = attfix[3] + attfix[7];

    for (int m = gw; m * 4 < N; m += waves) {
        int n = m * 4 + grp;
        bool nv = n < N;
        int beg = nv ? rowptr[n] : 0;
        int end = nv ? rowptr[n + 1] : 0;
        float4 ad = {0,0,0,0};
        if (nv) ad = ((const float4*)adst)[n];
        ad.x += cc0; ad.y += cc1; ad.z += cc2; ad.w += cc3;

        int e0 = beg + gl;
        bool v0 = e0 < end;
        int s0 = v0 ? esrc[e0] : 0;
        float4 a0 = ((const float4*)asrc)[s0];
        float x0 = v0 ? fexp(lrelu02(a0.x + ad.x)) : 0.f;
        float x1 = v0 ? fexp(lrelu02(a0.y + ad.y)) : 0.f;
        float x2 = v0 ? fexp(lrelu02(a0.z + ad.z)) : 0.f;
        float x3 = v0 ? fexp(lrelu02(a0.w + ad.w)) : 0.f;
        float d0 = x0, d1 = x1, d2 = x2, d3 = x3;
        for (int c = beg + 16; c < end; c += 16) {
            int e = c + gl;
            bool v = e < end;
            int s = v ? esrc[e] : 0;
            float4 a = ((const float4*)asrc)[s];
            if (v) {
                d0 += fexp(lrelu02(a.x + ad.x));
                d1 += fexp(lrelu02(a.y + ad.y));
                d2 += fexp(lrelu02(a.z + ad.z));
                d3 += fexp(lrelu02(a.w + ad.w));
            }
        }
#pragma unroll
        for (int off = 8; off; off >>= 1) {
            d0 += __shfl_xor(d0, off, 64);
            d1 += __shfl_xor(d1, off, 64);
            d2 += __shfl_xor(d2, off, 64);
            d3 += __shfl_xor(d3, off, 64);
        }
        float r0 = __builtin_amdgcn_rcpf(d0 + 2e-9f);
        float r1 = __builtin_amdgcn_rcpf(d1 + 2e-9f);
        float r2 = __builtin_amdgcn_rcpf(d2 + 2e-9f);
        float r3 = __builtin_amdgcn_rcpf(d3 + 2e-9f);

        float csum = d0*r0 + d1*r1 + d2*r2 + d3*r3;
        float4 acc0, acc1;
        acc0.x = csum*tb0.x; acc0.y = csum*tb0.y; acc0.z = csum*tb0.z; acc0.w = csum*tb0.w;
        acc1.x = csum*tb1.x; acc1.y = csum*tb1.y; acc1.z = csum*tb1.z; acc1.w = csum*tb1.w;

        float coef = x0*r0 + x1*r1 + x2*r2 + x3*r3;
#pragma unroll 4
        for (int jj = 0; jj < 16; ++jj) {
            float cj = __shfl(coef, wbase + jj, 64);
            if (cj > 0.f) {
                int sj = __shfl(s0, wbase + jj, 64);
                uint4 w = ((const uint4*)(Wx + (size_t)sj * 128))[gl];
                float4 lo, hi; unpack8(w, lo, hi);
                acc0.x = fmaf(cj, lo.x, acc0.x); acc0.y = fmaf(cj, lo.y, acc0.y);
                acc0.z = fmaf(cj, lo.z, acc0.z); acc0.w = fmaf(cj, lo.w, acc0.w);
                acc1.x = fmaf(cj, hi.x, acc1.x); acc1.y = fmaf(cj, hi.y, acc1.y);
                acc1.z = fmaf(cj, hi.z, acc1.z); acc1.w = fmaf(cj, hi.w, acc1.w);
            }
        }
        for (int c = beg + 16; c < end; c += 16) {
            int e = c + gl;
            bool v = e < end;
            int s = v ? esrc[e] : 0;
            float4 a = ((const float4*)asrc)[s];
            float cf = 0.f;
            if (v) {
                cf = fexp(lrelu02(a.x + ad.x)) * r0
                   + fexp(lrelu02(a.y + ad.y)) * r1
                   + fexp(lrelu02(a.z + ad.z)) * r2
                   + fexp(lrelu02(a.w + ad.w)) * r3;
            }
#pragma unroll 4
            for (int jj = 0; jj < 16; ++jj) {
                float cj = __shfl(cf, wbase + jj, 64);
                if (cj > 0.f) {
                    int sj = __shfl(s, wbase + jj, 64);
                    uint4 w = ((const uint4*)(Wx + (size_t)sj * 128))[gl];
                    float4 lo, hi; unpack8(w, lo, hi);
                    acc0.x = fmaf(cj, lo.x, acc0.x); acc0.y = fmaf(cj, lo.y, acc0.y);
                    acc0.z = fmaf(cj, lo.z, acc0.z); acc0.w = fmaf(cj, lo.w, acc0.w);
                    acc1.x = fmaf(cj, hi.x, acc1.x); acc1.y = fmaf(cj, hi.y, acc1.y);
                    acc1.z = fmaf(cj, hi.z, acc1.z); acc1.w = fmaf(cj, hi.w, acc1.w);
                }
            }
        }
        // x1 = elu(acc/4)
        acc0.x *= 0.25f; acc0.y *= 0.25f; acc0.z *= 0.25f; acc0.w *= 0.25f;
        acc1.x *= 0.25f; acc1.y *= 0.25f; acc1.z *= 0.25f; acc1.w *= 0.25f;
        acc0.x = acc0.x > 0.f ? acc0.x : expm1f(acc0.x);
        acc0.y = acc0.y > 0.f ? acc0.y : expm1f(acc0.y);
        acc0.z = acc0.z > 0.f ? acc0.z : expm1f(acc0.z);
        acc0.w = acc0.w > 0.f ? acc0.w : expm1f(acc0.w);
        acc1.x = acc1.x > 0.f ? acc1.x : expm1f(acc1.x);
        acc1.y = acc1.y > 0.f ? acc1.y : expm1f(acc1.y);
        acc1.z = acc1.z > 0.f ? acc1.z : expm1f(acc1.z);
        acc1.w = acc1.w > 0.f ? acc1.w : expm1f(acc1.w);

        float xo[8] = {acc0.x,acc0.y,acc0.z,acc0.w, acc1.x,acc1.y,acc1.z,acc1.w};

        // Wx2[n][8gl..8gl+8) = sum_k x1[k] * W2[k][c], x1 broadcast via shfl
        float4 wa0 = {0,0,0,0}, wa1 = {0,0,0,0};
        const uint4* w2v4 = (const uint4*)w2s;
#pragma unroll 2
        for (int j = 0; j < 16; ++j) {
            int src = wbase + j;
            float xk0 = __shfl(xo[0], src, 64);
            float xk1 = __shfl(xo[1], src, 64);
            float xk2 = __shfl(xo[2], src, 64);
            float xk3 = __shfl(xo[3], src, 64);
            float xk4 = __shfl(xo[4], src, 64);
            float xk5 = __shfl(xo[5], src, 64);
            float xk6 = __shfl(xo[6], src, 64);
            float xk7 = __shfl(xo[7], src, 64);
            float xks[8] = {xk0,xk1,xk2,xk3,xk4,xk5,xk6,xk7};
#pragma unroll
            for (int e = 0; e < 8; ++e) {
                uint4 w = w2v4[(8*j + e) * 16 + gl];
                float4 lo, hi; unpack8(w, lo, hi);
                float xv = xks[e];
                wa0.x = fmaf(xv, lo.x, wa0.x); wa0.y = fmaf(xv, lo.y, wa0.y);
                wa0.z = fmaf(xv, lo.z, wa0.z); wa0.w = fmaf(xv, lo.w, wa0.w);
                wa1.x = fmaf(xv, hi.x, wa1.x); wa1.y = fmaf(xv, hi.y, wa1.y);
                wa1.z = fmaf(xv, hi.z, wa1.z); wa1.w = fmaf(xv, hi.w, wa1.w);
            }
        }
        // att2 partials over own k-range (x values in regs)
        float aacc[8] = {0,0,0,0,0,0,0,0};
#pragma unroll
        for (int kk = 0; kk < 8; ++kk) {
            const float* mrow = &m2p[(8 * gl + kk) * 9];
            float xv = xo[kk];
#pragma unroll
            for (int h = 0; h < 8; ++h) aacc[h] = fmaf(xv, mrow[h], aacc[h]);
        }
#pragma unroll
        for (int off = 8; off; off >>= 1) {
#pragma unroll
            for (int h = 0; h < 8; ++h) aacc[h] += __shfl_xor(aacc[h], off, 64);
        }
        if (nv) {
            unsigned short* wrow = Wx2 + (size_t)n * 128 + 8 * gl;
            uint4 o;
            o.x = (unsigned)f2bf(wa0.x) | ((unsigned)f2bf(wa0.y) << 16);
            o.y = (unsigned)f2bf(wa0.z) | ((unsigned)f2bf(wa0.w) << 16);
            o.z = (unsigned)f2bf(wa1.x) | ((unsigned)f2bf(wa1.y) << 16);
            o.w = (unsigned)f2bf(wa1.z) | ((unsigned)f2bf(wa1.w) << 16);
            *(uint4*)wrow = o;
            if (gl == 0) {
                float4 o1; o1.x = aacc[0]; o1.y = aacc[1]; o1.z = aacc[2]; o1.w = aacc[3];
                float4 o2; o2.x = aacc[4]; o2.y = aacc[5]; o2.z = aacc[6]; o2.w = aacc[7];
                ((float4*)asrc2)[n] = o1;
                ((float4*)adst2)[n] = o2;
            }
        }
    }
}

// ---------------------------------------------------------------------------
// Fused GAT layer-2 aggregate + FC head. No xbuf (shfl broadcast); LDS = 32KB.
// ---------------------------------------------------------------------------
__global__ __launch_bounds__(512, 8) void k_msg0(
    const int* __restrict__ rowptr, const int* __restrict__ esrc,
    const float* __restrict__ asrc, const float* __restrict__ adst,
    const unsigned short* __restrict__ Wx,
    const float* __restrict__ fc1w, const float* __restrict__ fc1b,
    const float* __restrict__ fc2w, const float* __restrict__ fc2b,
    float* __restrict__ out, int N)
{
    __shared__ float fc1s[8192];            // 32KB: fc1w [c][j]
    int tid = threadIdx.x;
    for (int i = tid; i < 8192; i += 512) fc1s[i] = fc1w[i];
    __syncthreads();

    int lane = tid & 63;
    int grp = lane >> 4;
    int gl = lane & 15;
    int wbase = lane & 48;
    int gw = (blockIdx.x * blockDim.x + tid) >> 6;
    int waves = (gridDim.x * blockDim.x) >> 6;

    float4 b1v = *(const float4*)&fc1b[4 * gl];
    float4 w2v = *(const float4*)&fc2w[4 * gl];
    float b2 = fc2b[0];

    for (int m = gw; m * 4 < N; m += waves) {
        int n = m * 4 + grp;
        bool nv = n < N;
        int beg = nv ? rowptr[n] : 0;
        int end = nv ? rowptr[n + 1] : 0;
        float4 ad = {0,0,0,0};
        if (nv) ad = ((const float4*)adst)[n];

        int e0 = beg + gl;
        bool v0 = e0 < end;
        int s0 = v0 ? esrc[e0] : 0;
        float4 a0 = ((const float4*)asrc)[s0];
        float x0 = v0 ? fexp(lrelu02(a0.x + ad.x)) : 0.f;
        float x1 = v0 ? fexp(lrelu02(a0.y + ad.y)) : 0.f;
        float x2 = v0 ? fexp(lrelu02(a0.z + ad.z)) : 0.f;
        float x3 = v0 ? fexp(lrelu02(a0.w + ad.w)) : 0.f;
        float d0 = x0, d1 = x1, d2 = x2, d3 = x3;
        for (int c = beg + 16; c < end; c += 16) {
            int e = c + gl;
            bool v = e < end;
            int s = v ? esrc[e] : 0;
            float4 a = ((const float4*)asrc)[s];
            if (v) {
                d0 += fexp(lrelu02(a.x + ad.x));
                d1 += fexp(lrelu02(a.y + ad.y));
                d2 += fexp(lrelu02(a.z + ad.z));
                d3 += fexp(lrelu02(a.w + ad.w));
            }
        }
#pragma unroll
        for (int off = 8; off; off >>= 1) {
            d0 += __shfl_xor(d0, off, 64);
            d1 += __shfl_xor(d1, off, 64);
            d2 += __shfl_xor(d2, off, 64);
            d3 += __shfl_xor(d3, off, 64);
        }
        float r0 = __builtin_amdgcn_rcpf(d0 + 2e-9f);
        float r1 = __builtin_amdgcn_rcpf(d1 + 2e-9f);
        float r2 = __builtin_amdgcn_rcpf(d2 + 2e-9f);
        float r3 = __builtin_amdgcn_rcpf(d3 + 2e-9f);

        float4 acc0 = {0,0,0,0}, acc1 = {0,0,0,0};
        float coef = x0*r0 + x1*r1 + x2*r2 + x3*r3;
#pragma unroll 4
        for (int jj = 0; jj < 16; ++jj) {
            float cj = __shfl(coef, wbase + jj, 64);
            if (cj > 0.f) {
                int sj = __shfl(s0, wbase + jj, 64);
                uint4 w = ((const uint4*)(Wx + (size_t)sj * 128))[gl];
                float4 lo, hi; unpack8(w, lo, hi);
                acc0.x = fmaf(cj, lo.x, acc0.x); acc0.y = fmaf(cj, lo.y, acc0.y);
                acc0.z = fmaf(cj, lo.z, acc0.z); acc0.w = fmaf(cj, lo.w, acc0.w);
                acc1.x = fmaf(cj, hi.x, acc1.x); acc1.y = fmaf(cj, hi.y, acc1.y);
                acc1.z = fmaf(cj, hi.z, acc1.z); acc1.w = fmaf(cj, hi.w, acc1.w);
            }
        }
        for (int c = beg + 16; c < end; c += 16) {
            int e = c + gl;
            bool v = e < end;
            int s = v ? esrc[e] : 0;
            float4 a = ((const float4*)asrc)[s];
            float cf = 0.f;
            if (v) {
                cf = fexp(lrelu02(a.x + ad.x)) * r0
                   + fexp(lrelu02(a.y + ad.y)) * r1
                   + fexp(lrelu02(a.z + ad.z)) * r2
                   + fexp(lrelu02(a.w + ad.w)) * r3;
            }
#pragma unroll 4
            for (int jj = 0; jj < 16; ++jj) {
                float cj = __shfl(cf, wbase + jj, 64);
                if (cj > 0.f) {
                    int sj = __shfl(s, wbase + jj, 64);
                    uint4 w = ((const uint4*)(Wx + (size_t)sj * 128))[gl];
                    float4 lo, hi; unpack8(w, lo, hi);
                    acc0.x = fmaf(cj, lo.x, acc0.x); acc0.y = fmaf(cj, lo.y, acc0.y);
                    acc0.z = fmaf(cj, lo.z, acc0.z); acc0.w = fmaf(cj, lo.w, acc0.w);
                    acc1.x = fmaf(cj, hi.x, acc1.x); acc1.y = fmaf(cj, hi.y, acc1.y);
                    acc1.z = fmaf(cj, hi.z, acc1.z); acc1.w = fmaf(cj, hi.w, acc1.w);
                }
            }
        }
        // x = elu(acc/4); h = relu(x@fc1+b1) (x broadcast via shfl); out = h@fc2+b2
        acc0.x *= 0.25f; acc0.y *= 0.25f; acc0.z *= 0.25f; acc0.w *= 0.25f;
        acc1.x *= 0.25f; acc1.y *= 0.25f; acc1.z *= 0.25f; acc1.w *= 0.25f;
        acc0.x = acc0.x > 0.f ? acc0.x : expm1f(acc0.x);
        acc0.y = acc0.y > 0.f ? acc0.y : expm1f(acc0.y);
        acc0.z = acc0.z > 0.f ? acc0.z : expm1f(acc0.z);
        acc0.w = acc0.w > 0.f ? acc0.w : expm1f(acc0.w);
        acc1.x = acc1.x > 0.f ? acc1.x : expm1f(acc1.x);
        acc1.y = acc1.y > 0.f ? acc1.y : expm1f(acc1.y);
        acc1.z = acc1.z > 0.f ? acc1.z : expm1f(acc1.z);
        acc1.w = acc1.w > 0.f ? acc1.w : expm1f(acc1.w);
        float xo[8] = {acc0.x,acc0.y,acc0.z,acc0.w, acc1.x,acc1.y,acc1.z,acc1.w};

        float4 hacc = b1v;
#pragma unroll 2
        for (int j = 0; j < 16; ++j) {
            int src = wbase + j;
            float xk0 = __shfl(xo[0], src, 64);
            float xk1 = __shfl(xo[1], src, 64);
            float xk2 = __shfl(xo[2], src, 64);
            float xk3 = __shfl(xo[3], src, 64);
            float xk4 = __shfl(xo[4], src, 64);
            float xk5 = __shfl(xo[5], src, 64);
            float xk6 = __shfl(xo[6], src, 64);
            float xk7 = __shfl(xo[7], src, 64);
            float xks[8] = {xk0,xk1,xk2,xk3,xk4,xk5,xk6,xk7};
#pragma unroll
            for (int e = 0; e < 8; ++e) {
                float4 w = *(const float4*)&fc1s[(8*j + e) * 64 + 4 * gl];
                hacc.x = fmaf(xks[e], w.x, hacc.x); hacc.y = fmaf(xks[e], w.y, hacc.y);
                hacc.z = fmaf(xks[e], w.z, hacc.z); hacc.w = fmaf(xks[e], w.w, hacc.w);
            }
        }
        float r = fmaxf(hacc.x, 0.f) * w2v.x + fmaxf(hacc.y, 0.f) * w2v.y
                + fmaxf(hacc.z, 0.f) * w2v.z + fmaxf(hacc.w, 0.f) * w2v.w;
#pragma unroll
        for (int off = 8; off; off >>= 1) r += __shfl_xor(r, off, 64);
        if (nv && gl == 0) out[n] = r + b2;
    }
}

extern "C" void kernel_launch(void* const* d_in, const int* in_sizes, int n_in,
                              void* d_out, int out_size, void* d_ws, size_t ws_size,
                              hipStream_t stream)
{
    const float* nf   = (const float*)d_in[0];
    const int*   ei   = (const int*)  d_in[1];
    const float* ts   = (const float*)d_in[2];
    const float* Wih0 = (const float*)d_in[3];
    const float* Whh0 = (const float*)d_in[4];
    const float* b0   = (const float*)d_in[5];
    const float* Wih1 = (const float*)d_in[6];
    const float* Whh1 = (const float*)d_in[7];
    const float* b1   = (const float*)d_in[8];
    const float* W1   = (const float*)d_in[9];
    const float* A1   = (const float*)d_in[10];
    const float* W2   = (const float*)d_in[11];
    const float* A2   = (const float*)d_in[12];
    const float* fc1w = (const float*)d_in[13];
    const float* fc1b = (const float*)d_in[14];
    const float* fc2w = (const float*)d_in[15];
    const float* fc2b = (const float*)d_in[16];

    int N = in_sizes[0] / 16;
    int E = in_sizes[1] / 2;
    int T = in_sizes[2] / 3;

    char* ws = (char*)d_ws;
    size_t off = 0;
    auto alloc = [&](size_t bytes) {
        char* p = ws + off;
        off = (off + bytes + 255) & ~(size_t)255;
        return p;
    };
    float* tsb    = (float*)alloc(512);
    float* attfix = (float*)alloc(64);
    int*   flags  = (int*)  alloc(64);
    float* m2g    = (float*)alloc(1024 * sizeof(float));
    float* asrc   = (float*)alloc((size_t)N * 4 * sizeof(float));
    float* adst   = (float*)alloc((size_t)N * 4 * sizeof(float));
    float* asrc2  = (float*)alloc((size_t)N * 4 * sizeof(float));
    float* adst2  = (float*)alloc((size_t)N * 4 * sizeof(float));
    int*   rowptr = (int*)  alloc((size_t)(N + 1) * sizeof(int));
    int*   esrc   = (int*)  alloc((size_t)E * sizeof(int));
    int*   epos   = (int*)  alloc((size_t)E * sizeof(int));
    int*   deg    = (int*)  alloc((size_t)N * sizeof(int));
    int*   bsum   = (int*)  alloc(512 * sizeof(int));
    unsigned short* bufA = (unsigned short*)alloc((size_t)N * 128 * sizeof(unsigned short));
    unsigned short* bufC = (unsigned short*)alloc((size_t)N * 128 * sizeof(unsigned short));

    int NCH = (N + 2047) / 2048;

    hipMemsetAsync(deg, 0, (size_t)N * sizeof(int), stream);
    hipMemsetAsync(flags, 0, 64, stream);

    // ---- mega-front: LSTM || (hist -> scan -> scatter) || att1P || Wxp(bf16) || M2 ----
    k_front<<<256, 512, 0, stream>>>(
        ts, Wih0, Whh0, b0, Wih1, Whh1, b1, W1, A1, W2, A2,
        tsb, attfix, m2g,
        ei, deg, epos, nf, bufA, asrc, adst,
        rowptr, bsum, esrc, flags,
        N, E, T, NCH);

    // ---- layer-1 aggregate + layer-2 projections (fused) ----
    k_msg1<<<1024, 512, 0, stream>>>(rowptr, esrc, asrc, adst, bufA, tsb, attfix,
                                     W2, m2g, bufC, asrc2, adst2, N);

    // ---- layer-2 aggregate + FC head (fused) ----
    k_msg0<<<1024, 512, 0, stream>>>(rowptr, esrc, asrc2, adst2, bufC,
                                     fc1w, fc1b, fc2w, fc2b, (float*)d_out, N);
}

// Round 12
// 511.157 us; speedup vs baseline: 1.9623x; 1.0940x over previous
//
#include <hip/hip_runtime.h>
#include <math.h>

#define DEV __device__ __forceinline__

#define LOG2E 1.4426950408889634f

DEV float fexp(float x)  { return __builtin_amdgcn_exp2f(LOG2E * x); }
DEV float fsigm(float x) { return __builtin_amdgcn_rcpf(1.0f + __builtin_amdgcn_exp2f(-LOG2E * x)); }
DEV float ftanh(float x) { return 1.0f - 2.0f * __builtin_amdgcn_rcpf(__builtin_amdgcn_exp2f(2.0f * LOG2E * x) + 1.0f); }
DEV float lrelu02(float x) { return x > 0.0f ? x : 0.2f * x; }
DEV int aload(const int* p) {
    return __hip_atomic_load(p, __ATOMIC_RELAXED, __HIP_MEMORY_SCOPE_AGENT);
}
DEV void astore(int* p, int v) {
    __hip_atomic_store(p, v, __ATOMIC_RELAXED, __HIP_MEMORY_SCOPE_AGENT);
}
DEV unsigned short f2bf(float f) {
    unsigned u = __float_as_uint(f);
    return (unsigned short)((u + 0x7FFFu + ((u >> 16) & 1u)) >> 16);
}
DEV void unpack8(uint4 w, float4& lo, float4& hi) {
    lo.x = __uint_as_float(w.x << 16); lo.y = __uint_as_float(w.x & 0xFFFF0000u);
    lo.z = __uint_as_float(w.y << 16); lo.w = __uint_as_float(w.y & 0xFFFF0000u);
    hi.x = __uint_as_float(w.z << 16); hi.y = __uint_as_float(w.z & 0xFFFF0000u);
    hi.z = __uint_as_float(w.w << 16); hi.w = __uint_as_float(w.w & 0xFFFF0000u);
}
#define QB(v, ctrl) __int_as_float(__builtin_amdgcn_mov_dpp(__float_as_int(v), ctrl, 0xF, 0xF, true))

// ---------------------------------------------------------------------------
// Mega-front. __launch_bounds__(512,2): VGPR cap 256 so the LSTM's per-thread
// weight arrays (seg1: 128 floats) stay register-resident (r11 had VGPR=128
// => guaranteed scratch spill in the 128-FMA inner loop). Weight arrays are
// declared branch-locally; seg0/seg1 run separate k-loops with matched
// barrier counts (T+3 each; wave-uniform branch => legal on CDNA).
// ---------------------------------------------------------------------------
__global__ __launch_bounds__(512, 2) void k_front(
    const float* __restrict__ ts,
    const float* __restrict__ Wih0, const float* __restrict__ Whh0, const float* __restrict__ b0,
    const float* __restrict__ Wih1, const float* __restrict__ Whh1, const float* __restrict__ b1,
    const float* __restrict__ W1, const float* __restrict__ A1,
    const float* __restrict__ W2, const float* __restrict__ A2,
    float* __restrict__ tsb, float* __restrict__ attfix, float* __restrict__ m2g,
    const int* __restrict__ ei, int* __restrict__ deg, int* __restrict__ epos,
    const float* __restrict__ nf, unsigned short* __restrict__ Wxp,
    float* __restrict__ asrcP, float* __restrict__ adstP,
    int* __restrict__ rowptr, int* __restrict__ bsum,
    int* __restrict__ esrc, int* __restrict__ flags,
    int N, int E, int T, int NCH)
{
    __shared__ __align__(16) float h0b[2][64], h1b[2][64];
    __shared__ __align__(16) float tsbig[21504];   // 84KB pad -> 1 block/CU
    __shared__ float m1s[128];
    __shared__ int iwsum[8];
    __shared__ int stmp[512];
    const int tid = threadIdx.x;
    const int bid = blockIdx.x;

    auto signalflag = [&](int* f) {
        __syncthreads();
        if (tid == 0) {
            __threadfence();
            __hip_atomic_fetch_add(f, 1, __ATOMIC_RELEASE, __HIP_MEMORY_SCOPE_AGENT);
        }
    };
    auto waitflag = [&](int* f, int tgt) {
        if (tid == 0) {
            while (__hip_atomic_load(f, __ATOMIC_ACQUIRE, __HIP_MEMORY_SCOPE_AGENT) < tgt)
                __builtin_amdgcn_s_sleep(8);
        }
        __syncthreads();
    };

    if (bid == 0) {
        // ================= LSTM =================
        const int seg = tid >> 8;
        const int idx = tid & 255;
        const int u = idx >> 2;
        const int q = idx & 3;
        const int row = q * 64 + u;
        float* tss = tsbig;

        for (int i = tid; i < 3 * T && i < 512; i += 512) tss[i] = ts[i];
        if (tid < 64) {
            h0b[0][tid] = 0.f; h0b[1][tid] = 0.f;
            h1b[0][tid] = 0.f; h1b[1][tid] = 0.f;
        }
        __syncthreads();

        if (seg == 0) {
            // ----- layer 0: 64 weights/thread, branch-local -----
            float wa[64], wih[3];
            float bias = b0[row];
            wih[0] = Wih0[row*3+0]; wih[1] = Wih0[row*3+1]; wih[2] = Wih0[row*3+2];
#pragma unroll
            for (int k = 0; k < 64; k++) wa[k] = Whh0[row * 64 + k];
            float creg = 0.0f;
            for (int k = 0; k <= T; ++k) {
                if (k < T) {
                    const float* hprev = h0b[(k + 1) & 1];
                    float a0 = bias, a1 = 0.f, a2 = 0.f, a3 = 0.f;
                    a0 = fmaf(tss[3*k+0], wih[0], a0);
                    a1 = fmaf(tss[3*k+1], wih[1], a1);
                    a2 = fmaf(tss[3*k+2], wih[2], a2);
#pragma unroll
                    for (int p = 0; p < 64; p += 16) {
                        float4 u0 = *(const float4*)&hprev[p];
                        float4 u1 = *(const float4*)&hprev[p+4];
                        float4 u2 = *(const float4*)&hprev[p+8];
                        float4 u3 = *(const float4*)&hprev[p+12];
                        a0 = fmaf(u0.x, wa[p+0],  a0); a0 = fmaf(u0.y, wa[p+1],  a0);
                        a0 = fmaf(u0.z, wa[p+2],  a0); a0 = fmaf(u0.w, wa[p+3],  a0);
                        a1 = fmaf(u1.x, wa[p+4],  a1); a1 = fmaf(u1.y, wa[p+5],  a1);
                        a1 = fmaf(u1.z, wa[p+6],  a1); a1 = fmaf(u1.w, wa[p+7],  a1);
                        a2 = fmaf(u2.x, wa[p+8],  a2); a2 = fmaf(u2.y, wa[p+9],  a2);
                        a2 = fmaf(u2.z, wa[p+10], a2); a2 = fmaf(u2.w, wa[p+11], a2);
                        a3 = fmaf(u3.x, wa[p+12], a3); a3 = fmaf(u3.y, wa[p+13], a3);
                        a3 = fmaf(u3.z, wa[p+14], a3); a3 = fmaf(u3.w, wa[p+15], a3);
                    }
                    float mine = (a0 + a1) + (a2 + a3);
                    float gi = QB(mine, 0x00);
                    float gf = QB(mine, 0x55);
                    float gg = QB(mine, 0xAA);
                    float go = QB(mine, 0xFF);
                    creg = fsigm(gf) * creg + fsigm(gi) * ftanh(gg);
                    float h = fsigm(go) * ftanh(creg);
                    if (q == 0) h0b[k & 1][u] = h;
                }
                __syncthreads();
            }
            // epilogue (tid<128 subset of seg0)
            if (tid < 128) {
                const float* hf = h1b[(T - 1) & 1];
                float acc = 0.f;
#pragma unroll
                for (int kk = 0; kk < 64; kk++)
                    acc = fmaf(hf[kk], W1[(16 + kk) * 128 + tid], acc);
                tsb[tid] = acc;
                m1s[tid] = acc;
            }
            __syncthreads();
            if (tid < 8) {
                int half = tid >> 2, h = tid & 3;
                const float* a1p = A1 + (size_t)half * 512 + h;
                float acc = 0.f;
                for (int c = 0; c < 128; c++) acc = fmaf(m1s[c], a1p[c * 4], acc);
                attfix[tid] = acc;
            }
        } else {
            // ----- layer 1: 128 weights/thread, branch-local (needs VGPR>128) -----
            float wa[64], wb[64];
            float bias = b1[row];
#pragma unroll
            for (int k = 0; k < 64; k++) wa[k] = Whh1[row * 64 + k];
#pragma unroll
            for (int k = 0; k < 64; k++) wb[k] = Wih1[row * 64 + k];
            float creg = 0.0f;
            for (int k = 0; k <= T; ++k) {
                if (k >= 1) {
                    const float* h1prev = h1b[k & 1];
                    const float* h0in   = h0b[(k + 1) & 1];
                    float a0 = bias, a1 = 0.f, a2 = 0.f, a3 = 0.f;
#pragma unroll
                    for (int p = 0; p < 64; p += 8) {
                        float4 u0 = *(const float4*)&h1prev[p];
                        float4 u1 = *(const float4*)&h1prev[p+4];
                        a0 = fmaf(u0.x, wa[p+0], a0); a0 = fmaf(u0.y, wa[p+1], a0);
                        a0 = fmaf(u0.z, wa[p+2], a0); a0 = fmaf(u0.w, wa[p+3], a0);
                        a1 = fmaf(u1.x, wa[p+4], a1); a1 = fmaf(u1.y, wa[p+5], a1);
                        a1 = fmaf(u1.z, wa[p+6], a1); a1 = fmaf(u1.w, wa[p+7], a1);
                        float4 v0 = *(const float4*)&h0in[p];
                        float4 v1 = *(const float4*)&h0in[p+4];
                        a2 = fmaf(v0.x, wb[p+0], a2); a2 = fmaf(v0.y, wb[p+1], a2);
                        a2 = fmaf(v0.z, wb[p+2], a2); a2 = fmaf(v0.w, wb[p+3], a2);
                        a3 = fmaf(v1.x, wb[p+4], a3); a3 = fmaf(v1.y, wb[p+5], a3);
                        a3 = fmaf(v1.z, wb[p+6], a3); a3 = fmaf(v1.w, wb[p+7], a3);
                    }
                    float mine = (a0 + a1) + (a2 + a3);
                    float gi = QB(mine, 0x00);
                    float gf = QB(mine, 0x55);
                    float gg = QB(mine, 0xAA);
                    float go = QB(mine, 0xFF);
                    creg = fsigm(gf) * creg + fsigm(gi) * ftanh(gg);
                    float h = fsigm(go) * ftanh(creg);
                    if (q == 0) h1b[(k + 1) & 1][u] = h;
                }
                __syncthreads();
            }
            __syncthreads();   // match seg0's epilogue barrier
        }
        return;
    }

    // ================= workers =================
    const int W = gridDim.x - 1;
    const int wid = bid - 1;

    {
        int g = wid * 512 + tid, stride = W * 512;
        for (int e = g; e < E; e += stride)
            epos[e] = atomicAdd(&deg[ei[E + e]], 1);
    }
    signalflag(&flags[0]);

    if (wid < NCH) {
        waitflag(&flags[0], W);
        int base = wid * 2048 + tid * 4;
        int d0 = base + 0 < N ? aload(&deg[base + 0]) : 0;
        int d1 = base + 1 < N ? aload(&deg[base + 1]) : 0;
        int d2 = base + 2 < N ? aload(&deg[base + 2]) : 0;
        int d3 = base + 3 < N ? aload(&deg[base + 3]) : 0;
        int tsum = d0 + d1 + d2 + d3;
        int lane = tid & 63, wv = tid >> 6;
        int incl = tsum;
#pragma unroll
        for (int off = 1; off < 64; off <<= 1) {
            int t = __shfl_up(incl, off, 64);
            if (lane >= off) incl += t;
        }
        if (lane == 63) iwsum[wv] = incl;
        __syncthreads();
        int woff = 0;
#pragma unroll
        for (int w = 0; w < 8; w++) if (w < wv) woff += iwsum[w];
        int tex = woff + incl - tsum;
        if (base + 0 < N) rowptr[base + 0] = tex;
        if (base + 1 < N) rowptr[base + 1] = tex + d0;
        if (base + 2 < N) rowptr[base + 2] = tex + d0 + d1;
        if (base + 3 < N) rowptr[base + 3] = tex + d0 + d1 + d2;
        if (tid == 511) astore(&bsum[wid], woff + incl);
        signalflag(&flags[1]);
        waitflag(&flags[2], 1);
        int off2 = aload(&bsum[wid]);
#pragma unroll
        for (int i = 0; i < 4; i++) {
            int idx = base + i;
            if (idx < N) {
                int v = rowptr[idx] + off2;
                astore(&rowptr[idx], v);
            }
        }
        if (wid == 0 && tid == 0) astore(&rowptr[N], E);
        signalflag(&flags[3]);
    } else if (wid == NCH) {
        waitflag(&flags[1], NCH);
        int v = tid < NCH ? aload(&bsum[tid]) : 0;
        stmp[tid] = v;
        __syncthreads();
        for (int off = 1; off < 512; off <<= 1) {
            int t = (tid >= off) ? stmp[tid - off] : 0;
            __syncthreads();
            stmp[tid] += t;
            __syncthreads();
        }
        if (tid < NCH) astore(&bsum[tid], stmp[tid] - v);
        signalflag(&flags[2]);
        // ---- compute M2 = W2@A2 (128 x 8) while LSTM still runs ----
#pragma unroll
        for (int e = tid; e < 1024; e += 512) {
            int k = e >> 3, h8 = e & 7, half = h8 >> 2, h = h8 & 3;
            const float* w2p = W2 + (size_t)k * 128;
            const float* a2p = A2 + (size_t)half * 512 + h;
            float acc = 0.f;
            for (int c = 0; c < 128; c++) acc = fmaf(w2p[c], a2p[c * 4], acc);
            m2g[e] = acc;
        }
    } else {
        const int AW = W - NCH - 1;
        const int aw = wid - NCH - 1;
        if (tid < 128) {
            int k = tid >> 3, h8 = tid & 7, half = h8 >> 2, h = h8 & 3;
            const float* a1p = A1 + (size_t)half * 512 + h;
            const float* w1p = W1 + (size_t)k * 128;
            float acc = 0.f;
            for (int c = 0; c < 128; c++) acc = fmaf(w1p[c], a1p[c * 4], acc);
            m1s[tid] = acc;
        }
        __syncthreads();
        float m1r[128];
#pragma unroll
        for (int i = 0; i < 128; i++) m1r[i] = m1s[i];
        {
            int gt = aw * 512 + tid;
            int tstride = AW * 512;
            for (int n = gt; n < N; n += tstride) {
                const float4* nfr = (const float4*)(nf + (size_t)n * 16);
                float4 f0 = nfr[0], f1 = nfr[1], f2 = nfr[2], f3 = nfr[3];
                float xk[16] = {f0.x,f0.y,f0.z,f0.w, f1.x,f1.y,f1.z,f1.w,
                                f2.x,f2.y,f2.z,f2.w, f3.x,f3.y,f3.z,f3.w};
                float as0=0,as1=0,as2=0,as3=0, ad0=0,ad1=0,ad2=0,ad3=0;
#pragma unroll
                for (int k = 0; k < 16; k++) {
                    float xv = xk[k];
                    as0 = fmaf(xv, m1r[k*8+0], as0); as1 = fmaf(xv, m1r[k*8+1], as1);
                    as2 = fmaf(xv, m1r[k*8+2], as2); as3 = fmaf(xv, m1r[k*8+3], as3);
                    ad0 = fmaf(xv, m1r[k*8+4], ad0); ad1 = fmaf(xv, m1r[k*8+5], ad1);
                    ad2 = fmaf(xv, m1r[k*8+6], ad2); ad3 = fmaf(xv, m1r[k*8+7], ad3);
                }
                float4 o1; o1.x=as0; o1.y=as1; o1.z=as2; o1.w=as3;
                float4 o2; o2.x=ad0; o2.y=ad1; o2.z=ad2; o2.w=ad3;
                ((float4*)asrcP)[n] = o1;
                ((float4*)adstP)[n] = o2;
            }
        }
        {
            int lane = tid & 63;
            int bw = aw * 8 + (tid >> 6);
            int half = bw & 1;
            int col = lane + 64 * half;
            float wreg[16];
#pragma unroll
            for (int k = 0; k < 16; k++) wreg[k] = W1[k * 128 + col];
            int nstride = AW * 4;
            for (int n = (bw >> 1); n < N; n += nstride) {
                int nu = __builtin_amdgcn_readfirstlane(n);
                const float4* xr = (const float4*)(nf + (size_t)nu * 16);
                float4 x0 = xr[0], x1 = xr[1], x2 = xr[2], x3 = xr[3];
                float acc = 0.f;
                acc = fmaf(x0.x, wreg[0],  acc); acc = fmaf(x0.y, wreg[1],  acc);
                acc = fmaf(x0.z, wreg[2],  acc); acc = fmaf(x0.w, wreg[3],  acc);
                acc = fmaf(x1.x, wreg[4],  acc); acc = fmaf(x1.y, wreg[5],  acc);
                acc = fmaf(x1.z, wreg[6],  acc); acc = fmaf(x1.w, wreg[7],  acc);
                acc = fmaf(x2.x, wreg[8],  acc); acc = fmaf(x2.y, wreg[9],  acc);
                acc = fmaf(x2.z, wreg[10], acc); acc = fmaf(x2.w, wreg[11], acc);
                acc = fmaf(x3.x, wreg[12], acc); acc = fmaf(x3.y, wreg[13], acc);
                acc = fmaf(x3.z, wreg[14], acc); acc = fmaf(x3.w, wreg[15], acc);
                Wxp[(size_t)nu * 128 + col] = f2bf(acc);
            }
        }
    }

    waitflag(&flags[3], NCH);
    {
        int g = wid * 512 + tid, stride = W * 512;
        for (int e = g; e < E; e += stride) {
            int s = ei[e], d = ei[E + e];
            esrc[aload(&rowptr[d]) + epos[e]] = s;
        }
    }
}

// ---------------------------------------------------------------------------
// Fused GAT layer-1 aggregate + layer-2 projections (unchanged from r11).
// ---------------------------------------------------------------------------
__global__ __launch_bounds__(512, 8) void k_msg1(
    const int* __restrict__ rowptr, const int* __restrict__ esrc,
    const float* __restrict__ asrc, const float* __restrict__ adst,
    const unsigned short* __restrict__ Wx, const float* __restrict__ tsb,
    const float* __restrict__ attfix,
    const float* __restrict__ W2, const float* __restrict__ m2g,
    unsigned short* __restrict__ Wx2, float* __restrict__ asrc2,
    float* __restrict__ adst2, int N)
{
    __shared__ unsigned short w2s[16384];   // 32KB: W2 bf16 [k][c]
    __shared__ float m2p[128 * 9];          // padded M2
    int tid = threadIdx.x;
    for (int i = tid; i < 16384; i += 512) w2s[i] = f2bf(W2[i]);
    for (int i = tid; i < 1024; i += 512) m2p[(i >> 3) * 9 + (i & 7)] = m2g[i];
    __syncthreads();

    int lane = tid & 63;
    int grp = lane >> 4;
    int gl = lane & 15;
    int wbase = lane & 48;
    int gw = (blockIdx.x * blockDim.x + tid) >> 6;
    int waves = (gridDim.x * blockDim.x) >> 6;

    float4 tb0 = ((const float4*)tsb)[gl*2];
    float4 tb1 = ((const float4*)tsb)[gl*2+1];
    float cc0 = attfix[0] + attfix[4];
    float cc1 = attfix[1] + attfix[5];
    float cc2 = attfix[2] + attfix[6];
    float cc3 = attfix[3] + attfix[7];

    for (int m = gw; m * 4 < N; m += waves) {
        int n = m * 4 + grp;
        bool nv = n < N;
        int beg = nv ? rowptr[n] : 0;
        int end = nv ? rowptr[n + 1] : 0;
        float4 ad = {0,0,0,0};
        if (nv) ad = ((const float4*)adst)[n];
        ad.x += cc0; ad.y += cc1; ad.z += cc2; ad.w += cc3;

        int e0 = beg + gl;
        bool v0 = e0 < end;
        int s0 = v0 ? esrc[e0] : 0;
        float4 a0 = ((const float4*)asrc)[s0];
        float x0 = v0 ? fexp(lrelu02(a0.x + ad.x)) : 0.f;
        float x1 = v0 ? fexp(lrelu02(a0.y + ad.y)) : 0.f;
        float x2 = v0 ? fexp(lrelu02(a0.z + ad.z)) : 0.f;
        float x3 = v0 ? fexp(lrelu02(a0.w + ad.w)) : 0.f;
        float d0 = x0, d1 = x1, d2 = x2, d3 = x3;
        for (int c = beg + 16; c < end; c += 16) {
            int e = c + gl;
            bool v = e < end;
            int s = v ? esrc[e] : 0;
            float4 a = ((const float4*)asrc)[s];
            if (v) {
                d0 += fexp(lrelu02(a.x + ad.x));
                d1 += fexp(lrelu02(a.y + ad.y));
                d2 += fexp(lrelu02(a.z + ad.z));
                d3 += fexp(lrelu02(a.w + ad.w));
            }
        }
#pragma unroll
        for (int off = 8; off; off >>= 1) {
            d0 += __shfl_xor(d0, off, 64);
            d1 += __shfl_xor(d1, off, 64);
            d2 += __shfl_xor(d2, off, 64);
            d3 += __shfl_xor(d3, off, 64);
        }
        float r0 = __builtin_amdgcn_rcpf(d0 + 2e-9f);
        float r1 = __builtin_amdgcn_rcpf(d1 + 2e-9f);
        float r2 = __builtin_amdgcn_rcpf(d2 + 2e-9f);
        float r3 = __builtin_amdgcn_rcpf(d3 + 2e-9f);

        float csum = d0*r0 + d1*r1 + d2*r2 + d3*r3;
        float4 acc0, acc1;
        acc0.x = csum*tb0.x; acc0.y = csum*tb0.y; acc0.z = csum*tb0.z; acc0.w = csum*tb0.w;
        acc1.x = csum*tb1.x; acc1.y = csum*tb1.y; acc1.z = csum*tb1.z; acc1.w = csum*tb1.w;

        float coef = x0*r0 + x1*r1 + x2*r2 + x3*r3;
#pragma unroll 4
        for (int jj = 0; jj < 16; ++jj) {
            float cj = __shfl(coef, wbase + jj, 64);
            if (cj > 0.f) {
                int sj = __shfl(s0, wbase + jj, 64);
                uint4 w = ((const uint4*)(Wx + (size_t)sj * 128))[gl];
                float4 lo, hi; unpack8(w, lo, hi);
                acc0.x = fmaf(cj, lo.x, acc0.x); acc0.y = fmaf(cj, lo.y, acc0.y);
                acc0.z = fmaf(cj, lo.z, acc0.z); acc0.w = fmaf(cj, lo.w, acc0.w);
                acc1.x = fmaf(cj, hi.x, acc1.x); acc1.y = fmaf(cj, hi.y, acc1.y);
                acc1.z = fmaf(cj, hi.z, acc1.z); acc1.w = fmaf(cj, hi.w, acc1.w);
            }
        }
        for (int c = beg + 16; c < end; c += 16) {
            int e = c + gl;
            bool v = e < end;
            int s = v ? esrc[e] : 0;
            float4 a = ((const float4*)asrc)[s];
            float cf = 0.f;
            if (v) {
                cf = fexp(lrelu02(a.x + ad.x)) * r0
                   + fexp(lrelu02(a.y + ad.y)) * r1
                   + fexp(lrelu02(a.z + ad.z)) * r2
                   + fexp(lrelu02(a.w + ad.w)) * r3;
            }
#pragma unroll 4
            for (int jj = 0; jj < 16; ++jj) {
                float cj = __shfl(cf, wbase + jj, 64);
                if (cj > 0.f) {
                    int sj = __shfl(s, wbase + jj, 64);
                    uint4 w = ((const uint4*)(Wx + (size_t)sj * 128))[gl];
                    float4 lo, hi; unpack8(w, lo, hi);
                    acc0.x = fmaf(cj, lo.x, acc0.x); acc0.y = fmaf(cj, lo.y, acc0.y);
                    acc0.z = fmaf(cj, lo.z, acc0.z); acc0.w = fmaf(cj, lo.w, acc0.w);
                    acc1.x = fmaf(cj, hi.x, acc1.x); acc1.y = fmaf(cj, hi.y, acc1.y);
                    acc1.z = fmaf(cj, hi.z, acc1.z); acc1.w = fmaf(cj, hi.w, acc1.w);
                }
            }
        }
        // x1 = elu(acc/4)
        acc0.x *= 0.25f; acc0.y *= 0.25f; acc0.z *= 0.25f; acc0.w *= 0.25f;
        acc1.x *= 0.25f; acc1.y *= 0.25f; acc1.z *= 0.25f; acc1.w *= 0.25f;
        acc0.x = acc0.x > 0.f ? acc0.x : expm1f(acc0.x);
        acc0.y = acc0.y > 0.f ? acc0.y : expm1f(acc0.y);
        acc0.z = acc0.z > 0.f ? acc0.z : expm1f(acc0.z);
        acc0.w = acc0.w > 0.f ? acc0.w : expm1f(acc0.w);
        acc1.x = acc1.x > 0.f ? acc1.x : expm1f(acc1.x);
        acc1.y = acc1.y > 0.f ? acc1.y : expm1f(acc1.y);
        acc1.z = acc1.z > 0.f ? acc1.z : expm1f(acc1.z);
        acc1.w = acc1.w > 0.f ? acc1.w : expm1f(acc1.w);

        float xo[8] = {acc0.x,acc0.y,acc0.z,acc0.w, acc1.x,acc1.y,acc1.z,acc1.w};

        // Wx2[n][8gl..8gl+8) = sum_k x1[k] * W2[k][c], x1 broadcast via shfl
        float4 wa0 = {0,0,0,0}, wa1 = {0,0,0,0};
        const uint4* w2v4 = (const uint4*)w2s;
#pragma unroll 2
        for (int j = 0; j < 16; ++j) {
            int src = wbase + j;
            float xk0 = __shfl(xo[0], src, 64);
            float xk1 = __shfl(xo[1], src, 64);
            float xk2 = __shfl(xo[2], src, 64);
            float xk3 = __shfl(xo[3], src, 64);
            float xk4 = __shfl(xo[4], src, 64);
            float xk5 = __shfl(xo[5], src, 64);
            float xk6 = __shfl(xo[6], src, 64);
            float xk7 = __shfl(xo[7], src, 64);
            float xks[8] = {xk0,xk1,xk2,xk3,xk4,xk5,xk6,xk7};
#pragma unroll
            for (int e = 0; e < 8; ++e) {
                uint4 w = w2v4[(8*j + e) * 16 + gl];
                float4 lo, hi; unpack8(w, lo, hi);
                float xv = xks[e];
                wa0.x = fmaf(xv, lo.x, wa0.x); wa0.y = fmaf(xv, lo.y, wa0.y);
                wa0.z = fmaf(xv, lo.z, wa0.z); wa0.w = fmaf(xv, lo.w, wa0.w);
                wa1.x = fmaf(xv, hi.x, wa1.x); wa1.y = fmaf(xv, hi.y, wa1.y);
                wa1.z = fmaf(xv, hi.z, wa1.z); wa1.w = fmaf(xv, hi.w, wa1.w);
            }
        }
        // att2 partials over own k-range (x values in regs)
        float aacc[8] = {0,0,0,0,0,0,0,0};
#pragma unroll
        for (int kk = 0; kk < 8; ++kk) {
            const float* mrow = &m2p[(8 * gl + kk) * 9];
            float xv = xo[kk];
#pragma unroll
            for (int h = 0; h < 8; ++h) aacc[h] = fmaf(xv, mrow[h], aacc[h]);
        }
#pragma unroll
        for (int off = 8; off; off >>= 1) {
#pragma unroll
            for (int h = 0; h < 8; ++h) aacc[h] += __shfl_xor(aacc[h], off, 64);
        }
        if (nv) {
            unsigned short* wrow = Wx2 + (size_t)n * 128 + 8 * gl;
            uint4 o;
            o.x = (unsigned)f2bf(wa0.x) | ((unsigned)f2bf(wa0.y) << 16);
            o.y = (unsigned)f2bf(wa0.z) | ((unsigned)f2bf(wa0.w) << 16);
            o.z = (unsigned)f2bf(wa1.x) | ((unsigned)f2bf(wa1.y) << 16);
            o.w = (unsigned)f2bf(wa1.z) | ((unsigned)f2bf(wa1.w) << 16);
            *(uint4*)wrow = o;
            if (gl == 0) {
                float4 o1; o1.x = aacc[0]; o1.y = aacc[1]; o1.z = aacc[2]; o1.w = aacc[3];
                float4 o2; o2.x = aacc[4]; o2.y = aacc[5]; o2.z = aacc[6]; o2.w = aacc[7];
                ((float4*)asrc2)[n] = o1;
                ((float4*)adst2)[n] = o2;
            }
        }
    }
}

// ---------------------------------------------------------------------------
// Fused GAT layer-2 aggregate + FC head (unchanged from r11).
// ---------------------------------------------------------------------------
__global__ __launch_bounds__(512, 8) void k_msg0(
    const int* __restrict__ rowptr, const int* __restrict__ esrc,
    const float* __restrict__ asrc, const float* __restrict__ adst,
    const unsigned short* __restrict__ Wx,
    const float* __restrict__ fc1w, const float* __restrict__ fc1b,
    const float* __restrict__ fc2w, const float* __restrict__ fc2b,
    float* __restrict__ out, int N)
{
    __shared__ float fc1s[8192];            // 32KB: fc1w [c][j]
    int tid = threadIdx.x;
    for (int i = tid; i < 8192; i += 512) fc1s[i] = fc1w[i];
    __syncthreads();

    int lane = tid & 63;
    int grp = lane >> 4;
    int gl = lane & 15;
    int wbase = lane & 48;
    int gw = (blockIdx.x * blockDim.x + tid) >> 6;
    int waves = (gridDim.x * blockDim.x) >> 6;

    float4 b1v = *(const float4*)&fc1b[4 * gl];
    float4 w2v = *(const float4*)&fc2w[4 * gl];
    float b2 = fc2b[0];

    for (int m = gw; m * 4 < N; m += waves) {
        int n = m * 4 + grp;
        bool nv = n < N;
        int beg = nv ? rowptr[n] : 0;
        int end = nv ? rowptr[n + 1] : 0;
        float4 ad = {0,0,0,0};
        if (nv) ad = ((const float4*)adst)[n];

        int e0 = beg + gl;
        bool v0 = e0 < end;
        int s0 = v0 ? esrc[e0] : 0;
        float4 a0 = ((const float4*)asrc)[s0];
        float x0 = v0 ? fexp(lrelu02(a0.x + ad.x)) : 0.f;
        float x1 = v0 ? fexp(lrelu02(a0.y + ad.y)) : 0.f;
        float x2 = v0 ? fexp(lrelu02(a0.z + ad.z)) : 0.f;
        float x3 = v0 ? fexp(lrelu02(a0.w + ad.w)) : 0.f;
        float d0 = x0, d1 = x1, d2 = x2, d3 = x3;
        for (int c = beg + 16; c < end; c += 16) {
            int e = c + gl;
            bool v = e < end;
            int s = v ? esrc[e] : 0;
            float4 a = ((const float4*)asrc)[s];
            if (v) {
                d0 += fexp(lrelu02(a.x + ad.x));
                d1 += fexp(lrelu02(a.y + ad.y));
                d2 += fexp(lrelu02(a.z + ad.z));
                d3 += fexp(lrelu02(a.w + ad.w));
            }
        }
#pragma unroll
        for (int off = 8; off; off >>= 1) {
            d0 += __shfl_xor(d0, off, 64);
            d1 += __shfl_xor(d1, off, 64);
            d2 += __shfl_xor(d2, off, 64);
            d3 += __shfl_xor(d3, off, 64);
        }
        float r0 = __builtin_amdgcn_rcpf(d0 + 2e-9f);
        float r1 = __builtin_amdgcn_rcpf(d1 + 2e-9f);
        float r2 = __builtin_amdgcn_rcpf(d2 + 2e-9f);
        float r3 = __builtin_amdgcn_rcpf(d3 + 2e-9f);

        float4 acc0 = {0,0,0,0}, acc1 = {0,0,0,0};
        float coef = x0*r0 + x1*r1 + x2*r2 + x3*r3;
#pragma unroll 4
        for (int jj = 0; jj < 16; ++jj) {
            float cj = __shfl(coef, wbase + jj, 64);
            if (cj > 0.f) {
                int sj = __shfl(s0, wbase + jj, 64);
                uint4 w = ((const uint4*)(Wx + (size_t)sj * 128))[gl];
                float4 lo, hi; unpack8(w, lo, hi);
                acc0.x = fmaf(cj, lo.x, acc0.x); acc0.y = fmaf(cj, lo.y, acc0.y);
                acc0.z = fmaf(cj, lo.z, acc0.z); acc0.w = fmaf(cj, lo.w, acc0.w);
                acc1.x = fmaf(cj, hi.x, acc1.x); acc1.y = fmaf(cj, hi.y, acc1.y);
                acc1.z = fmaf(cj, hi.z, acc1.z); acc1.w = fmaf(cj, hi.w, acc1.w);
            }
        }
        for (int c = beg + 16; c < end; c += 16) {
            int e = c + gl;
            bool v = e < end;
            int s = v ? esrc[e] : 0;
            float4 a = ((const float4*)asrc)[s];
            float cf = 0.f;
            if (v) {
                cf = fexp(lrelu02(a.x + ad.x)) * r0
                   + fexp(lrelu02(a.y + ad.y)) * r1
                   + fexp(lrelu02(a.z + ad.z)) * r2
                   + fexp(lrelu02(a.w + ad.w)) * r3;
            }
#pragma unroll 4
            for (int jj = 0; jj < 16; ++jj) {
                float cj = __shfl(cf, wbase + jj, 64);
                if (cj > 0.f) {
                    int sj = __shfl(s, wbase + jj, 64);
                    uint4 w = ((const uint4*)(Wx + (size_t)sj * 128))[gl];
                    float4 lo, hi; unpack8(w, lo, hi);
                    acc0.x = fmaf(cj, lo.x, acc0.x); acc0.y = fmaf(cj, lo.y, acc0.y);
                    acc0.z = fmaf(cj, lo.z, acc0.z); acc0.w = fmaf(cj, lo.w, acc0.w);
                    acc1.x = fmaf(cj, hi.x, acc1.x); acc1.y = fmaf(cj, hi.y, acc1.y);
                    acc1.z = fmaf(cj, hi.z, acc1.z); acc1.w = fmaf(cj, hi.w, acc1.w);
                }
            }
        }
        // x = elu(acc/4); h = relu(x@fc1+b1) (x broadcast via shfl); out = h@fc2+b2
        acc0.x *= 0.25f; acc0.y *= 0.25f; acc0.z *= 0.25f; acc0.w *= 0.25f;
        acc1.x *= 0.25f; acc1.y *= 0.25f; acc1.z *= 0.25f; acc1.w *= 0.25f;
        acc0.x = acc0.x > 0.f ? acc0.x : expm1f(acc0.x);
        acc0.y = acc0.y > 0.f ? acc0.y : expm1f(acc0.y);
        acc0.z = acc0.z > 0.f ? acc0.z : expm1f(acc0.z);
        acc0.w = acc0.w > 0.f ? acc0.w : expm1f(acc0.w);
        acc1.x = acc1.x > 0.f ? acc1.x : expm1f(acc1.x);
        acc1.y = acc1.y > 0.f ? acc1.y : expm1f(acc1.y);
        acc1.z = acc1.z > 0.f ? acc1.z : expm1f(acc1.z);
        acc1.w = acc1.w > 0.f ? acc1.w : expm1f(acc1.w);
        float xo[8] = {acc0.x,acc0.y,acc0.z,acc0.w, acc1.x,acc1.y,acc1.z,acc1.w};

        float4 hacc = b1v;
#pragma unroll 2
        for (int j = 0; j < 16; ++j) {
            int src = wbase + j;
            float xk0 = __shfl(xo[0], src, 64);
            float xk1 = __shfl(xo[1], src, 64);
            float xk2 = __shfl(xo[2], src, 64);
            float xk3 = __shfl(xo[3], src, 64);
            float xk4 = __shfl(xo[4], src, 64);
            float xk5 = __shfl(xo[5], src, 64);
            float xk6 = __shfl(xo[6], src, 64);
            float xk7 = __shfl(xo[7], src, 64);
            float xks[8] = {xk0,xk1,xk2,xk3,xk4,xk5,xk6,xk7};
#pragma unroll
            for (int e = 0; e < 8; ++e) {
                float4 w = *(const float4*)&fc1s[(8*j + e) * 64 + 4 * gl];
                hacc.x = fmaf(xks[e], w.x, hacc.x); hacc.y = fmaf(xks[e], w.y, hacc.y);
                hacc.z = fmaf(xks[e], w.z, hacc.z); hacc.w = fmaf(xks[e], w.w, hacc.w);
            }
        }
        float r = fmaxf(hacc.x, 0.f) * w2v.x + fmaxf(hacc.y, 0.f) * w2v.y
                + fmaxf(hacc.z, 0.f) * w2v.z + fmaxf(hacc.w, 0.f) * w2v.w;
#pragma unroll
        for (int off = 8; off; off >>= 1) r += __shfl_xor(r, off, 64);
        if (nv && gl == 0) out[n] = r + b2;
    }
}

extern "C" void kernel_launch(void* const* d_in, const int* in_sizes, int n_in,
                              void* d_out, int out_size, void* d_ws, size_t ws_size,
                              hipStream_t stream)
{
    const float* nf   = (const float*)d_in[0];
    const int*   ei   = (const int*)  d_in[1];
    const float* ts   = (const float*)d_in[2];
    const float* Wih0 = (const float*)d_in[3];
    const float* Whh0 = (const float*)d_in[4];
    const float* b0   = (const float*)d_in[5];
    const float* Wih1 = (const float*)d_in[6];
    const float* Whh1 = (const float*)d_in[7];
    const float* b1   = (const float*)d_in[8];
    const float* W1   = (const float*)d_in[9];
    const float* A1   = (const float*)d_in[10];
    const float* W2   = (const float*)d_in[11];
    const float* A2   = (const float*)d_in[12];
    const float* fc1w = (const float*)d_in[13];
    const float* fc1b = (const float*)d_in[14];
    const float* fc2w = (const float*)d_in[15];
    const float* fc2b = (const float*)d_in[16];

    int N = in_sizes[0] / 16;
    int E = in_sizes[1] / 2;
    int T = in_sizes[2] / 3;

    char* ws = (char*)d_ws;
    size_t off = 0;
    auto alloc = [&](size_t bytes) {
        char* p = ws + off;
        off = (off + bytes + 255) & ~(size_t)255;
        return p;
    };
    float* tsb    = (float*)alloc(512);
    float* attfix = (float*)alloc(64);
    int*   flags  = (int*)  alloc(64);
    float* m2g    = (float*)alloc(1024 * sizeof(float));
    float* asrc   = (float*)alloc((size_t)N * 4 * sizeof(float));
    float* adst   = (float*)alloc((size_t)N * 4 * sizeof(float));
    float* asrc2  = (float*)alloc((size_t)N * 4 * sizeof(float));
    float* adst2  = (float*)alloc((size_t)N * 4 * sizeof(float));
    int*   rowptr = (int*)  alloc((size_t)(N + 1) * sizeof(int));
    int*   esrc   = (int*)  alloc((size_t)E * sizeof(int));
    int*   epos   = (int*)  alloc((size_t)E * sizeof(int));
    int*   deg    = (int*)  alloc((size_t)N * sizeof(int));
    int*   bsum   = (int*)  alloc(512 * sizeof(int));
    unsigned short* bufA = (unsigned short*)alloc((size_t)N * 128 * sizeof(unsigned short));
    unsigned short* bufC = (unsigned short*)alloc((size_t)N * 128 * sizeof(unsigned short));

    int NCH = (N + 2047) / 2048;

    hipMemsetAsync(deg, 0, (size_t)N * sizeof(int), stream);
    hipMemsetAsync(flags, 0, 64, stream);

    // ---- mega-front: LSTM || (hist -> scan -> scatter) || att1P || Wxp(bf16) || M2 ----
    k_front<<<256, 512, 0, stream>>>(
        ts, Wih0, Whh0, b0, Wih1, Whh1, b1, W1, A1, W2, A2,
        tsb, attfix, m2g,
        ei, deg, epos, nf, bufA, asrc, adst,
        rowptr, bsum, esrc, flags,
        N, E, T, NCH);

    // ---- layer-1 aggregate + layer-2 projections (fused) ----
    k_msg1<<<1024, 512, 0, stream>>>(rowptr, esrc, asrc, adst, bufA, tsb, attfix,
                                     W2, m2g, bufC, asrc2, adst2, N);

    // ---- layer-2 aggregate + FC head (fused) ----
    k_msg0<<<1024, 512, 0, stream>>>(rowptr, esrc, asrc2, adst2, bufC,
                                     fc1w, fc1b, fc2w, fc2b, (float*)d_out, N);
}

// Round 13
// 506.542 us; speedup vs baseline: 1.9801x; 1.0091x over previous
//
#include <hip/hip_runtime.h>
#include <math.h>

#define DEV __device__ __forceinline__

#define LOG2E 1.4426950408889634f

typedef _Float16 h2v __attribute__((ext_vector_type(2)));

DEV float fexp(float x)  { return __builtin_amdgcn_exp2f(LOG2E * x); }
DEV float fsigm(float x) { return __builtin_amdgcn_rcpf(1.0f + __builtin_amdgcn_exp2f(-LOG2E * x)); }
DEV float ftanh(float x) { return 1.0f - 2.0f * __builtin_amdgcn_rcpf(__builtin_amdgcn_exp2f(2.0f * LOG2E * x) + 1.0f); }
DEV float lrelu02(float x) { return x > 0.0f ? x : 0.2f * x; }
DEV float fdot2(h2v a, h2v b, float c) { return __builtin_amdgcn_fdot2(a, b, c, false); }
DEV int aload(const int* p) {
    return __hip_atomic_load(p, __ATOMIC_RELAXED, __HIP_MEMORY_SCOPE_AGENT);
}
DEV void astore(int* p, int v) {
    __hip_atomic_store(p, v, __ATOMIC_RELAXED, __HIP_MEMORY_SCOPE_AGENT);
}
DEV unsigned short f2bf(float f) {
    unsigned u = __float_as_uint(f);
    return (unsigned short)((u + 0x7FFFu + ((u >> 16) & 1u)) >> 16);
}
DEV void unpack8(uint4 w, float4& lo, float4& hi) {
    lo.x = __uint_as_float(w.x << 16); lo.y = __uint_as_float(w.x & 0xFFFF0000u);
    lo.z = __uint_as_float(w.y << 16); lo.w = __uint_as_float(w.y & 0xFFFF0000u);
    hi.x = __uint_as_float(w.z << 16); hi.y = __uint_as_float(w.z & 0xFFFF0000u);
    hi.z = __uint_as_float(w.w << 16); hi.w = __uint_as_float(w.w & 0xFFFF0000u);
}
#define QB(v, ctrl) __int_as_float(__builtin_amdgcn_mov_dpp(__float_as_int(v), ctrl, 0xF, 0xF, true))

// ---------------------------------------------------------------------------
// Mega-front. LSTM now uses packed-f16 weights + v_dot2_f32_f16:
// seg1's 128 f32 weight regs -> 64 packed VGPRs (fits; no spill) and the
// 128-FMA row dot -> 64 dot2 issues. h-state in LDS as _Float16.
// ---------------------------------------------------------------------------
__global__ __launch_bounds__(512, 2) void k_front(
    const float* __restrict__ ts,
    const float* __restrict__ Wih0, const float* __restrict__ Whh0, const float* __restrict__ b0,
    const float* __restrict__ Wih1, const float* __restrict__ Whh1, const float* __restrict__ b1,
    const float* __restrict__ W1, const float* __restrict__ A1,
    const float* __restrict__ W2, const float* __restrict__ A2,
    float* __restrict__ tsb, float* __restrict__ attfix, float* __restrict__ m2g,
    const int* __restrict__ ei, int* __restrict__ deg, int* __restrict__ epos,
    const float* __restrict__ nf, unsigned short* __restrict__ Wxp,
    float* __restrict__ asrcP, float* __restrict__ adstP,
    int* __restrict__ rowptr, int* __restrict__ bsum,
    int* __restrict__ esrc, int* __restrict__ flags,
    int N, int E, int T, int NCH)
{
    __shared__ __align__(16) _Float16 h0h[2][64], h1h[2][64];
    __shared__ __align__(16) float tsbig[21504];   // 84KB pad -> 1 block/CU
    __shared__ float m1s[128];
    __shared__ int iwsum[8];
    __shared__ int stmp[512];
    const int tid = threadIdx.x;
    const int bid = blockIdx.x;

    auto signalflag = [&](int* f) {
        __syncthreads();
        if (tid == 0) {
            __threadfence();
            __hip_atomic_fetch_add(f, 1, __ATOMIC_RELEASE, __HIP_MEMORY_SCOPE_AGENT);
        }
    };
    auto waitflag = [&](int* f, int tgt) {
        if (tid == 0) {
            while (__hip_atomic_load(f, __ATOMIC_ACQUIRE, __HIP_MEMORY_SCOPE_AGENT) < tgt)
                __builtin_amdgcn_s_sleep(8);
        }
        __syncthreads();
    };

    if (bid == 0) {
        // ================= LSTM =================
        const int seg = tid >> 8;
        const int idx = tid & 255;
        const int u = idx >> 2;
        const int q = idx & 3;
        const int row = q * 64 + u;
        float* tss = tsbig;

        for (int i = tid; i < 3 * T && i < 512; i += 512) tss[i] = ts[i];
        if (tid < 64) {
            h0h[0][tid] = (_Float16)0.f; h0h[1][tid] = (_Float16)0.f;
            h1h[0][tid] = (_Float16)0.f; h1h[1][tid] = (_Float16)0.f;
        }
        __syncthreads();

        if (seg == 0) {
            // ----- layer 0: 32 packed-f16 weight regs -----
            h2v wa[32];
            float wih[3];
            float bias = b0[row];
            wih[0] = Wih0[row*3+0]; wih[1] = Wih0[row*3+1]; wih[2] = Wih0[row*3+2];
#pragma unroll
            for (int k = 0; k < 32; k++) {
                h2v w; w.x = (_Float16)Whh0[row*64 + 2*k]; w.y = (_Float16)Whh0[row*64 + 2*k + 1];
                wa[k] = w;
            }
            float creg = 0.0f;
            for (int k = 0; k <= T; ++k) {
                if (k < T) {
                    const h2v* hp = (const h2v*)h0h[(k + 1) & 1];
                    float a0 = bias, a1 = 0.f, a2 = 0.f, a3 = 0.f;
                    a0 = fmaf(tss[3*k+0], wih[0], a0);
                    a1 = fmaf(tss[3*k+1], wih[1], a1);
                    a2 = fmaf(tss[3*k+2], wih[2], a2);
#pragma unroll
                    for (int p = 0; p < 32; p += 4) {
                        a0 = fdot2(wa[p+0], hp[p+0], a0);
                        a1 = fdot2(wa[p+1], hp[p+1], a1);
                        a2 = fdot2(wa[p+2], hp[p+2], a2);
                        a3 = fdot2(wa[p+3], hp[p+3], a3);
                    }
                    float mine = (a0 + a1) + (a2 + a3);
                    float gi = QB(mine, 0x00);
                    float gf = QB(mine, 0x55);
                    float gg = QB(mine, 0xAA);
                    float go = QB(mine, 0xFF);
                    creg = fsigm(gf) * creg + fsigm(gi) * ftanh(gg);
                    float h = fsigm(go) * ftanh(creg);
                    if (q == 0) h0h[k & 1][u] = (_Float16)h;
                }
                __syncthreads();
            }
            // epilogue (tid<128 subset of seg0)
            if (tid < 128) {
                const _Float16* hf = h1h[(T - 1) & 1];
                float acc = 0.f;
#pragma unroll
                for (int kk = 0; kk < 64; kk++)
                    acc = fmaf((float)hf[kk], W1[(16 + kk) * 128 + tid], acc);
                tsb[tid] = acc;
                m1s[tid] = acc;
            }
            __syncthreads();
            if (tid < 8) {
                int half = tid >> 2, h = tid & 3;
                const float* a1p = A1 + (size_t)half * 512 + h;
                float acc = 0.f;
                for (int c = 0; c < 128; c++) acc = fmaf(m1s[c], a1p[c * 4], acc);
                attfix[tid] = acc;
            }
        } else {
            // ----- layer 1: 64 packed-f16 weight regs (Whh1 + Wih1) -----
            h2v wa[32], wb[32];
            float bias = b1[row];
#pragma unroll
            for (int k = 0; k < 32; k++) {
                h2v w; w.x = (_Float16)Whh1[row*64 + 2*k]; w.y = (_Float16)Whh1[row*64 + 2*k + 1];
                wa[k] = w;
            }
#pragma unroll
            for (int k = 0; k < 32; k++) {
                h2v w; w.x = (_Float16)Wih1[row*64 + 2*k]; w.y = (_Float16)Wih1[row*64 + 2*k + 1];
                wb[k] = w;
            }
            float creg = 0.0f;
            for (int k = 0; k <= T; ++k) {
                if (k >= 1) {
                    const h2v* h1p = (const h2v*)h1h[k & 1];
                    const h2v* h0p = (const h2v*)h0h[(k + 1) & 1];
                    float a0 = bias, a1 = 0.f, a2 = 0.f, a3 = 0.f;
#pragma unroll
                    for (int p = 0; p < 32; p += 4) {
                        a0 = fdot2(wa[p+0], h1p[p+0], a0);
                        a1 = fdot2(wa[p+1], h1p[p+1], a1);
                        a2 = fdot2(wa[p+2], h1p[p+2], a2);
                        a3 = fdot2(wa[p+3], h1p[p+3], a3);
                    }
#pragma unroll
                    for (int p = 0; p < 32; p += 4) {
                        a0 = fdot2(wb[p+0], h0p[p+0], a0);
                        a1 = fdot2(wb[p+1], h0p[p+1], a1);
                        a2 = fdot2(wb[p+2], h0p[p+2], a2);
                        a3 = fdot2(wb[p+3], h0p[p+3], a3);
                    }
                    float mine = (a0 + a1) + (a2 + a3);
                    float gi = QB(mine, 0x00);
                    float gf = QB(mine, 0x55);
                    float gg = QB(mine, 0xAA);
                    float go = QB(mine, 0xFF);
                    creg = fsigm(gf) * creg + fsigm(gi) * ftanh(gg);
                    float h = fsigm(go) * ftanh(creg);
                    if (q == 0) h1h[(k + 1) & 1][u] = (_Float16)h;
                }
                __syncthreads();
            }
            __syncthreads();   // match seg0's epilogue barrier
        }
        return;
    }

    // ================= workers =================
    const int W = gridDim.x - 1;
    const int wid = bid - 1;

    {
        int g = wid * 512 + tid, stride = W * 512;
        for (int e = g; e < E; e += stride)
            epos[e] = atomicAdd(&deg[ei[E + e]], 1);
    }
    signalflag(&flags[0]);

    if (wid < NCH) {
        waitflag(&flags[0], W);
        int base = wid * 2048 + tid * 4;
        int d0 = base + 0 < N ? aload(&deg[base + 0]) : 0;
        int d1 = base + 1 < N ? aload(&deg[base + 1]) : 0;
        int d2 = base + 2 < N ? aload(&deg[base + 2]) : 0;
        int d3 = base + 3 < N ? aload(&deg[base + 3]) : 0;
        int tsum = d0 + d1 + d2 + d3;
        int lane = tid & 63, wv = tid >> 6;
        int incl = tsum;
#pragma unroll
        for (int off = 1; off < 64; off <<= 1) {
            int t = __shfl_up(incl, off, 64);
            if (lane >= off) incl += t;
        }
        if (lane == 63) iwsum[wv] = incl;
        __syncthreads();
        int woff = 0;
#pragma unroll
        for (int w = 0; w < 8; w++) if (w < wv) woff += iwsum[w];
        int tex = woff + incl - tsum;
        if (base + 0 < N) rowptr[base + 0] = tex;
        if (base + 1 < N) rowptr[base + 1] = tex + d0;
        if (base + 2 < N) rowptr[base + 2] = tex + d0 + d1;
        if (base + 3 < N) rowptr[base + 3] = tex + d0 + d1 + d2;
        if (tid == 511) astore(&bsum[wid], woff + incl);
        signalflag(&flags[1]);
        waitflag(&flags[2], 1);
        int off2 = aload(&bsum[wid]);
#pragma unroll
        for (int i = 0; i < 4; i++) {
            int idx = base + i;
            if (idx < N) {
                int v = rowptr[idx] + off2;
                astore(&rowptr[idx], v);
            }
        }
        if (wid == 0 && tid == 0) astore(&rowptr[N], E);
        signalflag(&flags[3]);
    } else if (wid == NCH) {
        waitflag(&flags[1], NCH);
        int v = tid < NCH ? aload(&bsum[tid]) : 0;
        stmp[tid] = v;
        __syncthreads();
        for (int off = 1; off < 512; off <<= 1) {
            int t = (tid >= off) ? stmp[tid - off] : 0;
            __syncthreads();
            stmp[tid] += t;
            __syncthreads();
        }
        if (tid < NCH) astore(&bsum[tid], stmp[tid] - v);
        signalflag(&flags[2]);
        // ---- compute M2 = W2@A2 (128 x 8) while LSTM still runs ----
#pragma unroll
        for (int e = tid; e < 1024; e += 512) {
            int k = e >> 3, h8 = e & 7, half = h8 >> 2, h = h8 & 3;
            const float* w2p = W2 + (size_t)k * 128;
            const float* a2p = A2 + (size_t)half * 512 + h;
            float acc = 0.f;
            for (int c = 0; c < 128; c++) acc = fmaf(w2p[c], a2p[c * 4], acc);
            m2g[e] = acc;
        }
    } else {
        const int AW = W - NCH - 1;
        const int aw = wid - NCH - 1;
        if (tid < 128) {
            int k = tid >> 3, h8 = tid & 7, half = h8 >> 2, h = h8 & 3;
            const float* a1p = A1 + (size_t)half * 512 + h;
            const float* w1p = W1 + (size_t)k * 128;
            float acc = 0.f;
            for (int c = 0; c < 128; c++) acc = fmaf(w1p[c], a1p[c * 4], acc);
            m1s[tid] = acc;
        }
        __syncthreads();
        float m1r[128];
#pragma unroll
        for (int i = 0; i < 128; i++) m1r[i] = m1s[i];
        {
            int gt = aw * 512 + tid;
            int tstride = AW * 512;
            for (int n = gt; n < N; n += tstride) {
                const float4* nfr = (const float4*)(nf + (size_t)n * 16);
                float4 f0 = nfr[0], f1 = nfr[1], f2 = nfr[2], f3 = nfr[3];
                float xk[16] = {f0.x,f0.y,f0.z,f0.w, f1.x,f1.y,f1.z,f1.w,
                                f2.x,f2.y,f2.z,f2.w, f3.x,f3.y,f3.z,f3.w};
                float as0=0,as1=0,as2=0,as3=0, ad0=0,ad1=0,ad2=0,ad3=0;
#pragma unroll
                for (int k = 0; k < 16; k++) {
                    float xv = xk[k];
                    as0 = fmaf(xv, m1r[k*8+0], as0); as1 = fmaf(xv, m1r[k*8+1], as1);
                    as2 = fmaf(xv, m1r[k*8+2], as2); as3 = fmaf(xv, m1r[k*8+3], as3);
                    ad0 = fmaf(xv, m1r[k*8+4], ad0); ad1 = fmaf(xv, m1r[k*8+5], ad1);
                    ad2 = fmaf(xv, m1r[k*8+6], ad2); ad3 = fmaf(xv, m1r[k*8+7], ad3);
                }
                float4 o1; o1.x=as0; o1.y=as1; o1.z=as2; o1.w=as3;
                float4 o2; o2.x=ad0; o2.y=ad1; o2.z=ad2; o2.w=ad3;
                ((float4*)asrcP)[n] = o1;
                ((float4*)adstP)[n] = o2;
            }
        }
        {
            int lane = tid & 63;
            int bw = aw * 8 + (tid >> 6);
            int half = bw & 1;
            int col = lane + 64 * half;
            float wreg[16];
#pragma unroll
            for (int k = 0; k < 16; k++) wreg[k] = W1[k * 128 + col];
            int nstride = AW * 4;
            for (int n = (bw >> 1); n < N; n += nstride) {
                int nu = __builtin_amdgcn_readfirstlane(n);
                const float4* xr = (const float4*)(nf + (size_t)nu * 16);
                float4 x0 = xr[0], x1 = xr[1], x2 = xr[2], x3 = xr[3];
                float acc = 0.f;
                acc = fmaf(x0.x, wreg[0],  acc); acc = fmaf(x0.y, wreg[1],  acc);
                acc = fmaf(x0.z, wreg[2],  acc); acc = fmaf(x0.w, wreg[3],  acc);
                acc = fmaf(x1.x, wreg[4],  acc); acc = fmaf(x1.y, wreg[5],  acc);
                acc = fmaf(x1.z, wreg[6],  acc); acc = fmaf(x1.w, wreg[7],  acc);
                acc = fmaf(x2.x, wreg[8],  acc); acc = fmaf(x2.y, wreg[9],  acc);
                acc = fmaf(x2.z, wreg[10], acc); acc = fmaf(x2.w, wreg[11], acc);
                acc = fmaf(x3.x, wreg[12], acc); acc = fmaf(x3.y, wreg[13], acc);
                acc = fmaf(x3.z, wreg[14], acc); acc = fmaf(x3.w, wreg[15], acc);
                Wxp[(size_t)nu * 128 + col] = f2bf(acc);
            }
        }
    }

    waitflag(&flags[3], NCH);
    {
        int g = wid * 512 + tid, stride = W * 512;
        for (int e = g; e < E; e += stride) {
            int s = ei[e], d = ei[E + e];
            esrc[aload(&rowptr[d]) + epos[e]] = s;
        }
    }
}

// ---------------------------------------------------------------------------
// Fused GAT layer-1 aggregate + layer-2 projections.
// __launch_bounds__(512,6): VGPR cap ~85 (kernel needs ~70 -> NO spill,
// unlike r12's (512,8) which clamped to 32 and spilled 290MB of scratch);
// LDS 37KB -> 3 blocks/CU = 75% occupancy.
// ---------------------------------------------------------------------------
__global__ __launch_bounds__(512, 6) void k_msg1(
    const int* __restrict__ rowptr, const int* __restrict__ esrc,
    const float* __restrict__ asrc, const float* __restrict__ adst,
    const unsigned short* __restrict__ Wx, const float* __restrict__ tsb,
    const float* __restrict__ attfix,
    const float* __restrict__ W2, const float* __restrict__ m2g,
    unsigned short* __restrict__ Wx2, float* __restrict__ asrc2,
    float* __restrict__ adst2, int N)
{
    __shared__ unsigned short w2s[16384];   // 32KB: W2 bf16 [k][c]
    __shared__ float m2p[128 * 9];          // padded M2
    int tid = threadIdx.x;
    for (int i = tid; i < 16384; i += 512) w2s[i] = f2bf(W2[i]);
    for (int i = tid; i < 1024; i += 512) m2p[(i >> 3) * 9 + (i & 7)] = m2g[i];
    __syncthreads();

    int lane = tid & 63;
    int grp = lane >> 4;
    int gl = lane & 15;
    int wbase = lane & 48;
    int gw = (blockIdx.x * blockDim.x + tid) >> 6;
    int waves = (gridDim.x * blockDim.x) >> 6;

    float4 tb0 = ((const float4*)tsb)[gl*2];
    float4 tb1 = ((const float4*)tsb)[gl*2+1];
    float cc0 = attfix[0] + attfix[4];
    float cc1 = attfix[1] + attfix[5];
    float cc2 = attfix[2] + attfix[6];
    float cc3 = attfix[3] + attfix[7];

    for (int m = gw; m * 4 < N; m += waves) {
        int n = m * 4 + grp;
        bool nv = n < N;
        int beg = nv ? rowptr[n] : 0;
        int end = nv ? rowptr[n + 1] : 0;
        float4 ad = {0,0,0,0};
        if (nv) ad = ((const float4*)adst)[n];
        ad.x += cc0; ad.y += cc1; ad.z += cc2; ad.w += cc3;

        int e0 = beg + gl;
        bool v0 = e0 < end;
        int s0 = v0 ? esrc[e0] : 0;
        float4 a0 = ((const float4*)asrc)[s0];
        float x0 = v0 ? fexp(lrelu02(a0.x + ad.x)) : 0.f;
        float x1 = v0 ? fexp(lrelu02(a0.y + ad.y)) : 0.f;
        float x2 = v0 ? fexp(lrelu02(a0.z + ad.z)) : 0.f;
        float x3 = v0 ? fexp(lrelu02(a0.w + ad.w)) : 0.f;
        float d0 = x0, d1 = x1, d2 = x2, d3 = x3;
        for (int c = beg + 16; c < end; c += 16) {
            int e = c + gl;
            bool v = e < end;
            int s = v ? esrc[e] : 0;
            float4 a = ((const float4*)asrc)[s];
            if (v) {
                d0 += fexp(lrelu02(a.x + ad.x));
                d1 += fexp(lrelu02(a.y + ad.y));
                d2 += fexp(lrelu02(a.z + ad.z));
                d3 += fexp(lrelu02(a.w + ad.w));
            }
        }
#pragma unroll
        for (int off = 8; off; off >>= 1) {
            d0 += __shfl_xor(d0, off, 64);
            d1 += __shfl_xor(d1, off, 64);
            d2 += __shfl_xor(d2, off, 64);
            d3 += __shfl_xor(d3, off, 64);
        }
        float r0 = __builtin_amdgcn_rcpf(d0 + 2e-9f);
        float r1 = __builtin_amdgcn_rcpf(d1 + 2e-9f);
        float r2 = __builtin_amdgcn_rcpf(d2 + 2e-9f);
        float r3 = __builtin_amdgcn_rcpf(d3 + 2e-9f);

        float csum = d0*r0 + d1*r1 + d2*r2 + d3*r3;
        float4 acc0, acc1;
        acc0.x = csum*tb0.x; acc0.y = csum*tb0.y; acc0.z = csum*tb0.z; acc0.w = csum*tb0.w;
        acc1.x = csum*tb1.x; acc1.y = csum*tb1.y; acc1.z = csum*tb1.z; acc1.w = csum*tb1.w;

        float coef = x0*r0 + x1*r1 + x2*r2 + x3*r3;
#pragma unroll 4
        for (int jj = 0; jj < 16; ++jj) {
            float cj = __shfl(coef, wbase + jj, 64);
            if (cj > 0.f) {
                int sj = __shfl(s0, wbase + jj, 64);
                uint4 w = ((const uint4*)(Wx + (size_t)sj * 128))[gl];
                float4 lo, hi; unpack8(w, lo, hi);
                acc0.x = fmaf(cj, lo.x, acc0.x); acc0.y = fmaf(cj, lo.y, acc0.y);
                acc0.z = fmaf(cj, lo.z, acc0.z); acc0.w = fmaf(cj, lo.w, acc0.w);
                acc1.x = fmaf(cj, hi.x, acc1.x); acc1.y = fmaf(cj, hi.y, acc1.y);
                acc1.z = fmaf(cj, hi.z, acc1.z); acc1.w = fmaf(cj, hi.w, acc1.w);
            }
        }
        for (int c = beg + 16; c < end; c += 16) {
            int e = c + gl;
            bool v = e < end;
            int s = v ? esrc[e] : 0;
            float4 a = ((const float4*)asrc)[s];
            float cf = 0.f;
            if (v) {
                cf = fexp(lrelu02(a.x + ad.x)) * r0
                   + fexp(lrelu02(a.y + ad.y)) * r1
                   + fexp(lrelu02(a.z + ad.z)) * r2
                   + fexp(lrelu02(a.w + ad.w)) * r3;
            }
#pragma unroll 4
            for (int jj = 0; jj < 16; ++jj) {
                float cj = __shfl(cf, wbase + jj, 64);
                if (cj > 0.f) {
                    int sj = __shfl(s, wbase + jj, 64);
                    uint4 w = ((const uint4*)(Wx + (size_t)sj * 128))[gl];
                    float4 lo, hi; unpack8(w, lo, hi);
                    acc0.x = fmaf(cj, lo.x, acc0.x); acc0.y = fmaf(cj, lo.y, acc0.y);
                    acc0.z = fmaf(cj, lo.z, acc0.z); acc0.w = fmaf(cj, lo.w, acc0.w);
                    acc1.x = fmaf(cj, hi.x, acc1.x); acc1.y = fmaf(cj, hi.y, acc1.y);
                    acc1.z = fmaf(cj, hi.z, acc1.z); acc1.w = fmaf(cj, hi.w, acc1.w);
                }
            }
        }
        // x1 = elu(acc/4)
        acc0.x *= 0.25f; acc0.y *= 0.25f; acc0.z *= 0.25f; acc0.w *= 0.25f;
        acc1.x *= 0.25f; acc1.y *= 0.25f; acc1.z *= 0.25f; acc1.w *= 0.25f;
        acc0.x = acc0.x > 0.f ? acc0.x : expm1f(acc0.x);
        acc0.y = acc0.y > 0.f ? acc0.y : expm1f(acc0.y);
        acc0.z = acc0.z > 0.f ? acc0.z : expm1f(acc0.z);
        acc0.w = acc0.w > 0.f ? acc0.w : expm1f(acc0.w);
        acc1.x = acc1.x > 0.f ? acc1.x : expm1f(acc1.x);
        acc1.y = acc1.y > 0.f ? acc1.y : expm1f(acc1.y);
        acc1.z = acc1.z > 0.f ? acc1.z : expm1f(acc1.z);
        acc1.w = acc1.w > 0.f ? acc1.w : expm1f(acc1.w);

        float xo[8] = {acc0.x,acc0.y,acc0.z,acc0.w, acc1.x,acc1.y,acc1.z,acc1.w};

        // Wx2[n][8gl..8gl+8) = sum_k x1[k] * W2[k][c], x1 broadcast via shfl
        float4 wa0 = {0,0,0,0}, wa1 = {0,0,0,0};
        const uint4* w2v4 = (const uint4*)w2s;
#pragma unroll 2
        for (int j = 0; j < 16; ++j) {
            int src = wbase + j;
            float xk0 = __shfl(xo[0], src, 64);
            float xk1 = __shfl(xo[1], src, 64);
            float xk2 = __shfl(xo[2], src, 64);
            float xk3 = __shfl(xo[3], src, 64);
            float xk4 = __shfl(xo[4], src, 64);
            float xk5 = __shfl(xo[5], src, 64);
            float xk6 = __shfl(xo[6], src, 64);
            float xk7 = __shfl(xo[7], src, 64);
            float xks[8] = {xk0,xk1,xk2,xk3,xk4,xk5,xk6,xk7};
#pragma unroll
            for (int e = 0; e < 8; ++e) {
                uint4 w = w2v4[(8*j + e) * 16 + gl];
                float4 lo, hi; unpack8(w, lo, hi);
                float xv = xks[e];
                wa0.x = fmaf(xv, lo.x, wa0.x); wa0.y = fmaf(xv, lo.y, wa0.y);
                wa0.z = fmaf(xv, lo.z, wa0.z); wa0.w = fmaf(xv, lo.w, wa0.w);
                wa1.x = fmaf(xv, hi.x, wa1.x); wa1.y = fmaf(xv, hi.y, wa1.y);
                wa1.z = fmaf(xv, hi.z, wa1.z); wa1.w = fmaf(xv, hi.w, wa1.w);
            }
        }
        // att2 partials over own k-range (x values in regs)
        float aacc[8] = {0,0,0,0,0,0,0,0};
#pragma unroll
        for (int kk = 0; kk < 8; ++kk) {
            const float* mrow = &m2p[(8 * gl + kk) * 9];
            float xv = xo[kk];
#pragma unroll
            for (int h = 0; h < 8; ++h) aacc[h] = fmaf(xv, mrow[h], aacc[h]);
        }
#pragma unroll
        for (int off = 8; off; off >>= 1) {
#pragma unroll
            for (int h = 0; h < 8; ++h) aacc[h] += __shfl_xor(aacc[h], off, 64);
        }
        if (nv) {
            unsigned short* wrow = Wx2 + (size_t)n * 128 + 8 * gl;
            uint4 o;
            o.x = (unsigned)f2bf(wa0.x) | ((unsigned)f2bf(wa0.y) << 16);
            o.y = (unsigned)f2bf(wa0.z) | ((unsigned)f2bf(wa0.w) << 16);
            o.z = (unsigned)f2bf(wa1.x) | ((unsigned)f2bf(wa1.y) << 16);
            o.w = (unsigned)f2bf(wa1.z) | ((unsigned)f2bf(wa1.w) << 16);
            *(uint4*)wrow = o;
            if (gl == 0) {
                float4 o1; o1.x = aacc[0]; o1.y = aacc[1]; o1.z = aacc[2]; o1.w = aacc[3];
                float4 o2; o2.x = aacc[4]; o2.y = aacc[5]; o2.z = aacc[6]; o2.w = aacc[7];
                ((float4*)asrc2)[n] = o1;
                ((float4*)adst2)[n] = o2;
            }
        }
    }
}

// ---------------------------------------------------------------------------
// Fused GAT layer-2 aggregate + FC head. (512,6): no spill, high occupancy.
// ---------------------------------------------------------------------------
__global__ __launch_bounds__(512, 6) void k_msg0(
    const int* __restrict__ rowptr, const int* __restrict__ esrc,
    const float* __restrict__ asrc, const float* __restrict__ adst,
    const unsigned short* __restrict__ Wx,
    const float* __restrict__ fc1w, const float* __restrict__ fc1b,
    const float* __restrict__ fc2w, const float* __restrict__ fc2b,
    float* __restrict__ out, int N)
{
    __shared__ float fc1s[8192];            // 32KB: fc1w [c][j]
    int tid = threadIdx.x;
    for (int i = tid; i < 8192; i += 512) fc1s[i] = fc1w[i];
    __syncthreads();

    int lane = tid & 63;
    int grp = lane >> 4;
    int gl = lane & 15;
    int wbase = lane & 48;
    int gw = (blockIdx.x * blockDim.x + tid) >> 6;
    int waves = (gridDim.x * blockDim.x) >> 6;

    float4 b1v = *(const float4*)&fc1b[4 * gl];
    float4 w2v = *(const float4*)&fc2w[4 * gl];
    float b2 = fc2b[0];

    for (int m = gw; m * 4 < N; m += waves) {
        int n = m * 4 + grp;
        bool nv = n < N;
        int beg = nv ? rowptr[n] : 0;
        int end = nv ? rowptr[n + 1] : 0;
        float4 ad = {0,0,0,0};
        if (nv) ad = ((const float4*)adst)[n];

        int e0 = beg + gl;
        bool v0 = e0 < end;
        int s0 = v0 ? esrc[e0] : 0;
        float4 a0 = ((const float4*)asrc)[s0];
        float x0 = v0 ? fexp(lrelu02(a0.x + ad.x)) : 0.f;
        float x1 = v0 ? fexp(lrelu02(a0.y + ad.y)) : 0.f;
        float x2 = v0 ? fexp(lrelu02(a0.z + ad.z)) : 0.f;
        float x3 = v0 ? fexp(lrelu02(a0.w + ad.w)) : 0.f;
        float d0 = x0, d1 = x1, d2 = x2, d3 = x3;
        for (int c = beg + 16; c < end; c += 16) {
            int e = c + gl;
            bool v = e < end;
            int s = v ? esrc[e] : 0;
            float4 a = ((const float4*)asrc)[s];
            if (v) {
                d0 += fexp(lrelu02(a.x + ad.x));
                d1 += fexp(lrelu02(a.y + ad.y));
                d2 += fexp(lrelu02(a.z + ad.z));
                d3 += fexp(lrelu02(a.w + ad.w));
            }
        }
#pragma unroll
        for (int off = 8; off; off >>= 1) {
            d0 += __shfl_xor(d0, off, 64);
            d1 += __shfl_xor(d1, off, 64);
            d2 += __shfl_xor(d2, off, 64);
            d3 += __shfl_xor(d3, off, 64);
        }
        float r0 = __builtin_amdgcn_rcpf(d0 + 2e-9f);
        float r1 = __builtin_amdgcn_rcpf(d1 + 2e-9f);
        float r2 = __builtin_amdgcn_rcpf(d2 + 2e-9f);
        float r3 = __builtin_amdgcn_rcpf(d3 + 2e-9f);

        float4 acc0 = {0,0,0,0}, acc1 = {0,0,0,0};
        float coef = x0*r0 + x1*r1 + x2*r2 + x3*r3;
#pragma unroll 4
        for (int jj = 0; jj < 16; ++jj) {
            float cj = __shfl(coef, wbase + jj, 64);
            if (cj > 0.f) {
                int sj = __shfl(s0, wbase + jj, 64);
                uint4 w = ((const uint4*)(Wx + (size_t)sj * 128))[gl];
                float4 lo, hi; unpack8(w, lo, hi);
                acc0.x = fmaf(cj, lo.x, acc0.x); acc0.y = fmaf(cj, lo.y, acc0.y);
                acc0.z = fmaf(cj, lo.z, acc0.z); acc0.w = fmaf(cj, lo.w, acc0.w);
                acc1.x = fmaf(cj, hi.x, acc1.x); acc1.y = fmaf(cj, hi.y, acc1.y);
                acc1.z = fmaf(cj, hi.z, acc1.z); acc1.w = fmaf(cj, hi.w, acc1.w);
            }
        }
        for (int c = beg + 16; c < end; c += 16) {
            int e = c + gl;
            bool v = e < end;
            int s = v ? esrc[e] : 0;
            float4 a = ((const float4*)asrc)[s];
            float cf = 0.f;
            if (v) {
                cf = fexp(lrelu02(a.x + ad.x)) * r0
                   + fexp(lrelu02(a.y + ad.y)) * r1
                   + fexp(lrelu02(a.z + ad.z)) * r2
                   + fexp(lrelu02(a.w + ad.w)) * r3;
            }
#pragma unroll 4
            for (int jj = 0; jj < 16; ++jj) {
                float cj = __shfl(cf, wbase + jj, 64);
                if (cj > 0.f) {
                    int sj = __shfl(s, wbase + jj, 64);
                    uint4 w = ((const uint4*)(Wx + (size_t)sj * 128))[gl];
                    float4 lo, hi; unpack8(w, lo, hi);
                    acc0.x = fmaf(cj, lo.x, acc0.x); acc0.y = fmaf(cj, lo.y, acc0.y);
                    acc0.z = fmaf(cj, lo.z, acc0.z); acc0.w = fmaf(cj, lo.w, acc0.w);
                    acc1.x = fmaf(cj, hi.x, acc1.x); acc1.y = fmaf(cj, hi.y, acc1.y);
                    acc1.z = fmaf(cj, hi.z, acc1.z); acc1.w = fmaf(cj, hi.w, acc1.w);
                }
            }
        }
        // x = elu(acc/4); h = relu(x@fc1+b1) (x broadcast via shfl); out = h@fc2+b2
        acc0.x *= 0.25f; acc0.y *= 0.25f; acc0.z *= 0.25f; acc0.w *= 0.25f;
        acc1.x *= 0.25f; acc1.y *= 0.25f; acc1.z *= 0.25f; acc1.w *= 0.25f;
        acc0.x = acc0.x > 0.f ? acc0.x : expm1f(acc0.x);
        acc0.y = acc0.y > 0.f ? acc0.y : expm1f(acc0.y);
        acc0.z = acc0.z > 0.f ? acc0.z : expm1f(acc0.z);
        acc0.w = acc0.w > 0.f ? acc0.w : expm1f(acc0.w);
        acc1.x = acc1.x > 0.f ? acc1.x : expm1f(acc1.x);
        acc1.y = acc1.y > 0.f ? acc1.y : expm1f(acc1.y);
        acc1.z = acc1.z > 0.f ? acc1.z : expm1f(acc1.z);
        acc1.w = acc1.w > 0.f ? acc1.w : expm1f(acc1.w);
        float xo[8] = {acc0.x,acc0.y,acc0.z,acc0.w, acc1.x,acc1.y,acc1.z,acc1.w};

        float4 hacc = b1v;
#pragma unroll 2
        for (int j = 0; j < 16; ++j) {
            int src = wbase + j;
            float xk0 = __shfl(xo[0], src, 64);
            float xk1 = __shfl(xo[1], src, 64);
            float xk2 = __shfl(xo[2], src, 64);
            float xk3 = __shfl(xo[3], src, 64);
            float xk4 = __shfl(xo[4], src, 64);
            float xk5 = __shfl(xo[5], src, 64);
            float xk6 = __shfl(xo[6], src, 64);
            float xk7 = __shfl(xo[7], src, 64);
            float xks[8] = {xk0,xk1,xk2,xk3,xk4,xk5,xk6,xk7};
#pragma unroll
            for (int e = 0; e < 8; ++e) {
                float4 w = *(const float4*)&fc1s[(8*j + e) * 64 + 4 * gl];
                hacc.x = fmaf(xks[e], w.x, hacc.x); hacc.y = fmaf(xks[e], w.y, hacc.y);
                hacc.z = fmaf(xks[e], w.z, hacc.z); hacc.w = fmaf(xks[e], w.w, hacc.w);
            }
        }
        float r = fmaxf(hacc.x, 0.f) * w2v.x + fmaxf(hacc.y, 0.f) * w2v.y
                + fmaxf(hacc.z, 0.f) * w2v.z + fmaxf(hacc.w, 0.f) * w2v.w;
#pragma unroll
        for (int off = 8; off; off >>= 1) r += __shfl_xor(r, off, 64);
        if (nv && gl == 0) out[n] = r + b2;
    }
}

extern "C" void kernel_launch(void* const* d_in, const int* in_sizes, int n_in,
                              void* d_out, int out_size, void* d_ws, size_t ws_size,
                              hipStream_t stream)
{
    const float* nf   = (const float*)d_in[0];
    const int*   ei   = (const int*)  d_in[1];
    const float* ts   = (const float*)d_in[2];
    const float* Wih0 = (const float*)d_in[3];
    const float* Whh0 = (const float*)d_in[4];
    const float* b0   = (const float*)d_in[5];
    const float* Wih1 = (const float*)d_in[6];
    const float* Whh1 = (const float*)d_in[7];
    const float* b1   = (const float*)d_in[8];
    const float* W1   = (const float*)d_in[9];
    const float* A1   = (const float*)d_in[10];
    const float* W2   = (const float*)d_in[11];
    const float* A2   = (const float*)d_in[12];
    const float* fc1w = (const float*)d_in[13];
    const float* fc1b = (const float*)d_in[14];
    const float* fc2w = (const float*)d_in[15];
    const float* fc2b = (const float*)d_in[16];

    int N = in_sizes[0] / 16;
    int E = in_sizes[1] / 2;
    int T = in_sizes[2] / 3;

    char* ws = (char*)d_ws;
    size_t off = 0;
    auto alloc = [&](size_t bytes) {
        char* p = ws + off;
        off = (off + bytes + 255) & ~(size_t)255;
        return p;
    };
    float* tsb    = (float*)alloc(512);
    float* attfix = (float*)alloc(64);
    int*   flags  = (int*)  alloc(64);
    float* m2g    = (float*)alloc(1024 * sizeof(float));
    float* asrc   = (float*)alloc((size_t)N * 4 * sizeof(float));
    float* adst   = (float*)alloc((size_t)N * 4 * sizeof(float));
    float* asrc2  = (float*)alloc((size_t)N * 4 * sizeof(float));
    float* adst2  = (float*)alloc((size_t)N * 4 * sizeof(float));
    int*   rowptr = (int*)  alloc((size_t)(N + 1) * sizeof(int));
    int*   esrc   = (int*)  alloc((size_t)E * sizeof(int));
    int*   epos   = (int*)  alloc((size_t)E * sizeof(int));
    int*   deg    = (int*)  alloc((size_t)N * sizeof(int));
    int*   bsum   = (int*)  alloc(512 * sizeof(int));
    unsigned short* bufA = (unsigned short*)alloc((size_t)N * 128 * sizeof(unsigned short));
    unsigned short* bufC = (unsigned short*)alloc((size_t)N * 128 * sizeof(unsigned short));

    int NCH = (N + 2047) / 2048;

    hipMemsetAsync(deg, 0, (size_t)N * sizeof(int), stream);
    hipMemsetAsync(flags, 0, 64, stream);

    // ---- mega-front: LSTM(f16 dot2) || (hist -> scan -> scatter) || att1P || Wxp(bf16) || M2 ----
    k_front<<<256, 512, 0, stream>>>(
        ts, Wih0, Whh0, b0, Wih1, Whh1, b1, W1, A1, W2, A2,
        tsb, attfix, m2g,
        ei, deg, epos, nf, bufA, asrc, adst,
        rowptr, bsum, esrc, flags,
        N, E, T, NCH);

    // ---- layer-1 aggregate + layer-2 projections (fused) ----
    k_msg1<<<1024, 512, 0, stream>>>(rowptr, esrc, asrc, adst, bufA, tsb, attfix,
                                     W2, m2g, bufC, asrc2, adst2, N);

    // ---- layer-2 aggregate + FC head (fused) ----
    k_msg0<<<1024, 512, 0, stream>>>(rowptr, esrc, asrc2, adst2, bufC,
                                     fc1w, fc1b, fc2w, fc2b, (float*)d_out, N);
}